// Round 14
// baseline (560.157 us; speedup 1.0000x reference)
//
#include <hip/hip_runtime.h>
#include <math.h>

#define B_ 32
#define T_ 128
#define H_ 300
#define HG 1200   // 4*H
#define LMAX 10
#define WLCAP 8192
#define ECAP 2048
#define NEGV -10000000.0f

typedef __attribute__((ext_vector_type(8))) short bf16x8;
typedef __attribute__((ext_vector_type(4))) float f32x4;
typedef unsigned short ushort_t;

__device__ __forceinline__ float sigm(float x){ return 1.f/(1.f+expf(-x)); }

__device__ __forceinline__ unsigned short f2bf(float x){
  union { float f; unsigned int u; } c; c.f = x;
  unsigned int u = c.u;
  return (unsigned short)((u + 0x7fffu + ((u >> 16) & 1u)) >> 16);
}
__device__ __forceinline__ float bf2f(unsigned short h){
  union { unsigned int u; float f; } c; c.u = ((unsigned int)h) << 16;
  return c.f;
}

// ---------------- fused weight prep: fp32 transposes + bf16 hi/lo padded weights ----------------
__global__ __launch_bounds__(256) void k_prep_all(
    const float* __restrict__ enc_uh, const float* __restrict__ comp_uh,
    const float* __restrict__ enc_wx, const float* __restrict__ comp_wx,
    const float* __restrict__ pw, const float* __restrict__ cw1,
    float* __restrict__ te, float* __restrict__ tc, float* __restrict__ w1t,
    ushort_t* __restrict__ WencH, ushort_t* __restrict__ WencL,
    ushort_t* __restrict__ WcompH, ushort_t* __restrict__ WcompL,
    ushort_t* __restrict__ WPH, ushort_t* __restrict__ WPL)
{
  int i = blockIdx.x*256 + threadIdx.x;
  if (i < 90000) {                       // uh1 transposes: te/tc[m][k] = uh[1][k][m]
    int m = i / H_, k = i - m*H_;
    te[i] = enc_uh[H_*H_ + (size_t)k*H_ + m];
    tc[i] = comp_uh[H_*H_ + (size_t)k*H_ + m];
  } else if (i < 450000) {               // w1t (1200 x 300): w1t[m][k] = cw1[k][m]
    int i2 = i - 90000;
    int m = i2 / H_, k = i2 - m*H_;
    w1t[i2] = cw1[(size_t)k*HG + m];
  } else if (i < 834000) {               // Wenc hi/lo [1200][320], zero-padded
    int i2 = i - 450000;
    int n = i2 / 320, k = i2 - n*320;
    float v = (k < 300) ? enc_wx[(size_t)n*300 + k] : 0.f;
    ushort_t h = f2bf(v);
    WencH[i2] = h; WencL[i2] = f2bf(v - bf2f(h));
  } else if (i < 1218000) {              // Wcomp hi/lo [1200][320]
    int i2 = i - 834000;
    int n = i2 / 320, k = i2 - n*320;
    float v = (k < 300) ? comp_wx[(size_t)n*300 + k] : 0.f;
    ushort_t h = f2bf(v);
    WcompH[i2] = h; WcompL[i2] = f2bf(v - bf2f(h));
  } else if (i < 1496400) {              // folded proj W hi/lo [300][928]
    int i2 = i - 1218000;
    int n = i2 / 928, k = i2 - n*928;
    const float* r = pw + (size_t)n*HG;
    float v = 0.f;
    if (k < 300)      v = r[k] + r[600+k];
    else if (k < 600) v = r[k] - r[k+300];
    else if (k < 900) v = r[k+300];
    ushort_t h = f2bf(v);
    WPH[i2] = h; WPL[i2] = f2bf(v - bf2f(h));
  }
}

// ---------------- embedding gather + bf16 split: [8192][320] hi/lo ----------------
__global__ __launch_bounds__(256) void k_embed_split(const int* __restrict__ prem, const int* __restrict__ hyp,
    const float* __restrict__ emb, ushort_t* __restrict__ EH, ushort_t* __restrict__ EL)
{
  int i = blockIdx.x*256 + threadIdx.x;      // over 8192*320
  int bt = i / 320, k = i - bt*320;
  int side = bt >> 12, bt2 = bt & 4095;
  float v = 0.f;
  if (k < 300) {
    int tok = (side == 0 ? prem : hyp)[bt2];
    v = emb[(size_t)tok*H_ + k];
  }
  ushort_t h = f2bf(v);
  EH[i] = h; EL[i] = f2bf(v - bf2f(h));
}

// ---------------- H1 -> bf16 hi/lo split: [8192][320] (aliases dead EH/EL) ----------------
__global__ __launch_bounds__(256) void k_h_split(const float* __restrict__ H1,
    ushort_t* __restrict__ HH, ushort_t* __restrict__ HL)
{
  int i = blockIdx.x*256 + threadIdx.x;      // over 8192*320
  int r = i / 320, k = i - r*320;
  float v = (k < 300) ? H1[(size_t)r*H_ + k] : 0.f;
  ushort_t h = f2bf(v);
  HH[i] = h; HL[i] = f2bf(v - bf2f(h));
}

// ---------------- enhance + bf16 split: A=[H1|ATT|H1*ATT] -> [8192][928] hi/lo ----------------
__global__ __launch_bounds__(256) void k_enh_split(const float* __restrict__ H1, const float* __restrict__ ATT,
    ushort_t* __restrict__ AH, ushort_t* __restrict__ AL)
{
  int i = blockIdx.x*256 + threadIdx.x;      // over 8192*928
  int r = i / 928, k = i - r*928;
  float v = 0.f;
  if (k < 300)      v = H1[(size_t)r*H_ + k];
  else if (k < 600) v = ATT[(size_t)r*H_ + k - 300];
  else if (k < 900) { int kk = k - 600; v = H1[(size_t)r*H_ + kk] * ATT[(size_t)r*H_ + kk]; }
  ushort_t h = f2bf(v);
  AH[i] = h; AL[i] = f2bf(v - bf2f(h));
}

// ---------------- graph analysis v2 (round-10 proven) ----------------
__global__ __launch_bounds__(256) void k_build(const float* __restrict__ lg, const float* __restrict__ rg,
    int* __restrict__ cnt_g, int* __restrict__ coff_g, int* __restrict__ eidx_g, float* __restrict__ ew_g,
    int* __restrict__ hasp_g, int* __restrict__ depth_g, int* __restrict__ maxd_g,
    int* __restrict__ lvlcnt_g, int* __restrict__ wl_g)
{
  int chain = blockIdx.x; int s = chain >> 5, b = chain & 31;
  const float* graph = (s ? rg : lg) + (size_t)b*T_*T_;
  int tid = threadIdx.x;
  __shared__ float gbuf[T_*T_];            // 64 KB
  __shared__ int cnt[T_], coff[T_], depth[T_], hasp[T_];
  __shared__ short eidx[ECAP];
  __shared__ float ew[ECAP];
  __shared__ int lcnt[LMAX], lbase[LMAX], lpos[LMAX];
  __shared__ int etot_s;

  #pragma unroll
  for (int k = 0; k < 16; ++k)
    ((float4*)gbuf)[tid + k*256] = ((const float4*)graph)[tid + k*256];
  if (tid < T_) hasp[tid] = 0;
  if (tid < LMAX) { lcnt[tid] = 0; lpos[tid] = 0; }
  __syncthreads();
  if (tid < T_) {
    int j = tid, c = 0;
    const float* gr = gbuf + j*T_;
    for (int t = 0; t < j; ++t) c += (gr[t] != 0.f) ? 1 : 0;
    cnt[j] = c;
  }
  __syncthreads();
  if (tid == 0) { int a = 0; for (int j = 0; j < T_; ++j) { coff[j] = a; a += cnt[j]; } etot_s = a; }
  __syncthreads();
  if (tid < T_) {
    int j = tid, p = coff[j];
    const float* gr = gbuf + j*T_;
    for (int t = 0; t < j; ++t) {
      float g = gr[t];
      if (g != 0.f && p < ECAP) { eidx[p] = (short)t; ew[p] = g; hasp[t] = 1; ++p; }
    }
  }
  __syncthreads();
  if (tid == 0) {
    int md = 0;
    for (int j = 0; j < T_; ++j) {
      int d = 0, e0 = coff[j], e1 = coff[j] + cnt[j];
      if (e1 > ECAP) e1 = ECAP;
      for (int k = e0; k < e1; ++k) { int dd = depth[eidx[k]] + 1; d = dd > d ? dd : d; }
      depth[j] = d; md = d > md ? d : md;
    }
    maxd_g[chain] = md;
  }
  __syncthreads();
  if (tid < T_) { int L = depth[tid]; if (L < LMAX) atomicAdd(&lcnt[L], 1); }
  __syncthreads();
  if (tid < LMAX && lcnt[tid] > 0) lbase[tid] = atomicAdd(&lvlcnt_g[tid], lcnt[tid]);
  __syncthreads();
  if (tid < T_) {
    int L = depth[tid];
    if (L < LMAX) {
      int p = atomicAdd(&lpos[L], 1);
      wl_g[L*WLCAP + lbase[L] + p] = (chain << 8) | tid;
    }
  }
  int base = chain * T_;
  if (tid < T_) {
    cnt_g[base+tid] = cnt[tid]; coff_g[base+tid] = coff[tid];
    hasp_g[base+tid] = hasp[tid]; depth_g[base+tid] = depth[tid];
  }
  int etot = etot_s; if (etot > ECAP) etot = ECAP;
  for (int i = tid; i < etot; i += 256) { eidx_g[chain*ECAP + i] = eidx[i]; ew_g[chain*ECAP + i] = ew[i]; }
}

// ---------------- per-level tree-LSTM: 4 nodes/block, float4 LDS matvec ----------------
__global__ __launch_bounds__(1024) void k_level(
    const float* __restrict__ xg, const float* __restrict__ bhv, const float* __restrict__ uh1T,
    const int* __restrict__ cnt_g, const int* __restrict__ coff_g,
    const int* __restrict__ eidx_g, const float* __restrict__ ew_g,
    const int* __restrict__ hasp_g, const int* __restrict__ lvlcnt_g, const int* __restrict__ wl_g,
    int L, float* __restrict__ hout, float* __restrict__ chist, float* __restrict__ fh)
{
  int count = lvlcnt_g[L];
  int nblk = (count + 3) >> 2;
  int tid = threadIdx.x;
  __shared__ float h_s[4][H_];
  __shared__ float psum[3][4][H_];
  __shared__ int nodes[4];
  __shared__ int anyp;
  for (int blk = blockIdx.x; blk < nblk; blk += gridDim.x) {
    int base = blk * 4;
    int nn = count - base; if (nn > 4) nn = 4;
    if (tid == 0) anyp = 0;
    __syncthreads();
    if (tid < 4) {
      int pk = (tid < nn) ? wl_g[L*WLCAP + base + tid] : -1;
      nodes[tid] = pk;
      if (pk >= 0 && hasp_g[(pk >> 8)*T_ + (pk & 255)]) atomicAdd(&anyp, 1);
      if (pk < 0) {   // pad: zero h_s row so matvec stays valid
      }
    }
    __syncthreads();
    for (int w = tid; w < 4*H_; w += 1024) {   // zero pad rows for nn<4
      int n = w / H_;
      if (n >= nn) h_s[n][w - n*H_] = 0.f;
    }
    for (int w = tid; w < nn*H_; w += 1024) {
      int n = w / H_, e = w - n*H_;
      int pk = nodes[n]; int chain = pk >> 8, j = pk & 255;
      size_t cb = (size_t)chain*T_*H_, xb = (size_t)chain*T_*HG;
      const float* xp = xg + xb + (size_t)j*HG;
      float x0 = xp[e], x1 = xp[H_+e], x2 = xp[2*H_+e], x3 = xp[3*H_+e];
      float iu  = sigm(x0 + bhv[e]) * tanhf(x3 + bhv[3*H_+e]);
      float og  = sigm(x2 + bhv[2*H_+e]);
      float x1b = x1 + bhv[H_+e];
      float acc = iu;
      int c0 = coff_g[chain*T_+j], c1 = c0 + cnt_g[chain*T_+j];
      const int* ei = eidx_g + chain*ECAP;
      const float* ewp = ew_g + chain*ECAP;
      for (int k = c0; k < c1; ++k) {
        int t = ei[k];
        acc += ewp[k] * sigm(x1b + fh[cb + (size_t)t*H_ + e]) * chist[cb + (size_t)t*H_ + e];
      }
      chist[cb + (size_t)j*H_ + e] = acc;
      float hv = og * tanhf(acc);
      hout[cb + (size_t)j*H_ + e] = hv;
      h_s[n][e] = hv;
    }
    __syncthreads();
    if (anyp > 0) {
      if (tid < 3*H_) {
        int g = tid / H_, e = tid - g*H_;
        float a0=0.f, a1=0.f, a2=0.f, a3=0.f;
        const float* up = uh1T + e;
        int m0 = g*100;
        #pragma unroll 5
        for (int m = m0; m < m0 + 100; m += 4) {
          float4 h0 = *(const float4*)&h_s[0][m];
          float4 h1 = *(const float4*)&h_s[1][m];
          float4 h2 = *(const float4*)&h_s[2][m];
          float4 h3 = *(const float4*)&h_s[3][m];
          float u0 = up[(size_t)m*H_];
          float u1 = up[(size_t)(m+1)*H_];
          float u2 = up[(size_t)(m+2)*H_];
          float u3 = up[(size_t)(m+3)*H_];
          a0 = fmaf(u0,h0.x,a0); a0 = fmaf(u1,h0.y,a0); a0 = fmaf(u2,h0.z,a0); a0 = fmaf(u3,h0.w,a0);
          a1 = fmaf(u0,h1.x,a1); a1 = fmaf(u1,h1.y,a1); a1 = fmaf(u2,h1.z,a1); a1 = fmaf(u3,h1.w,a1);
          a2 = fmaf(u0,h2.x,a2); a2 = fmaf(u1,h2.y,a2); a2 = fmaf(u2,h2.z,a2); a2 = fmaf(u3,h2.w,a2);
          a3 = fmaf(u0,h3.x,a3); a3 = fmaf(u1,h3.y,a3); a3 = fmaf(u2,h3.z,a3); a3 = fmaf(u3,h3.w,a3);
        }
        psum[g][0][e]=a0; psum[g][1][e]=a1; psum[g][2][e]=a2; psum[g][3][e]=a3;
      }
      __syncthreads();
      for (int w = tid; w < nn*H_; w += 1024) {
        int n = w / H_, e = w - n*H_;
        int pk = nodes[n]; int chain = pk >> 8, j = pk & 255;
        if (hasp_g[chain*T_+j]) {
          size_t cb = (size_t)chain*T_*H_;
          fh[cb + (size_t)j*H_ + e] = psum[0][n][e] + psum[1][n][e] + psum[2][n][e];
        }
      }
    }
    __syncthreads();
  }
}

// ---------------- serial tail for rare deep graphs (inline gates, float4 LDS matvec) ----------------
__global__ __launch_bounds__(320) void k_tail(const float* __restrict__ xg, const float* __restrict__ bhv,
    const float* __restrict__ uh1T, const int* __restrict__ cnt_g, const int* __restrict__ coff_g,
    const int* __restrict__ eidx_g, const float* __restrict__ ew_g, const int* __restrict__ hasp_g,
    const int* __restrict__ depth_g, const int* __restrict__ maxd_g,
    float* __restrict__ hout, float* __restrict__ chist, float* __restrict__ fh)
{
  int chain = blockIdx.x;
  if (maxd_g[chain] < LMAX) return;
  int tid = threadIdx.x;
  bool act = tid < H_;
  float bh0=0.f,bh1=0.f,bh2=0.f,bh3=0.f;
  if (act) { bh0=bhv[tid]; bh1=bhv[H_+tid]; bh2=bhv[2*H_+tid]; bh3=bhv[3*H_+tid]; }
  __shared__ float h_lds[H_];
  size_t cb = (size_t)chain*T_*H_, xb = (size_t)chain*T_*HG;
  const int* ei = eidx_g + chain*ECAP;
  const float* ewp = ew_g + chain*ECAP;
  for (int j = 0; j < T_; ++j) {
    if (depth_g[chain*T_+j] < LMAX) continue;
    if (act) {
      const float* xp = xg + xb + (size_t)j*HG;
      float x0 = xp[tid], x1 = xp[H_+tid], x2 = xp[2*H_+tid], x3 = xp[3*H_+tid];
      float acc = sigm(x0+bh0) * tanhf(x3+bh3);
      float og  = sigm(x2+bh2);
      float x1b = x1 + bh1;
      int c0 = coff_g[chain*T_+j], c1 = c0 + cnt_g[chain*T_+j];
      for (int k = c0; k < c1; ++k) {
        int t = ei[k];
        acc += ewp[k] * sigm(x1b + fh[cb + (size_t)t*H_ + tid]) * chist[cb + (size_t)t*H_ + tid];
      }
      chist[cb + (size_t)j*H_ + tid] = acc;
      float hv = og * tanhf(acc);
      hout[cb + (size_t)j*H_ + tid] = hv;
      h_lds[tid] = hv;
    }
    __syncthreads();
    if (hasp_g[chain*T_+j] && act) {
      float a = 0.f;
      const float* up = uh1T + tid;
      #pragma unroll 5
      for (int m = 0; m < H_; m += 4) {
        float4 hv4 = *(const float4*)&h_lds[m];
        a = fmaf(up[(size_t)m*H_],     hv4.x, a);
        a = fmaf(up[(size_t)(m+1)*H_], hv4.y, a);
        a = fmaf(up[(size_t)(m+2)*H_], hv4.z, a);
        a = fmaf(up[(size_t)(m+3)*H_], hv4.w, a);
      }
      fh[cb + (size_t)j*H_ + tid] = a;
    }
    __syncthreads();
  }
}

// ---------------- split-bf16 MFMA GEMM v2 (round-9 proven) ----------------
template<int OUTBF>
__global__ __launch_bounds__(256) void k_gemm_bf(
    const ushort_t* __restrict__ Ah, const ushort_t* __restrict__ Al, int AS,
    const ushort_t* __restrict__ Wh, const ushort_t* __restrict__ Wl, int WS,
    const float* __restrict__ bias, float* __restrict__ C,
    ushort_t* __restrict__ Ch, ushort_t* __restrict__ Cl, int CS,
    int N, int NT, int act)
{
  __shared__ ushort_t sAh[128*32], sAl[128*32], sWh[128*32], sWl[128*32];  // 32 KB
  int tid = threadIdx.x;
  int bn = blockIdx.x * 128, bm = blockIdx.y * 128;
  int lane = tid & 63, wave = tid >> 6;
  int wr = (wave >> 1) * 64, wc = (wave & 1) * 64;
  int lrow = lane & 15, q = lane >> 4;

  int srow = tid >> 1, half = tid & 1;
  int ssw = (srow >> 1) & 3;
  int sg0 = ((2*half) ^ ssw) * 8, sg1 = ((2*half+1) ^ ssw) * 8;
  int sbase = srow * 32;
  const ushort_t* pAh = Ah + (size_t)(bm + srow)*AS + half*16;
  const ushort_t* pAl = Al + (size_t)(bm + srow)*AS + half*16;
  int wrow = bn + srow;
  int wsafe = (wrow < N) ? wrow : 0;
  const ushort_t* pWh = Wh + (size_t)wsafe*WS + half*16;
  const ushort_t* pWl = Wl + (size_t)wsafe*WS + half*16;

  bf16x8 rA0, rA1, rAl0, rAl1, rW0, rW1, rWl0, rWl1;
  auto issue = [&](int t){
    int kb = t * 32;
    rA0  = *(const bf16x8*)(pAh + kb); rA1  = *(const bf16x8*)(pAh + kb + 8);
    rAl0 = *(const bf16x8*)(pAl + kb); rAl1 = *(const bf16x8*)(pAl + kb + 8);
    rW0  = *(const bf16x8*)(pWh + kb); rW1  = *(const bf16x8*)(pWh + kb + 8);
    rWl0 = *(const bf16x8*)(pWl + kb); rWl1 = *(const bf16x8*)(pWl + kb + 8);
  };
  auto commit = [&](){
    *(bf16x8*)&sAh[sbase + sg0] = rA0; *(bf16x8*)&sAh[sbase + sg1] = rA1;
    *(bf16x8*)&sAl[sbase + sg0] = rAl0; *(bf16x8*)&sAl[sbase + sg1] = rAl1;
    *(bf16x8*)&sWh[sbase + sg0] = rW0; *(bf16x8*)&sWh[sbase + sg1] = rW1;
    *(bf16x8*)&sWl[sbase + sg0] = rWl0; *(bf16x8*)&sWl[sbase + sg1] = rWl1;
  };

  f32x4 acc[4][4];
  #pragma unroll
  for (int m = 0; m < 4; ++m)
    #pragma unroll
    for (int n = 0; n < 4; ++n) acc[m][n] = (f32x4){0.f,0.f,0.f,0.f};

  issue(0); commit();
  __syncthreads();
  for (int t = 0; t < NT; ++t) {
    bool more = (t+1 < NT);
    if (more) issue(t+1);
    bf16x8 ah[4], al[4], bh[4], bl[4];
    #pragma unroll
    for (int m = 0; m < 4; ++m) {
      int R = wr + m*16 + lrow;
      int o = R*32 + ((q ^ ((R>>1)&3)) * 8);
      ah[m] = *(const bf16x8*)&sAh[o];
      al[m] = *(const bf16x8*)&sAl[o];
    }
    #pragma unroll
    for (int n = 0; n < 4; ++n) {
      int R = wc + n*16 + lrow;
      int o = R*32 + ((q ^ ((R>>1)&3)) * 8);
      bh[n] = *(const bf16x8*)&sWh[o];
      bl[n] = *(const bf16x8*)&sWl[o];
    }
    #pragma unroll
    for (int m = 0; m < 4; ++m)
      #pragma unroll
      for (int n = 0; n < 4; ++n) {
        acc[m][n] = __builtin_amdgcn_mfma_f32_16x16x32_bf16(ah[m], bh[n], acc[m][n], 0,0,0);
        acc[m][n] = __builtin_amdgcn_mfma_f32_16x16x32_bf16(ah[m], bl[n], acc[m][n], 0,0,0);
        acc[m][n] = __builtin_amdgcn_mfma_f32_16x16x32_bf16(al[m], bh[n], acc[m][n], 0,0,0);
      }
    __syncthreads();
    if (more) commit();
    __syncthreads();
  }
  #pragma unroll
  for (int m = 0; m < 4; ++m) {
    int row0 = bm + wr + m*16 + (lane >> 4)*4;
    #pragma unroll
    for (int n = 0; n < 4; ++n) {
      int col = bn + wc + n*16 + lrow;
      if (OUTBF) {
        if (col < CS) {
          float bv = (col < N) ? bias[col] : 0.f;
          #pragma unroll
          for (int r = 0; r < 4; ++r) {
            float v = 0.f;
            if (col < N) { v = acc[m][n][r] + bv; if (act) v = fmaxf(v, 0.f); }
            ushort_t h = f2bf(v);
            Ch[(size_t)(row0 + r)*CS + col] = h;
            Cl[(size_t)(row0 + r)*CS + col] = f2bf(v - bf2f(h));
          }
        }
      } else {
        if (col < N) {
          float bv = bias[col];
          #pragma unroll
          for (int r = 0; r < 4; ++r) {
            float v = acc[m][n][r] + bv;
            if (act) v = fmaxf(v, 0.f);
            C[(size_t)(row0 + r)*N + col] = v;
          }
        }
      }
    }
  }
}

// ---------------- fused MFMA attention v2: bf16 pre-split inputs (round-13) ----------------
__global__ __launch_bounds__(256) void k_attn_mfma(
    const ushort_t* __restrict__ HH, const ushort_t* __restrict__ HL,
    const int* __restrict__ plen, const int* __restrict__ hlen,
    float* __restrict__ ATT)
{
  __shared__ float regA_f[12800];
  __shared__ ushort_t pbuf[2*64*136];
  ushort_t* regA = (ushort_t*)regA_f;

  int tid = threadIdx.x;
  int lane = tid & 63, wave = tid >> 6;
  int lrow = lane & 15, koff = (lane >> 4) * 8;
  int d = blockIdx.x, b = blockIdx.y, q0 = blockIdx.z * 64;
  int qbase = (d*B_ + b)*T_ + q0;
  int kbase = ((1-d)*B_ + b)*T_;
  float* outp = ATT + ((size_t)(d*B_ + b)*T_ + q0) * H_;
  int klen = (d == 0) ? hlen[b] : plen[b];

  ushort_t* sQh = regA;            // [64][40]
  ushort_t* sQl = regA + 2560;
  ushort_t* sKh = regA + 5120;     // [128][40]
  ushort_t* sKl = regA + 10240;
  int qrow = tid >> 2, qo = (tid & 3) * 8;
  int krow = tid >> 1, ko = (tid & 1) * 16;
  const ushort_t* Qh = HH + (size_t)(qbase + qrow)*320 + qo;
  const ushort_t* Ql = HL + (size_t)(qbase + qrow)*320 + qo;
  const ushort_t* Kh = HH + (size_t)(kbase + krow)*320 + ko;
  const ushort_t* Kl = HL + (size_t)(kbase + krow)*320 + ko;

  bf16x8 rqh, rql, rkh0, rkh1, rkl0, rkl1;
  auto issue1 = [&](int t){
    int kb = t*32;
    rqh  = *(const bf16x8*)(Qh + kb);
    rql  = *(const bf16x8*)(Ql + kb);
    rkh0 = *(const bf16x8*)(Kh + kb); rkh1 = *(const bf16x8*)(Kh + kb + 8);
    rkl0 = *(const bf16x8*)(Kl + kb); rkl1 = *(const bf16x8*)(Kl + kb + 8);
  };
  auto commit1 = [&](){
    *(bf16x8*)&sQh[qrow*40 + qo] = rqh;
    *(bf16x8*)&sQl[qrow*40 + qo] = rql;
    *(bf16x8*)&sKh[krow*40 + ko] = rkh0; *(bf16x8*)&sKh[krow*40 + ko + 8] = rkh1;
    *(bf16x8*)&sKl[krow*40 + ko] = rkl0; *(bf16x8*)&sKl[krow*40 + ko + 8] = rkl1;
  };

  f32x4 acc1[4][2];
  #pragma unroll
  for (int m = 0; m < 4; ++m)
    #pragma unroll
    for (int n = 0; n < 2; ++n) acc1[m][n] = (f32x4){0.f,0.f,0.f,0.f};
  int wc = wave * 32;

  issue1(0); commit1();
  __syncthreads();
  for (int t = 0; t < 10; ++t) {
    bool more = (t < 9);
    bf16x8 ah[4], al[4], bh[2], bl[2];
    #pragma unroll
    for (int m = 0; m < 4; ++m) {
      int o = (m*16 + lrow)*40 + koff;
      ah[m] = *(const bf16x8*)&sQh[o];
      al[m] = *(const bf16x8*)&sQl[o];
    }
    #pragma unroll
    for (int n = 0; n < 2; ++n) {
      int o = (wc + n*16 + lrow)*40 + koff;
      bh[n] = *(const bf16x8*)&sKh[o];
      bl[n] = *(const bf16x8*)&sKl[o];
    }
    if (more) issue1(t+1);
    __syncthreads();
    if (more) commit1();
    #pragma unroll
    for (int m = 0; m < 4; ++m)
      #pragma unroll
      for (int n = 0; n < 2; ++n) {
        acc1[m][n] = __builtin_amdgcn_mfma_f32_16x16x32_bf16(ah[m], bh[n], acc1[m][n], 0,0,0);
        acc1[m][n] = __builtin_amdgcn_mfma_f32_16x16x32_bf16(ah[m], bl[n], acc1[m][n], 0,0,0);
        acc1[m][n] = __builtin_amdgcn_mfma_f32_16x16x32_bf16(al[m], bh[n], acc1[m][n], 0,0,0);
      }
    __syncthreads();
  }
  float* sim = regA_f;
  #pragma unroll
  for (int m = 0; m < 4; ++m)
    #pragma unroll
    for (int n = 0; n < 2; ++n)
      #pragma unroll
      for (int r = 0; r < 4; ++r)
        sim[(m*16 + (lane>>4)*4 + r)*132 + wc + n*16 + lrow] = acc1[m][n][r];
  __syncthreads();

  {
    int row = tid >> 2, qtr = (tid & 3) * 32;
    const float* sr = sim + row*132;
    float mx = NEGV;
    for (int c = 0; c < 32; ++c) { int cg = qtr + c; float s = (cg < klen) ? sr[cg] : NEGV; mx = fmaxf(mx, s); }
    mx = fmaxf(mx, __shfl_xor(mx, 1));
    mx = fmaxf(mx, __shfl_xor(mx, 2));
    float sum = 0.f;
    for (int c = 0; c < 32; ++c) { int cg = qtr + c; if (cg < klen) sum += expf(sr[cg] - mx); }
    sum += __shfl_xor(sum, 1);
    sum += __shfl_xor(sum, 2);
    float rinv = 1.f / sum;
    for (int c = 0; c < 32; ++c) {
      int cg = qtr + c;
      float p = (cg < klen) ? expf(sr[cg] - mx) * rinv : 0.f;
      ushort_t h = f2bf(p);
      pbuf[row*136 + cg] = h;
      pbuf[64*136 + row*136 + cg] = f2bf(p - bf2f(h));
    }
  }
  __syncthreads();

  ushort_t* kth = regA;            // [320][40]
  ushort_t* ktl = regA + 12800;
  int wr2 = (wave & 1) * 32;
  int wcf = (wave >> 1) * 160;
  f32x4 acc3[2][10];
  #pragma unroll
  for (int m = 0; m < 2; ++m)
    #pragma unroll
    for (int n = 0; n < 10; ++n) acc3[m][n] = (f32x4){0.f,0.f,0.f,0.f};
  int skey = tid >> 3, sf8 = tid & 7;

  for (int kc = 0; kc < 4; ++kc) {
    __syncthreads();
    int key = kbase + kc*32 + skey;
    const ushort_t* krh = HH + (size_t)key*320;
    const ushort_t* krl = HL + (size_t)key*320;
    for (int f8 = sf8; f8 < 40; f8 += 8) {
      bf16x8 vh = *(const bf16x8*)(krh + f8*8);
      bf16x8 vl = *(const bf16x8*)(krl + f8*8);
      #pragma unroll
      for (int i = 0; i < 8; ++i) {
        int feat = f8*8 + i;
        kth[feat*40 + skey] = (ushort_t)vh[i];
        ktl[feat*40 + skey] = (ushort_t)vl[i];
      }
    }
    __syncthreads();
    bf16x8 ph[2], pl[2], kh[10], kl[10];
    #pragma unroll
    for (int m = 0; m < 2; ++m) {
      int o = (wr2 + m*16 + lrow)*136 + kc*32 + koff;
      ph[m] = *(const bf16x8*)&pbuf[o];
      pl[m] = *(const bf16x8*)&pbuf[64*136 + o];
    }
    #pragma unroll
    for (int n = 0; n < 10; ++n) {
      int o = (wcf + n*16 + lrow)*40 + koff;
      kh[n] = *(const bf16x8*)&kth[o];
      kl[n] = *(const bf16x8*)&ktl[o];
    }
    #pragma unroll
    for (int m = 0; m < 2; ++m)
      #pragma unroll
      for (int n = 0; n < 10; ++n) {
        acc3[m][n] = __builtin_amdgcn_mfma_f32_16x16x32_bf16(ph[m], kh[n], acc3[m][n], 0,0,0);
        acc3[m][n] = __builtin_amdgcn_mfma_f32_16x16x32_bf16(ph[m], kl[n], acc3[m][n], 0,0,0);
        acc3[m][n] = __builtin_amdgcn_mfma_f32_16x16x32_bf16(pl[m], kh[n], acc3[m][n], 0,0,0);
      }
  }
  #pragma unroll
  for (int m = 0; m < 2; ++m) {
    int row0 = wr2 + m*16 + (lane >> 4)*4;
    #pragma unroll
    for (int n = 0; n < 10; ++n) {
      int col = wcf + n*16 + lrow;
      if (col < H_) {
        #pragma unroll
        for (int r = 0; r < 4; ++r)
          outp[(size_t)(row0 + r)*H_ + col] = acc3[m][n][r];
      }
    }
  }
}

// ---------------- pool stage 1 ----------------
__global__ __launch_bounds__(320) void k_pool(const float* __restrict__ H,
    const int* __restrict__ plen, const int* __restrict__ hlen,
    float* __restrict__ psum, float* __restrict__ pmax)
{
  int chain = blockIdx.x; int s = chain >> 5, b = chain & 31;
  int c = blockIdx.y; int t0 = c * 16;
  int len = (s == 0 ? plen[b] : hlen[b]);
  int tid = threadIdx.x;
  __shared__ float buf[16*H_];
  const float* hp = H + (size_t)chain*T_*H_ + (size_t)t0*H_;
  for (int i = tid; i < 16*H_; i += 320) buf[i] = hp[i];
  __syncthreads();
  if (tid < H_) {
    int tmax = len - t0; if (tmax > 16) tmax = 16;
    float sum = 0.f, mx = NEGV;
    for (int t = 0; t < tmax; ++t) { float x = buf[t*H_ + tid]; sum += x; mx = fmaxf(mx, x); }
    int o = (chain*8 + c)*H_ + tid;
    psum[o] = sum; pmax[o] = mx;
  }
}

// ---------------- pool stage 2 + classifier ----------------
__global__ __launch_bounds__(320) void k_classify(
    const float* __restrict__ psum, const float* __restrict__ pmax,
    const int* __restrict__ plen, const int* __restrict__ hlen,
    const float* __restrict__ w1t, const float* __restrict__ b1,
    const float* __restrict__ w2, const float* __restrict__ b2,
    float* __restrict__ out)
{
  int b = blockIdx.x;
  int tid = threadIdx.x;
  __shared__ float v[HG];
  __shared__ float hid[H_];
  for (int s = 0; s < 2; ++s) {
    int chain = s*B_ + b;
    int len = (s == 0 ? plen[b] : hlen[b]);
    if (tid < H_) {
      float sum = 0.f, mx = NEGV;
      #pragma unroll
      for (int c = 0; c < 8; ++c) {
        int o = (chain*8 + c)*H_ + tid;
        sum += psum[o]; mx = fmaxf(mx, pmax[o]);
      }
      v[s*600 + tid]       = sum / (float)len;
      v[s*600 + 300 + tid] = mx;
    }
  }
  __syncthreads();
  if (tid < H_) {
    float a0 = b1[tid], a1 = 0.f, a2 = 0.f, a3 = 0.f;
    for (int m = 0; m < HG; m += 4) {
      a0 = fmaf(v[m+0], w1t[(size_t)(m+0)*H_ + tid], a0);
      a1 = fmaf(v[m+1], w1t[(size_t)(m+1)*H_ + tid], a1);
      a2 = fmaf(v[m+2], w1t[(size_t)(m+2)*H_ + tid], a2);
      a3 = fmaf(v[m+3], w1t[(size_t)(m+3)*H_ + tid], a3);
    }
    hid[tid] = tanhf(a0 + a1 + a2 + a3);
  }
  __syncthreads();
  if (tid < 3) {
    float a = b2[tid];
    const float* wr = w2 + (size_t)tid*H_;
    for (int n = 0; n < H_; ++n) a = fmaf(hid[n], wr[n], a);
    out[b*3 + tid] = a;
  }
}

// ---------------- launch ----------------
extern "C" void kernel_launch(void* const* d_in, const int* in_sizes, int n_in,
                              void* d_out, int out_size, void* d_ws, size_t ws_size,
                              hipStream_t stream) {
  const int*   prem    = (const int*)d_in[0];
  const int*   plen    = (const int*)d_in[1];
  const int*   hyp     = (const int*)d_in[2];
  const int*   hlen    = (const int*)d_in[3];
  const float* lg      = (const float*)d_in[4];
  const float* rg      = (const float*)d_in[5];
  const float* emb     = (const float*)d_in[6];
  const float* enc_wx  = (const float*)d_in[7];
  const float* enc_bx  = (const float*)d_in[8];
  const float* enc_uh  = (const float*)d_in[9];
  const float* enc_bh  = (const float*)d_in[10];
  const float* comp_wx = (const float*)d_in[11];
  const float* comp_bx = (const float*)d_in[12];
  const float* comp_uh = (const float*)d_in[13];
  const float* comp_bh = (const float*)d_in[14];
  const float* proj_w  = (const float*)d_in[15];
  const float* proj_b  = (const float*)d_in[16];
  const float* cls_w1  = (const float*)d_in[17];
  const float* cls_b1  = (const float*)d_in[18];
  const float* cls_w2  = (const float*)d_in[19];
  const float* cls_b2  = (const float*)d_in[20];
  float* outp = (float*)d_out;

  // workspace layout (floats); ENH bf16 aliases XG; PROJ/H-split bf16 alias EH/EL
  float* XG  = (float*)d_ws;                       // 9,830,400 f
  ushort_t* EH = (ushort_t*)(XG + 9830400);        // [8192][320] hi (emb -> h-split -> PROJ)
  ushort_t* EL = EH + 2621440;                     // [8192][320] lo
  float* H1  = XG + 9830400 + 2621440;
  float* CH  = H1 + 2457600;                       // ATT alias
  float* FH  = CH + 2457600;
  float* UTE = FH + 2457600;
  float* UTC = UTE + 90000;
  float* W1T = UTC + 90000;
  ushort_t* WencH  = (ushort_t*)(W1T + 360000);
  ushort_t* WencL  = WencH + 384000;
  ushort_t* WcompH = WencL + 384000;
  ushort_t* WcompL = WcompH + 384000;
  ushort_t* WPH    = WcompL + 384000;
  ushort_t* WPL    = WPH + 278400;
  float* PSUM = W1T + 360000 + 1046400;
  float* PMAX = PSUM + 153600;
  float* EW   = PMAX + 153600;
  int* EIDX   = (int*)(EW + 64*ECAP);
  int* CNT    = EIDX + 64*ECAP;
  int* COFF   = CNT + 64*T_;
  int* DEPTH  = COFF + 64*T_;
  int* HASP   = DEPTH + 64*T_;
  int* MAXD   = HASP + 64*T_;
  int* LVLCNT = MAXD + 64;
  int* WL     = LVLCNT + LMAX;
  float* ATT  = CH;
  ushort_t* ENH_H = (ushort_t*)XG;                 // [8192][928] hi (after enc scan, XG dead)
  ushort_t* ENH_L = ENH_H + 7602176;

  hipMemsetAsync(LVLCNT, 0, LMAX*sizeof(int), stream);
  // 1. weight prep + graph analysis + embedding split
  k_prep_all<<<(1496400 + 255)/256, 256, 0, stream>>>(enc_uh, comp_uh, enc_wx, comp_wx, proj_w, cls_w1,
      UTE, UTC, W1T, WencH, WencL, WcompH, WcompL, WPH, WPL);
  k_build<<<64, 256, 0, stream>>>(lg, rg, CNT, COFF, EIDX, EW, HASP, DEPTH, MAXD, LVLCNT, WL);
  k_embed_split<<<10240, 256, 0, stream>>>(prem, hyp, emb, EH, EL);
  // 2. enc xg = emb @ enc_wx^T + enc_bx
  k_gemm_bf<0><<<dim3(10, 64), 256, 0, stream>>>(EH, EL, 320, WencH, WencL, 320,
      enc_bx, XG, nullptr, nullptr, 0, HG, 10, 0);
  // 3. enc tree scan
  for (int L = 0; L < LMAX; ++L)
    k_level<<<640, 1024, 0, stream>>>(XG, enc_bh, UTE, CNT, COFF, EIDX, EW, HASP, LVLCNT, WL, L, H1, CH, FH);
  k_tail<<<64, 320, 0, stream>>>(XG, enc_bh, UTE, CNT, COFF, EIDX, EW, HASP, DEPTH, MAXD, H1, CH, FH);
  // 4. h-split + attention (CH dead -> ATT)
  k_h_split<<<10240, 256, 0, stream>>>(H1, EH, EL);
  k_attn_mfma<<<dim3(2, B_, 2), 256, 0, stream>>>(EH, EL, plen, hlen, ATT);
  // 5. enhance split (enc-xg dead), proj GEMM -> PROJ bf16 hi/lo (overwrites EH/EL)
  k_enh_split<<<29696, 256, 0, stream>>>(H1, ATT, ENH_H, ENH_L);
  k_gemm_bf<1><<<dim3(3, 64), 256, 0, stream>>>(ENH_H, ENH_L, 928, WPH, WPL, 928,
      proj_b, nullptr, EH, EL, 320, H_, 29, 1);
  // 6. comp xg = proj @ comp_wx^T + comp_bx (overwrites XG)
  k_gemm_bf<0><<<dim3(10, 64), 256, 0, stream>>>(EH, EL, 320, WcompH, WcompL, 320,
      comp_bx, XG, nullptr, nullptr, 0, HG, 10, 0);
  // 7. comp tree scan
  for (int L = 0; L < LMAX; ++L)
    k_level<<<640, 1024, 0, stream>>>(XG, comp_bh, UTC, CNT, COFF, EIDX, EW, HASP, LVLCNT, WL, L, H1, CH, FH);
  k_tail<<<64, 320, 0, stream>>>(XG, comp_bh, UTC, CNT, COFF, EIDX, EW, HASP, DEPTH, MAXD, H1, CH, FH);
  // 8. pool + classifier
  k_pool<<<dim3(64, 8), 320, 0, stream>>>(H1, plen, hlen, PSUM, PMAX);
  k_classify<<<B_, 320, 0, stream>>>(PSUM, PMAX, plen, hlen, W1T, cls_b1, cls_w2, cls_b2, outp);
}

// Round 15
// 495.359 us; speedup vs baseline: 1.1308x; 1.1308x over previous
//
#include <hip/hip_runtime.h>
#include <math.h>

#define B_ 32
#define T_ 128
#define H_ 300
#define HG 1200   // 4*H
#define LMAX 10
#define WLCAP 8192
#define ECAP 2048
#define NEGV -10000000.0f

typedef __attribute__((ext_vector_type(8))) short bf16x8;
typedef __attribute__((ext_vector_type(4))) float f32x4;
typedef unsigned short ushort_t;

__device__ __forceinline__ float sigm(float x){ return 1.f/(1.f+expf(-x)); }

__device__ __forceinline__ unsigned short f2bf(float x){
  union { float f; unsigned int u; } c; c.f = x;
  unsigned int u = c.u;
  return (unsigned short)((u + 0x7fffu + ((u >> 16) & 1u)) >> 16);
}
__device__ __forceinline__ float bf2f(unsigned short h){
  union { unsigned int u; float f; } c; c.u = ((unsigned int)h) << 16;
  return c.f;
}

// ---------------- fused weight prep: fp32 transposes + bf16 hi/lo padded weights ----------------
__global__ __launch_bounds__(256) void k_prep_all(
    const float* __restrict__ enc_uh, const float* __restrict__ comp_uh,
    const float* __restrict__ enc_wx, const float* __restrict__ comp_wx,
    const float* __restrict__ pw, const float* __restrict__ cw1,
    float* __restrict__ te, float* __restrict__ tc, float* __restrict__ w1t,
    ushort_t* __restrict__ WencH, ushort_t* __restrict__ WencL,
    ushort_t* __restrict__ WcompH, ushort_t* __restrict__ WcompL,
    ushort_t* __restrict__ WPH, ushort_t* __restrict__ WPL)
{
  int i = blockIdx.x*256 + threadIdx.x;
  if (i < 90000) {                       // uh1 transposes: te/tc[m][k] = uh[1][k][m]
    int m = i / H_, k = i - m*H_;
    te[i] = enc_uh[H_*H_ + (size_t)k*H_ + m];
    tc[i] = comp_uh[H_*H_ + (size_t)k*H_ + m];
  } else if (i < 450000) {               // w1t (1200 x 300): w1t[m][k] = cw1[k][m]
    int i2 = i - 90000;
    int m = i2 / H_, k = i2 - m*H_;
    w1t[i2] = cw1[(size_t)k*HG + m];
  } else if (i < 834000) {               // Wenc hi/lo [1200][320], zero-padded
    int i2 = i - 450000;
    int n = i2 / 320, k = i2 - n*320;
    float v = (k < 300) ? enc_wx[(size_t)n*300 + k] : 0.f;
    ushort_t h = f2bf(v);
    WencH[i2] = h; WencL[i2] = f2bf(v - bf2f(h));
  } else if (i < 1218000) {              // Wcomp hi/lo [1200][320]
    int i2 = i - 834000;
    int n = i2 / 320, k = i2 - n*320;
    float v = (k < 300) ? comp_wx[(size_t)n*300 + k] : 0.f;
    ushort_t h = f2bf(v);
    WcompH[i2] = h; WcompL[i2] = f2bf(v - bf2f(h));
  } else if (i < 1496400) {              // folded proj W hi/lo [300][928]
    int i2 = i - 1218000;
    int n = i2 / 928, k = i2 - n*928;
    const float* r = pw + (size_t)n*HG;
    float v = 0.f;
    if (k < 300)      v = r[k] + r[600+k];
    else if (k < 600) v = r[k] - r[k+300];
    else if (k < 900) v = r[k+300];
    ushort_t h = f2bf(v);
    WPH[i2] = h; WPL[i2] = f2bf(v - bf2f(h));
  }
}

// ---------------- embedding gather + bf16 split: [8192][320] hi/lo ----------------
__global__ __launch_bounds__(256) void k_embed_split(const int* __restrict__ prem, const int* __restrict__ hyp,
    const float* __restrict__ emb, ushort_t* __restrict__ EH, ushort_t* __restrict__ EL)
{
  int i = blockIdx.x*256 + threadIdx.x;      // over 8192*320
  int bt = i / 320, k = i - bt*320;
  int side = bt >> 12, bt2 = bt & 4095;
  float v = 0.f;
  if (k < 300) {
    int tok = (side == 0 ? prem : hyp)[bt2];
    v = emb[(size_t)tok*H_ + k];
  }
  ushort_t h = f2bf(v);
  EH[i] = h; EL[i] = f2bf(v - bf2f(h));
}

// ---------------- H1 -> bf16 hi/lo split: [8192][320] (aliases dead EH/EL) ----------------
__global__ __launch_bounds__(256) void k_h_split(const float* __restrict__ H1,
    ushort_t* __restrict__ HH, ushort_t* __restrict__ HL)
{
  int i = blockIdx.x*256 + threadIdx.x;      // over 8192*320
  int r = i / 320, k = i - r*320;
  float v = (k < 300) ? H1[(size_t)r*H_ + k] : 0.f;
  ushort_t h = f2bf(v);
  HH[i] = h; HL[i] = f2bf(v - bf2f(h));
}

// ---------------- enhance + bf16 split: A=[H1|ATT|H1*ATT] -> [8192][928] hi/lo ----------------
__global__ __launch_bounds__(256) void k_enh_split(const float* __restrict__ H1, const float* __restrict__ ATT,
    ushort_t* __restrict__ AH, ushort_t* __restrict__ AL)
{
  int i = blockIdx.x*256 + threadIdx.x;      // over 8192*928
  int r = i / 928, k = i - r*928;
  float v = 0.f;
  if (k < 300)      v = H1[(size_t)r*H_ + k];
  else if (k < 600) v = ATT[(size_t)r*H_ + k - 300];
  else if (k < 900) { int kk = k - 600; v = H1[(size_t)r*H_ + kk] * ATT[(size_t)r*H_ + kk]; }
  ushort_t h = f2bf(v);
  AH[i] = h; AL[i] = f2bf(v - bf2f(h));
}

// ---------------- graph analysis v3: parented-first worklist partition per (chain,level) ----------------
__global__ __launch_bounds__(256) void k_build(const float* __restrict__ lg, const float* __restrict__ rg,
    int* __restrict__ cnt_g, int* __restrict__ coff_g, int* __restrict__ eidx_g, float* __restrict__ ew_g,
    int* __restrict__ hasp_g, int* __restrict__ depth_g, int* __restrict__ maxd_g,
    int* __restrict__ lvlcnt_g, int* __restrict__ wl_g)
{
  int chain = blockIdx.x; int s = chain >> 5, b = chain & 31;
  const float* graph = (s ? rg : lg) + (size_t)b*T_*T_;
  int tid = threadIdx.x;
  __shared__ float gbuf[T_*T_];            // 64 KB
  __shared__ int cnt[T_], coff[T_], depth[T_], hasp[T_];
  __shared__ short eidx[ECAP];
  __shared__ float ew[ECAP];
  __shared__ int lcnt[LMAX], lbase[LMAX], lppos[LMAX], lnpos[LMAX];
  __shared__ int etot_s;

  #pragma unroll
  for (int k = 0; k < 16; ++k)
    ((float4*)gbuf)[tid + k*256] = ((const float4*)graph)[tid + k*256];
  if (tid < T_) hasp[tid] = 0;
  if (tid < LMAX) { lcnt[tid] = 0; lppos[tid] = 0; lnpos[tid] = 0; }
  __syncthreads();
  if (tid < T_) {
    int j = tid, c = 0;
    const float* gr = gbuf + j*T_;
    for (int t = 0; t < j; ++t) c += (gr[t] != 0.f) ? 1 : 0;
    cnt[j] = c;
  }
  __syncthreads();
  if (tid == 0) { int a = 0; for (int j = 0; j < T_; ++j) { coff[j] = a; a += cnt[j]; } etot_s = a; }
  __syncthreads();
  if (tid < T_) {
    int j = tid, p = coff[j];
    const float* gr = gbuf + j*T_;
    for (int t = 0; t < j; ++t) {
      float g = gr[t];
      if (g != 0.f && p < ECAP) { eidx[p] = (short)t; ew[p] = g; hasp[t] = 1; ++p; }
    }
  }
  __syncthreads();
  if (tid == 0) {
    int md = 0;
    for (int j = 0; j < T_; ++j) {
      int d = 0, e0 = coff[j], e1 = coff[j] + cnt[j];
      if (e1 > ECAP) e1 = ECAP;
      for (int k = e0; k < e1; ++k) { int dd = depth[eidx[k]] + 1; d = dd > d ? dd : d; }
      depth[j] = d; md = d > md ? d : md;
    }
    maxd_g[chain] = md;
  }
  __syncthreads();
  if (tid < T_) { int L = depth[tid]; if (L < LMAX) atomicAdd(&lcnt[L], 1); }
  __syncthreads();
  if (tid < LMAX && lcnt[tid] > 0) lbase[tid] = atomicAdd(&lvlcnt_g[tid], lcnt[tid]);
  __syncthreads();
  // fill worklist chunk: parented nodes from the front, unparented from the back
  if (tid < T_) {
    int L = depth[tid];
    if (L < LMAX) {
      int pos;
      if (hasp[tid]) { int p = atomicAdd(&lppos[L], 1); pos = p; }
      else           { int p = atomicAdd(&lnpos[L], 1); pos = lcnt[L] - 1 - p; }
      wl_g[L*WLCAP + lbase[L] + pos] = (chain << 8) | tid;
    }
  }
  int base = chain * T_;
  if (tid < T_) {
    cnt_g[base+tid] = cnt[tid]; coff_g[base+tid] = coff[tid];
    hasp_g[base+tid] = hasp[tid]; depth_g[base+tid] = depth[tid];
  }
  int etot = etot_s; if (etot > ECAP) etot = ECAP;
  for (int i = tid; i < etot; i += 256) { eidx_g[chain*ECAP + i] = eidx[i]; ew_g[chain*ECAP + i] = ew[i]; }
}

// ---------------- per-level tree-LSTM (round-10 proven: 4 nodes/block, scalar matvec) ----------------
__global__ __launch_bounds__(1024) void k_level(
    const float* __restrict__ xg, const float* __restrict__ bhv, const float* __restrict__ uh1T,
    const int* __restrict__ cnt_g, const int* __restrict__ coff_g,
    const int* __restrict__ eidx_g, const float* __restrict__ ew_g,
    const int* __restrict__ hasp_g, const int* __restrict__ lvlcnt_g, const int* __restrict__ wl_g,
    int L, float* __restrict__ hout, float* __restrict__ chist, float* __restrict__ fh)
{
  int count = lvlcnt_g[L];
  int nblk = (count + 3) >> 2;
  int tid = threadIdx.x;
  __shared__ float h_s[4][H_];
  __shared__ float psum[3][4][H_];
  __shared__ int nodes[4];
  __shared__ int anyp;
  for (int blk = blockIdx.x; blk < nblk; blk += gridDim.x) {
    int base = blk * 4;
    int nn = count - base; if (nn > 4) nn = 4;
    if (tid == 0) anyp = 0;
    __syncthreads();
    if (tid < 4) {
      int pk = (tid < nn) ? wl_g[L*WLCAP + base + tid] : -1;
      nodes[tid] = pk;
      if (pk >= 0 && hasp_g[(pk >> 8)*T_ + (pk & 255)]) atomicAdd(&anyp, 1);
    }
    __syncthreads();
    for (int w = tid; w < nn*H_; w += 1024) {
      int n = w / H_, e = w - n*H_;
      int pk = nodes[n]; int chain = pk >> 8, j = pk & 255;
      size_t cb = (size_t)chain*T_*H_, xb = (size_t)chain*T_*HG;
      const float* xp = xg + xb + (size_t)j*HG;
      float x0 = xp[e], x1 = xp[H_+e], x2 = xp[2*H_+e], x3 = xp[3*H_+e];
      float iu  = sigm(x0 + bhv[e]) * tanhf(x3 + bhv[3*H_+e]);
      float og  = sigm(x2 + bhv[2*H_+e]);
      float x1b = x1 + bhv[H_+e];
      float acc = iu;
      int c0 = coff_g[chain*T_+j], c1 = c0 + cnt_g[chain*T_+j];
      const int* ei = eidx_g + chain*ECAP;
      const float* ewp = ew_g + chain*ECAP;
      for (int k = c0; k < c1; ++k) {
        int t = ei[k];
        acc += ewp[k] * sigm(x1b + fh[cb + (size_t)t*H_ + e]) * chist[cb + (size_t)t*H_ + e];
      }
      chist[cb + (size_t)j*H_ + e] = acc;
      float hv = og * tanhf(acc);
      hout[cb + (size_t)j*H_ + e] = hv;
      h_s[n][e] = hv;
    }
    __syncthreads();
    if (anyp > 0) {
      if (tid < 3*H_) {
        int g = tid / H_, e = tid - g*H_;
        float a0=0.f, a1=0.f, a2=0.f, a3=0.f;
        const float* up = uh1T + e;
        int m0 = g*100, m1 = m0 + 100;
        #pragma unroll 4
        for (int m = m0; m < m1; ++m) {
          float u = up[(size_t)m*H_];
          a0 = fmaf(u, h_s[0][m], a0);
          a1 = fmaf(u, h_s[1][m], a1);
          a2 = fmaf(u, h_s[2][m], a2);
          a3 = fmaf(u, h_s[3][m], a3);
        }
        psum[g][0][e]=a0; psum[g][1][e]=a1; psum[g][2][e]=a2; psum[g][3][e]=a3;
      }
      __syncthreads();
      for (int w = tid; w < nn*H_; w += 1024) {
        int n = w / H_, e = w - n*H_;
        int pk = nodes[n]; int chain = pk >> 8, j = pk & 255;
        if (hasp_g[chain*T_+j]) {
          size_t cb = (size_t)chain*T_*H_;
          fh[cb + (size_t)j*H_ + e] = psum[0][n][e] + psum[1][n][e] + psum[2][n][e];
        }
      }
    }
    __syncthreads();
  }
}

// ---------------- serial tail for rare deep graphs (inline gates) ----------------
__global__ __launch_bounds__(320) void k_tail(const float* __restrict__ xg, const float* __restrict__ bhv,
    const float* __restrict__ uh1T, const int* __restrict__ cnt_g, const int* __restrict__ coff_g,
    const int* __restrict__ eidx_g, const float* __restrict__ ew_g, const int* __restrict__ hasp_g,
    const int* __restrict__ depth_g, const int* __restrict__ maxd_g,
    float* __restrict__ hout, float* __restrict__ chist, float* __restrict__ fh)
{
  int chain = blockIdx.x;
  if (maxd_g[chain] < LMAX) return;
  int tid = threadIdx.x;
  bool act = tid < H_;
  float bh0=0.f,bh1=0.f,bh2=0.f,bh3=0.f;
  if (act) { bh0=bhv[tid]; bh1=bhv[H_+tid]; bh2=bhv[2*H_+tid]; bh3=bhv[3*H_+tid]; }
  __shared__ float h_lds[H_];
  size_t cb = (size_t)chain*T_*H_, xb = (size_t)chain*T_*HG;
  const int* ei = eidx_g + chain*ECAP;
  const float* ewp = ew_g + chain*ECAP;
  for (int j = 0; j < T_; ++j) {
    if (depth_g[chain*T_+j] < LMAX) continue;
    if (act) {
      const float* xp = xg + xb + (size_t)j*HG;
      float x0 = xp[tid], x1 = xp[H_+tid], x2 = xp[2*H_+tid], x3 = xp[3*H_+tid];
      float acc = sigm(x0+bh0) * tanhf(x3+bh3);
      float og  = sigm(x2+bh2);
      float x1b = x1 + bh1;
      int c0 = coff_g[chain*T_+j], c1 = c0 + cnt_g[chain*T_+j];
      for (int k = c0; k < c1; ++k) {
        int t = ei[k];
        acc += ewp[k] * sigm(x1b + fh[cb + (size_t)t*H_ + tid]) * chist[cb + (size_t)t*H_ + tid];
      }
      chist[cb + (size_t)j*H_ + tid] = acc;
      float hv = og * tanhf(acc);
      hout[cb + (size_t)j*H_ + tid] = hv;
      h_lds[tid] = hv;
    }
    __syncthreads();
    if (hasp_g[chain*T_+j] && act) {
      float a = 0.f;
      const float* up = uh1T + tid;
      #pragma unroll 4
      for (int m = 0; m < H_; ++m) a = fmaf(up[(size_t)m*H_], h_lds[m], a);
      fh[cb + (size_t)j*H_ + tid] = a;
    }
    __syncthreads();
  }
}

// ---------------- split-bf16 MFMA GEMM v2 (round-9 proven) ----------------
template<int OUTBF>
__global__ __launch_bounds__(256) void k_gemm_bf(
    const ushort_t* __restrict__ Ah, const ushort_t* __restrict__ Al, int AS,
    const ushort_t* __restrict__ Wh, const ushort_t* __restrict__ Wl, int WS,
    const float* __restrict__ bias, float* __restrict__ C,
    ushort_t* __restrict__ Ch, ushort_t* __restrict__ Cl, int CS,
    int N, int NT, int act)
{
  __shared__ ushort_t sAh[128*32], sAl[128*32], sWh[128*32], sWl[128*32];  // 32 KB
  int tid = threadIdx.x;
  int bn = blockIdx.x * 128, bm = blockIdx.y * 128;
  int lane = tid & 63, wave = tid >> 6;
  int wr = (wave >> 1) * 64, wc = (wave & 1) * 64;
  int lrow = lane & 15, q = lane >> 4;

  int srow = tid >> 1, half = tid & 1;
  int ssw = (srow >> 1) & 3;
  int sg0 = ((2*half) ^ ssw) * 8, sg1 = ((2*half+1) ^ ssw) * 8;
  int sbase = srow * 32;
  const ushort_t* pAh = Ah + (size_t)(bm + srow)*AS + half*16;
  const ushort_t* pAl = Al + (size_t)(bm + srow)*AS + half*16;
  int wrow = bn + srow;
  int wsafe = (wrow < N) ? wrow : 0;
  const ushort_t* pWh = Wh + (size_t)wsafe*WS + half*16;
  const ushort_t* pWl = Wl + (size_t)wsafe*WS + half*16;

  bf16x8 rA0, rA1, rAl0, rAl1, rW0, rW1, rWl0, rWl1;
  auto issue = [&](int t){
    int kb = t * 32;
    rA0  = *(const bf16x8*)(pAh + kb); rA1  = *(const bf16x8*)(pAh + kb + 8);
    rAl0 = *(const bf16x8*)(pAl + kb); rAl1 = *(const bf16x8*)(pAl + kb + 8);
    rW0  = *(const bf16x8*)(pWh + kb); rW1  = *(const bf16x8*)(pWh + kb + 8);
    rWl0 = *(const bf16x8*)(pWl + kb); rWl1 = *(const bf16x8*)(pWl + kb + 8);
  };
  auto commit = [&](){
    *(bf16x8*)&sAh[sbase + sg0] = rA0; *(bf16x8*)&sAh[sbase + sg1] = rA1;
    *(bf16x8*)&sAl[sbase + sg0] = rAl0; *(bf16x8*)&sAl[sbase + sg1] = rAl1;
    *(bf16x8*)&sWh[sbase + sg0] = rW0; *(bf16x8*)&sWh[sbase + sg1] = rW1;
    *(bf16x8*)&sWl[sbase + sg0] = rWl0; *(bf16x8*)&sWl[sbase + sg1] = rWl1;
  };

  f32x4 acc[4][4];
  #pragma unroll
  for (int m = 0; m < 4; ++m)
    #pragma unroll
    for (int n = 0; n < 4; ++n) acc[m][n] = (f32x4){0.f,0.f,0.f,0.f};

  issue(0); commit();
  __syncthreads();
  for (int t = 0; t < NT; ++t) {
    bool more = (t+1 < NT);
    if (more) issue(t+1);
    bf16x8 ah[4], al[4], bh[4], bl[4];
    #pragma unroll
    for (int m = 0; m < 4; ++m) {
      int R = wr + m*16 + lrow;
      int o = R*32 + ((q ^ ((R>>1)&3)) * 8);
      ah[m] = *(const bf16x8*)&sAh[o];
      al[m] = *(const bf16x8*)&sAl[o];
    }
    #pragma unroll
    for (int n = 0; n < 4; ++n) {
      int R = wc + n*16 + lrow;
      int o = R*32 + ((q ^ ((R>>1)&3)) * 8);
      bh[n] = *(const bf16x8*)&sWh[o];
      bl[n] = *(const bf16x8*)&sWl[o];
    }
    #pragma unroll
    for (int m = 0; m < 4; ++m)
      #pragma unroll
      for (int n = 0; n < 4; ++n) {
        acc[m][n] = __builtin_amdgcn_mfma_f32_16x16x32_bf16(ah[m], bh[n], acc[m][n], 0,0,0);
        acc[m][n] = __builtin_amdgcn_mfma_f32_16x16x32_bf16(ah[m], bl[n], acc[m][n], 0,0,0);
        acc[m][n] = __builtin_amdgcn_mfma_f32_16x16x32_bf16(al[m], bh[n], acc[m][n], 0,0,0);
      }
    __syncthreads();
    if (more) commit();
    __syncthreads();
  }
  #pragma unroll
  for (int m = 0; m < 4; ++m) {
    int row0 = bm + wr + m*16 + (lane >> 4)*4;
    #pragma unroll
    for (int n = 0; n < 4; ++n) {
      int col = bn + wc + n*16 + lrow;
      if (OUTBF) {
        if (col < CS) {
          float bv = (col < N) ? bias[col] : 0.f;
          #pragma unroll
          for (int r = 0; r < 4; ++r) {
            float v = 0.f;
            if (col < N) { v = acc[m][n][r] + bv; if (act) v = fmaxf(v, 0.f); }
            ushort_t h = f2bf(v);
            Ch[(size_t)(row0 + r)*CS + col] = h;
            Cl[(size_t)(row0 + r)*CS + col] = f2bf(v - bf2f(h));
          }
        }
      } else {
        if (col < N) {
          float bv = bias[col];
          #pragma unroll
          for (int r = 0; r < 4; ++r) {
            float v = acc[m][n][r] + bv;
            if (act) v = fmaxf(v, 0.f);
            C[(size_t)(row0 + r)*N + col] = v;
          }
        }
      }
    }
  }
}

// ---------------- fused MFMA attention v2: bf16 pre-split inputs (round-13) ----------------
__global__ __launch_bounds__(256) void k_attn_mfma(
    const ushort_t* __restrict__ HH, const ushort_t* __restrict__ HL,
    const int* __restrict__ plen, const int* __restrict__ hlen,
    float* __restrict__ ATT)
{
  __shared__ float regA_f[12800];
  __shared__ ushort_t pbuf[2*64*136];
  ushort_t* regA = (ushort_t*)regA_f;

  int tid = threadIdx.x;
  int lane = tid & 63, wave = tid >> 6;
  int lrow = lane & 15, koff = (lane >> 4) * 8;
  int d = blockIdx.x, b = blockIdx.y, q0 = blockIdx.z * 64;
  int qbase = (d*B_ + b)*T_ + q0;
  int kbase = ((1-d)*B_ + b)*T_;
  float* outp = ATT + ((size_t)(d*B_ + b)*T_ + q0) * H_;
  int klen = (d == 0) ? hlen[b] : plen[b];

  ushort_t* sQh = regA;            // [64][40]
  ushort_t* sQl = regA + 2560;
  ushort_t* sKh = regA + 5120;     // [128][40]
  ushort_t* sKl = regA + 10240;
  int qrow = tid >> 2, qo = (tid & 3) * 8;
  int krow = tid >> 1, ko = (tid & 1) * 16;
  const ushort_t* Qh = HH + (size_t)(qbase + qrow)*320 + qo;
  const ushort_t* Ql = HL + (size_t)(qbase + qrow)*320 + qo;
  const ushort_t* Kh = HH + (size_t)(kbase + krow)*320 + ko;
  const ushort_t* Kl = HL + (size_t)(kbase + krow)*320 + ko;

  bf16x8 rqh, rql, rkh0, rkh1, rkl0, rkl1;
  auto issue1 = [&](int t){
    int kb = t*32;
    rqh  = *(const bf16x8*)(Qh + kb);
    rql  = *(const bf16x8*)(Ql + kb);
    rkh0 = *(const bf16x8*)(Kh + kb); rkh1 = *(const bf16x8*)(Kh + kb + 8);
    rkl0 = *(const bf16x8*)(Kl + kb); rkl1 = *(const bf16x8*)(Kl + kb + 8);
  };
  auto commit1 = [&](){
    *(bf16x8*)&sQh[qrow*40 + qo] = rqh;
    *(bf16x8*)&sQl[qrow*40 + qo] = rql;
    *(bf16x8*)&sKh[krow*40 + ko] = rkh0; *(bf16x8*)&sKh[krow*40 + ko + 8] = rkh1;
    *(bf16x8*)&sKl[krow*40 + ko] = rkl0; *(bf16x8*)&sKl[krow*40 + ko + 8] = rkl1;
  };

  f32x4 acc1[4][2];
  #pragma unroll
  for (int m = 0; m < 4; ++m)
    #pragma unroll
    for (int n = 0; n < 2; ++n) acc1[m][n] = (f32x4){0.f,0.f,0.f,0.f};
  int wc = wave * 32;

  issue1(0); commit1();
  __syncthreads();
  for (int t = 0; t < 10; ++t) {
    bool more = (t < 9);
    bf16x8 ah[4], al[4], bh[2], bl[2];
    #pragma unroll
    for (int m = 0; m < 4; ++m) {
      int o = (m*16 + lrow)*40 + koff;
      ah[m] = *(const bf16x8*)&sQh[o];
      al[m] = *(const bf16x8*)&sQl[o];
    }
    #pragma unroll
    for (int n = 0; n < 2; ++n) {
      int o = (wc + n*16 + lrow)*40 + koff;
      bh[n] = *(const bf16x8*)&sKh[o];
      bl[n] = *(const bf16x8*)&sKl[o];
    }
    if (more) issue1(t+1);
    __syncthreads();
    if (more) commit1();
    #pragma unroll
    for (int m = 0; m < 4; ++m)
      #pragma unroll
      for (int n = 0; n < 2; ++n) {
        acc1[m][n] = __builtin_amdgcn_mfma_f32_16x16x32_bf16(ah[m], bh[n], acc1[m][n], 0,0,0);
        acc1[m][n] = __builtin_amdgcn_mfma_f32_16x16x32_bf16(ah[m], bl[n], acc1[m][n], 0,0,0);
        acc1[m][n] = __builtin_amdgcn_mfma_f32_16x16x32_bf16(al[m], bh[n], acc1[m][n], 0,0,0);
      }
    __syncthreads();
  }
  float* sim = regA_f;
  #pragma unroll
  for (int m = 0; m < 4; ++m)
    #pragma unroll
    for (int n = 0; n < 2; ++n)
      #pragma unroll
      for (int r = 0; r < 4; ++r)
        sim[(m*16 + (lane>>4)*4 + r)*132 + wc + n*16 + lrow] = acc1[m][n][r];
  __syncthreads();

  {
    int row = tid >> 2, qtr = (tid & 3) * 32;
    const float* sr = sim + row*132;
    float mx = NEGV;
    for (int c = 0; c < 32; ++c) { int cg = qtr + c; float s = (cg < klen) ? sr[cg] : NEGV; mx = fmaxf(mx, s); }
    mx = fmaxf(mx, __shfl_xor(mx, 1));
    mx = fmaxf(mx, __shfl_xor(mx, 2));
    float sum = 0.f;
    for (int c = 0; c < 32; ++c) { int cg = qtr + c; if (cg < klen) sum += expf(sr[cg] - mx); }
    sum += __shfl_xor(sum, 1);
    sum += __shfl_xor(sum, 2);
    float rinv = 1.f / sum;
    for (int c = 0; c < 32; ++c) {
      int cg = qtr + c;
      float p = (cg < klen) ? expf(sr[cg] - mx) * rinv : 0.f;
      ushort_t h = f2bf(p);
      pbuf[row*136 + cg] = h;
      pbuf[64*136 + row*136 + cg] = f2bf(p - bf2f(h));
    }
  }
  __syncthreads();

  ushort_t* kth = regA;            // [320][40]
  ushort_t* ktl = regA + 12800;
  int wr2 = (wave & 1) * 32;
  int wcf = (wave >> 1) * 160;
  f32x4 acc3[2][10];
  #pragma unroll
  for (int m = 0; m < 2; ++m)
    #pragma unroll
    for (int n = 0; n < 10; ++n) acc3[m][n] = (f32x4){0.f,0.f,0.f,0.f};
  int skey = tid >> 3, sf8 = tid & 7;

  for (int kc = 0; kc < 4; ++kc) {
    __syncthreads();
    int key = kbase + kc*32 + skey;
    const ushort_t* krh = HH + (size_t)key*320;
    const ushort_t* krl = HL + (size_t)key*320;
    for (int f8 = sf8; f8 < 40; f8 += 8) {
      bf16x8 vh = *(const bf16x8*)(krh + f8*8);
      bf16x8 vl = *(const bf16x8*)(krl + f8*8);
      #pragma unroll
      for (int i = 0; i < 8; ++i) {
        int feat = f8*8 + i;
        kth[feat*40 + skey] = (ushort_t)vh[i];
        ktl[feat*40 + skey] = (ushort_t)vl[i];
      }
    }
    __syncthreads();
    bf16x8 ph[2], pl[2], kh[10], kl[10];
    #pragma unroll
    for (int m = 0; m < 2; ++m) {
      int o = (wr2 + m*16 + lrow)*136 + kc*32 + koff;
      ph[m] = *(const bf16x8*)&pbuf[o];
      pl[m] = *(const bf16x8*)&pbuf[64*136 + o];
    }
    #pragma unroll
    for (int n = 0; n < 10; ++n) {
      int o = (wcf + n*16 + lrow)*40 + koff;
      kh[n] = *(const bf16x8*)&kth[o];
      kl[n] = *(const bf16x8*)&ktl[o];
    }
    #pragma unroll
    for (int m = 0; m < 2; ++m)
      #pragma unroll
      for (int n = 0; n < 10; ++n) {
        acc3[m][n] = __builtin_amdgcn_mfma_f32_16x16x32_bf16(ph[m], kh[n], acc3[m][n], 0,0,0);
        acc3[m][n] = __builtin_amdgcn_mfma_f32_16x16x32_bf16(ph[m], kl[n], acc3[m][n], 0,0,0);
        acc3[m][n] = __builtin_amdgcn_mfma_f32_16x16x32_bf16(pl[m], kh[n], acc3[m][n], 0,0,0);
      }
  }
  #pragma unroll
  for (int m = 0; m < 2; ++m) {
    int row0 = wr2 + m*16 + (lane >> 4)*4;
    #pragma unroll
    for (int n = 0; n < 10; ++n) {
      int col = wcf + n*16 + lrow;
      if (col < H_) {
        #pragma unroll
        for (int r = 0; r < 4; ++r)
          outp[(size_t)(row0 + r)*H_ + col] = acc3[m][n][r];
      }
    }
  }
}

// ---------------- pool stage 1 ----------------
__global__ __launch_bounds__(320) void k_pool(const float* __restrict__ H,
    const int* __restrict__ plen, const int* __restrict__ hlen,
    float* __restrict__ psum, float* __restrict__ pmax)
{
  int chain = blockIdx.x; int s = chain >> 5, b = chain & 31;
  int c = blockIdx.y; int t0 = c * 16;
  int len = (s == 0 ? plen[b] : hlen[b]);
  int tid = threadIdx.x;
  __shared__ float buf[16*H_];
  const float* hp = H + (size_t)chain*T_*H_ + (size_t)t0*H_;
  for (int i = tid; i < 16*H_; i += 320) buf[i] = hp[i];
  __syncthreads();
  if (tid < H_) {
    int tmax = len - t0; if (tmax > 16) tmax = 16;
    float sum = 0.f, mx = NEGV;
    for (int t = 0; t < tmax; ++t) { float x = buf[t*H_ + tid]; sum += x; mx = fmaxf(mx, x); }
    int o = (chain*8 + c)*H_ + tid;
    psum[o] = sum; pmax[o] = mx;
  }
}

// ---------------- pool stage 2 + classifier ----------------
__global__ __launch_bounds__(320) void k_classify(
    const float* __restrict__ psum, const float* __restrict__ pmax,
    const int* __restrict__ plen, const int* __restrict__ hlen,
    const float* __restrict__ w1t, const float* __restrict__ b1,
    const float* __restrict__ w2, const float* __restrict__ b2,
    float* __restrict__ out)
{
  int b = blockIdx.x;
  int tid = threadIdx.x;
  __shared__ float v[HG];
  __shared__ float hid[H_];
  for (int s = 0; s < 2; ++s) {
    int chain = s*B_ + b;
    int len = (s == 0 ? plen[b] : hlen[b]);
    if (tid < H_) {
      float sum = 0.f, mx = NEGV;
      #pragma unroll
      for (int c = 0; c < 8; ++c) {
        int o = (chain*8 + c)*H_ + tid;
        sum += psum[o]; mx = fmaxf(mx, pmax[o]);
      }
      v[s*600 + tid]       = sum / (float)len;
      v[s*600 + 300 + tid] = mx;
    }
  }
  __syncthreads();
  if (tid < H_) {
    float a0 = b1[tid], a1 = 0.f, a2 = 0.f, a3 = 0.f;
    for (int m = 0; m < HG; m += 4) {
      a0 = fmaf(v[m+0], w1t[(size_t)(m+0)*H_ + tid], a0);
      a1 = fmaf(v[m+1], w1t[(size_t)(m+1)*H_ + tid], a1);
      a2 = fmaf(v[m+2], w1t[(size_t)(m+2)*H_ + tid], a2);
      a3 = fmaf(v[m+3], w1t[(size_t)(m+3)*H_ + tid], a3);
    }
    hid[tid] = tanhf(a0 + a1 + a2 + a3);
  }
  __syncthreads();
  if (tid < 3) {
    float a = b2[tid];
    const float* wr = w2 + (size_t)tid*H_;
    for (int n = 0; n < H_; ++n) a = fmaf(hid[n], wr[n], a);
    out[b*3 + tid] = a;
  }
}

// ---------------- launch ----------------
extern "C" void kernel_launch(void* const* d_in, const int* in_sizes, int n_in,
                              void* d_out, int out_size, void* d_ws, size_t ws_size,
                              hipStream_t stream) {
  const int*   prem    = (const int*)d_in[0];
  const int*   plen    = (const int*)d_in[1];
  const int*   hyp     = (const int*)d_in[2];
  const int*   hlen    = (const int*)d_in[3];
  const float* lg      = (const float*)d_in[4];
  const float* rg      = (const float*)d_in[5];
  const float* emb     = (const float*)d_in[6];
  const float* enc_wx  = (const float*)d_in[7];
  const float* enc_bx  = (const float*)d_in[8];
  const float* enc_uh  = (const float*)d_in[9];
  const float* enc_bh  = (const float*)d_in[10];
  const float* comp_wx = (const float*)d_in[11];
  const float* comp_bx = (const float*)d_in[12];
  const float* comp_uh = (const float*)d_in[13];
  const float* comp_bh = (const float*)d_in[14];
  const float* proj_w  = (const float*)d_in[15];
  const float* proj_b  = (const float*)d_in[16];
  const float* cls_w1  = (const float*)d_in[17];
  const float* cls_b1  = (const float*)d_in[18];
  const float* cls_w2  = (const float*)d_in[19];
  const float* cls_b2  = (const float*)d_in[20];
  float* outp = (float*)d_out;

  // workspace layout (floats); ENH bf16 aliases XG; PROJ/H-split bf16 alias EH/EL
  float* XG  = (float*)d_ws;                       // 9,830,400 f
  ushort_t* EH = (ushort_t*)(XG + 9830400);        // [8192][320] hi (emb -> h-split -> PROJ)
  ushort_t* EL = EH + 2621440;                     // [8192][320] lo
  float* H1  = XG + 9830400 + 2621440;
  float* CH  = H1 + 2457600;                       // ATT alias
  float* FH  = CH + 2457600;
  float* UTE = FH + 2457600;
  float* UTC = UTE + 90000;
  float* W1T = UTC + 90000;
  ushort_t* WencH  = (ushort_t*)(W1T + 360000);
  ushort_t* WencL  = WencH + 384000;
  ushort_t* WcompH = WencL + 384000;
  ushort_t* WcompL = WcompH + 384000;
  ushort_t* WPH    = WcompL + 384000;
  ushort_t* WPL    = WPH + 278400;
  float* PSUM = W1T + 360000 + 1046400;
  float* PMAX = PSUM + 153600;
  float* EW   = PMAX + 153600;
  int* EIDX   = (int*)(EW + 64*ECAP);
  int* CNT    = EIDX + 64*ECAP;
  int* COFF   = CNT + 64*T_;
  int* DEPTH  = COFF + 64*T_;
  int* HASP   = DEPTH + 64*T_;
  int* MAXD   = HASP + 64*T_;
  int* LVLCNT = MAXD + 64;
  int* WL     = LVLCNT + LMAX;
  float* ATT  = CH;
  ushort_t* ENH_H = (ushort_t*)XG;                 // [8192][928] hi (after enc scan, XG dead)
  ushort_t* ENH_L = ENH_H + 7602176;

  hipMemsetAsync(LVLCNT, 0, LMAX*sizeof(int), stream);
  // 1. weight prep + graph analysis + embedding split
  k_prep_all<<<(1496400 + 255)/256, 256, 0, stream>>>(enc_uh, comp_uh, enc_wx, comp_wx, proj_w, cls_w1,
      UTE, UTC, W1T, WencH, WencL, WcompH, WcompL, WPH, WPL);
  k_build<<<64, 256, 0, stream>>>(lg, rg, CNT, COFF, EIDX, EW, HASP, DEPTH, MAXD, LVLCNT, WL);
  k_embed_split<<<10240, 256, 0, stream>>>(prem, hyp, emb, EH, EL);
  // 2. enc xg = emb @ enc_wx^T + enc_bx
  k_gemm_bf<0><<<dim3(10, 64), 256, 0, stream>>>(EH, EL, 320, WencH, WencL, 320,
      enc_bx, XG, nullptr, nullptr, 0, HG, 10, 0);
  // 3. enc tree scan
  for (int L = 0; L < LMAX; ++L)
    k_level<<<640, 1024, 0, stream>>>(XG, enc_bh, UTE, CNT, COFF, EIDX, EW, HASP, LVLCNT, WL, L, H1, CH, FH);
  k_tail<<<64, 320, 0, stream>>>(XG, enc_bh, UTE, CNT, COFF, EIDX, EW, HASP, DEPTH, MAXD, H1, CH, FH);
  // 4. h-split + attention (CH dead -> ATT)
  k_h_split<<<10240, 256, 0, stream>>>(H1, EH, EL);
  k_attn_mfma<<<dim3(2, B_, 2), 256, 0, stream>>>(EH, EL, plen, hlen, ATT);
  // 5. enhance split (enc-xg dead), proj GEMM -> PROJ bf16 hi/lo (overwrites EH/EL)
  k_enh_split<<<29696, 256, 0, stream>>>(H1, ATT, ENH_H, ENH_L);
  k_gemm_bf<1><<<dim3(3, 64), 256, 0, stream>>>(ENH_H, ENH_L, 928, WPH, WPL, 928,
      proj_b, nullptr, EH, EL, 320, H_, 29, 1);
  // 6. comp xg = proj @ comp_wx^T + comp_bx (overwrites XG)
  k_gemm_bf<0><<<dim3(10, 64), 256, 0, stream>>>(EH, EL, 320, WcompH, WcompL, 320,
      comp_bx, XG, nullptr, nullptr, 0, HG, 10, 0);
  // 7. comp tree scan
  for (int L = 0; L < LMAX; ++L)
    k_level<<<640, 1024, 0, stream>>>(XG, comp_bh, UTC, CNT, COFF, EIDX, EW, HASP, LVLCNT, WL, L, H1, CH, FH);
  k_tail<<<64, 320, 0, stream>>>(XG, comp_bh, UTC, CNT, COFF, EIDX, EW, HASP, DEPTH, MAXD, H1, CH, FH);
  // 8. pool + classifier
  k_pool<<<dim3(64, 8), 320, 0, stream>>>(H1, plen, hlen, PSUM, PMAX);
  k_classify<<<B_, 320, 0, stream>>>(PSUM, PMAX, plen, hlen, W1T, cls_b1, cls_w2, cls_b2, outp);
}

// Round 16
// 492.420 us; speedup vs baseline: 1.1376x; 1.0060x over previous
//
#include <hip/hip_runtime.h>
#include <math.h>

#define B_ 32
#define T_ 128
#define H_ 300
#define HG 1200   // 4*H
#define TAILD 4   // levels >= TAILD handled by serial per-chain tail
#define WLCAP 8192
#define ECAP 2048
#define NEGV -10000000.0f

typedef __attribute__((ext_vector_type(8))) short bf16x8;
typedef __attribute__((ext_vector_type(4))) float f32x4;
typedef unsigned short ushort_t;

__device__ __forceinline__ float sigm(float x){ return 1.f/(1.f+expf(-x)); }

__device__ __forceinline__ unsigned short f2bf(float x){
  union { float f; unsigned int u; } c; c.f = x;
  unsigned int u = c.u;
  return (unsigned short)((u + 0x7fffu + ((u >> 16) & 1u)) >> 16);
}
__device__ __forceinline__ float bf2f(unsigned short h){
  union { unsigned int u; float f; } c; c.u = ((unsigned int)h) << 16;
  return c.f;
}

// ---------------- fused weight prep: fp32 transposes + bf16 hi/lo padded weights ----------------
__global__ __launch_bounds__(256) void k_prep_all(
    const float* __restrict__ enc_uh, const float* __restrict__ comp_uh,
    const float* __restrict__ enc_wx, const float* __restrict__ comp_wx,
    const float* __restrict__ pw, const float* __restrict__ cw1,
    float* __restrict__ te, float* __restrict__ tc, float* __restrict__ w1t,
    ushort_t* __restrict__ WencH, ushort_t* __restrict__ WencL,
    ushort_t* __restrict__ WcompH, ushort_t* __restrict__ WcompL,
    ushort_t* __restrict__ WPH, ushort_t* __restrict__ WPL)
{
  int i = blockIdx.x*256 + threadIdx.x;
  if (i < 90000) {                       // uh1 transposes: te/tc[m][k] = uh[1][k][m]
    int m = i / H_, k = i - m*H_;
    te[i] = enc_uh[H_*H_ + (size_t)k*H_ + m];
    tc[i] = comp_uh[H_*H_ + (size_t)k*H_ + m];
  } else if (i < 450000) {               // w1t (1200 x 300): w1t[m][k] = cw1[k][m]
    int i2 = i - 90000;
    int m = i2 / H_, k = i2 - m*H_;
    w1t[i2] = cw1[(size_t)k*HG + m];
  } else if (i < 834000) {               // Wenc hi/lo [1200][320], zero-padded
    int i2 = i - 450000;
    int n = i2 / 320, k = i2 - n*320;
    float v = (k < 300) ? enc_wx[(size_t)n*300 + k] : 0.f;
    ushort_t h = f2bf(v);
    WencH[i2] = h; WencL[i2] = f2bf(v - bf2f(h));
  } else if (i < 1218000) {              // Wcomp hi/lo [1200][320]
    int i2 = i - 834000;
    int n = i2 / 320, k = i2 - n*320;
    float v = (k < 300) ? comp_wx[(size_t)n*300 + k] : 0.f;
    ushort_t h = f2bf(v);
    WcompH[i2] = h; WcompL[i2] = f2bf(v - bf2f(h));
  } else if (i < 1496400) {              // folded proj W hi/lo [300][928]
    int i2 = i - 1218000;
    int n = i2 / 928, k = i2 - n*928;
    const float* r = pw + (size_t)n*HG;
    float v = 0.f;
    if (k < 300)      v = r[k] + r[600+k];
    else if (k < 600) v = r[k] - r[k+300];
    else if (k < 900) v = r[k+300];
    ushort_t h = f2bf(v);
    WPH[i2] = h; WPL[i2] = f2bf(v - bf2f(h));
  }
}

// ---------------- embedding gather + bf16 split: [8192][320] hi/lo ----------------
__global__ __launch_bounds__(256) void k_embed_split(const int* __restrict__ prem, const int* __restrict__ hyp,
    const float* __restrict__ emb, ushort_t* __restrict__ EH, ushort_t* __restrict__ EL)
{
  int i = blockIdx.x*256 + threadIdx.x;      // over 8192*320
  int bt = i / 320, k = i - bt*320;
  int side = bt >> 12, bt2 = bt & 4095;
  float v = 0.f;
  if (k < 300) {
    int tok = (side == 0 ? prem : hyp)[bt2];
    v = emb[(size_t)tok*H_ + k];
  }
  ushort_t h = f2bf(v);
  EH[i] = h; EL[i] = f2bf(v - bf2f(h));
}

// ---------------- H1 -> bf16 hi/lo split: [8192][320] (aliases dead EH/EL) ----------------
__global__ __launch_bounds__(256) void k_h_split(const float* __restrict__ H1,
    ushort_t* __restrict__ HH, ushort_t* __restrict__ HL)
{
  int i = blockIdx.x*256 + threadIdx.x;      // over 8192*320
  int r = i / 320, k = i - r*320;
  float v = (k < 300) ? H1[(size_t)r*H_ + k] : 0.f;
  ushort_t h = f2bf(v);
  HH[i] = h; HL[i] = f2bf(v - bf2f(h));
}

// ---------------- enhance + bf16 split: A=[H1|ATT|H1*ATT] -> [8192][928] hi/lo ----------------
__global__ __launch_bounds__(256) void k_enh_split(const float* __restrict__ H1, const float* __restrict__ ATT,
    ushort_t* __restrict__ AH, ushort_t* __restrict__ AL)
{
  int i = blockIdx.x*256 + threadIdx.x;      // over 8192*928
  int r = i / 928, k = i - r*928;
  float v = 0.f;
  if (k < 300)      v = H1[(size_t)r*H_ + k];
  else if (k < 600) v = ATT[(size_t)r*H_ + k - 300];
  else if (k < 900) { int kk = k - 600; v = H1[(size_t)r*H_ + kk] * ATT[(size_t)r*H_ + kk]; }
  ushort_t h = f2bf(v);
  AH[i] = h; AL[i] = f2bf(v - bf2f(h));
}

// ---------------- graph analysis v3: parented-first worklists for levels < TAILD ----------------
__global__ __launch_bounds__(256) void k_build(const float* __restrict__ lg, const float* __restrict__ rg,
    int* __restrict__ cnt_g, int* __restrict__ coff_g, int* __restrict__ eidx_g, float* __restrict__ ew_g,
    int* __restrict__ hasp_g, int* __restrict__ depth_g, int* __restrict__ maxd_g,
    int* __restrict__ lvlcnt_g, int* __restrict__ wl_g)
{
  int chain = blockIdx.x; int s = chain >> 5, b = chain & 31;
  const float* graph = (s ? rg : lg) + (size_t)b*T_*T_;
  int tid = threadIdx.x;
  __shared__ float gbuf[T_*T_];            // 64 KB
  __shared__ int cnt[T_], coff[T_], depth[T_], hasp[T_];
  __shared__ short eidx[ECAP];
  __shared__ float ew[ECAP];
  __shared__ int lcnt[TAILD], lbase[TAILD], lppos[TAILD], lnpos[TAILD];
  __shared__ int etot_s;

  #pragma unroll
  for (int k = 0; k < 16; ++k)
    ((float4*)gbuf)[tid + k*256] = ((const float4*)graph)[tid + k*256];
  if (tid < T_) hasp[tid] = 0;
  if (tid < TAILD) { lcnt[tid] = 0; lppos[tid] = 0; lnpos[tid] = 0; }
  __syncthreads();
  if (tid < T_) {
    int j = tid, c = 0;
    const float* gr = gbuf + j*T_;
    for (int t = 0; t < j; ++t) c += (gr[t] != 0.f) ? 1 : 0;
    cnt[j] = c;
  }
  __syncthreads();
  if (tid == 0) { int a = 0; for (int j = 0; j < T_; ++j) { coff[j] = a; a += cnt[j]; } etot_s = a; }
  __syncthreads();
  if (tid < T_) {
    int j = tid, p = coff[j];
    const float* gr = gbuf + j*T_;
    for (int t = 0; t < j; ++t) {
      float g = gr[t];
      if (g != 0.f && p < ECAP) { eidx[p] = (short)t; ew[p] = g; hasp[t] = 1; ++p; }
    }
  }
  __syncthreads();
  if (tid == 0) {
    int md = 0;
    for (int j = 0; j < T_; ++j) {
      int d = 0, e0 = coff[j], e1 = coff[j] + cnt[j];
      if (e1 > ECAP) e1 = ECAP;
      for (int k = e0; k < e1; ++k) { int dd = depth[eidx[k]] + 1; d = dd > d ? dd : d; }
      depth[j] = d; md = d > md ? d : md;
    }
    maxd_g[chain] = md;
  }
  __syncthreads();
  if (tid < T_) { int L = depth[tid]; if (L < TAILD) atomicAdd(&lcnt[L], 1); }
  __syncthreads();
  if (tid < TAILD && lcnt[tid] > 0) lbase[tid] = atomicAdd(&lvlcnt_g[tid], lcnt[tid]);
  __syncthreads();
  // fill worklist chunk: parented nodes from the front, unparented from the back
  if (tid < T_) {
    int L = depth[tid];
    if (L < TAILD) {
      int pos;
      if (hasp[tid]) { int p = atomicAdd(&lppos[L], 1); pos = p; }
      else           { int p = atomicAdd(&lnpos[L], 1); pos = lcnt[L] - 1 - p; }
      wl_g[L*WLCAP + lbase[L] + pos] = (chain << 8) | tid;
    }
  }
  int base = chain * T_;
  if (tid < T_) {
    cnt_g[base+tid] = cnt[tid]; coff_g[base+tid] = coff[tid];
    hasp_g[base+tid] = hasp[tid]; depth_g[base+tid] = depth[tid];
  }
  int etot = etot_s; if (etot > ECAP) etot = ECAP;
  for (int i = tid; i < etot; i += 256) { eidx_g[chain*ECAP + i] = eidx[i]; ew_g[chain*ECAP + i] = ew[i]; }
}

// ---------------- per-level tree-LSTM (round-10 proven: 4 nodes/block, scalar matvec) ----------------
__global__ __launch_bounds__(1024) void k_level(
    const float* __restrict__ xg, const float* __restrict__ bhv, const float* __restrict__ uh1T,
    const int* __restrict__ cnt_g, const int* __restrict__ coff_g,
    const int* __restrict__ eidx_g, const float* __restrict__ ew_g,
    const int* __restrict__ hasp_g, const int* __restrict__ lvlcnt_g, const int* __restrict__ wl_g,
    int L, float* __restrict__ hout, float* __restrict__ chist, float* __restrict__ fh)
{
  int count = lvlcnt_g[L];
  int nblk = (count + 3) >> 2;
  int tid = threadIdx.x;
  __shared__ float h_s[4][H_];
  __shared__ float psum[3][4][H_];
  __shared__ int nodes[4];
  __shared__ int anyp;
  for (int blk = blockIdx.x; blk < nblk; blk += gridDim.x) {
    int base = blk * 4;
    int nn = count - base; if (nn > 4) nn = 4;
    if (tid == 0) anyp = 0;
    __syncthreads();
    if (tid < 4) {
      int pk = (tid < nn) ? wl_g[L*WLCAP + base + tid] : -1;
      nodes[tid] = pk;
      if (pk >= 0 && hasp_g[(pk >> 8)*T_ + (pk & 255)]) atomicAdd(&anyp, 1);
    }
    __syncthreads();
    for (int w = tid; w < nn*H_; w += 1024) {
      int n = w / H_, e = w - n*H_;
      int pk = nodes[n]; int chain = pk >> 8, j = pk & 255;
      size_t cb = (size_t)chain*T_*H_, xb = (size_t)chain*T_*HG;
      const float* xp = xg + xb + (size_t)j*HG;
      float x0 = xp[e], x1 = xp[H_+e], x2 = xp[2*H_+e], x3 = xp[3*H_+e];
      float iu  = sigm(x0 + bhv[e]) * tanhf(x3 + bhv[3*H_+e]);
      float og  = sigm(x2 + bhv[2*H_+e]);
      float x1b = x1 + bhv[H_+e];
      float acc = iu;
      int c0 = coff_g[chain*T_+j], c1 = c0 + cnt_g[chain*T_+j];
      const int* ei = eidx_g + chain*ECAP;
      const float* ewp = ew_g + chain*ECAP;
      for (int k = c0; k < c1; ++k) {
        int t = ei[k];
        acc += ewp[k] * sigm(x1b + fh[cb + (size_t)t*H_ + e]) * chist[cb + (size_t)t*H_ + e];
      }
      chist[cb + (size_t)j*H_ + e] = acc;
      float hv = og * tanhf(acc);
      hout[cb + (size_t)j*H_ + e] = hv;
      h_s[n][e] = hv;
    }
    __syncthreads();
    if (anyp > 0) {
      if (tid < 3*H_) {
        int g = tid / H_, e = tid - g*H_;
        float a0=0.f, a1=0.f, a2=0.f, a3=0.f;
        const float* up = uh1T + e;
        int m0 = g*100, m1 = m0 + 100;
        #pragma unroll 4
        for (int m = m0; m < m1; ++m) {
          float u = up[(size_t)m*H_];
          a0 = fmaf(u, h_s[0][m], a0);
          a1 = fmaf(u, h_s[1][m], a1);
          a2 = fmaf(u, h_s[2][m], a2);
          a3 = fmaf(u, h_s[3][m], a3);
        }
        psum[g][0][e]=a0; psum[g][1][e]=a1; psum[g][2][e]=a2; psum[g][3][e]=a3;
      }
      __syncthreads();
      for (int w = tid; w < nn*H_; w += 1024) {
        int n = w / H_, e = w - n*H_;
        int pk = nodes[n]; int chain = pk >> 8, j = pk & 255;
        if (hasp_g[chain*T_+j]) {
          size_t cb = (size_t)chain*T_*H_;
          fh[cb + (size_t)j*H_ + e] = psum[0][n][e] + psum[1][n][e] + psum[2][n][e];
        }
      }
    }
    __syncthreads();
  }
}

// ---------------- serial tail: all nodes with depth >= TAILD (inline gates) ----------------
__global__ __launch_bounds__(320) void k_tail(const float* __restrict__ xg, const float* __restrict__ bhv,
    const float* __restrict__ uh1T, const int* __restrict__ cnt_g, const int* __restrict__ coff_g,
    const int* __restrict__ eidx_g, const float* __restrict__ ew_g, const int* __restrict__ hasp_g,
    const int* __restrict__ depth_g, const int* __restrict__ maxd_g,
    float* __restrict__ hout, float* __restrict__ chist, float* __restrict__ fh)
{
  int chain = blockIdx.x;
  if (maxd_g[chain] < TAILD) return;
  int tid = threadIdx.x;
  bool act = tid < H_;
  float bh0=0.f,bh1=0.f,bh2=0.f,bh3=0.f;
  if (act) { bh0=bhv[tid]; bh1=bhv[H_+tid]; bh2=bhv[2*H_+tid]; bh3=bhv[3*H_+tid]; }
  __shared__ float h_lds[H_];
  size_t cb = (size_t)chain*T_*H_, xb = (size_t)chain*T_*HG;
  const int* ei = eidx_g + chain*ECAP;
  const float* ewp = ew_g + chain*ECAP;
  for (int j = 0; j < T_; ++j) {
    if (depth_g[chain*T_+j] < TAILD) continue;
    if (act) {
      const float* xp = xg + xb + (size_t)j*HG;
      float x0 = xp[tid], x1 = xp[H_+tid], x2 = xp[2*H_+tid], x3 = xp[3*H_+tid];
      float acc = sigm(x0+bh0) * tanhf(x3+bh3);
      float og  = sigm(x2+bh2);
      float x1b = x1 + bh1;
      int c0 = coff_g[chain*T_+j], c1 = c0 + cnt_g[chain*T_+j];
      for (int k = c0; k < c1; ++k) {
        int t = ei[k];
        acc += ewp[k] * sigm(x1b + fh[cb + (size_t)t*H_ + tid]) * chist[cb + (size_t)t*H_ + tid];
      }
      chist[cb + (size_t)j*H_ + tid] = acc;
      float hv = og * tanhf(acc);
      hout[cb + (size_t)j*H_ + tid] = hv;
      h_lds[tid] = hv;
    }
    __syncthreads();
    if (hasp_g[chain*T_+j] && act) {
      float a = 0.f;
      const float* up = uh1T + tid;
      #pragma unroll 4
      for (int m = 0; m < H_; ++m) a = fmaf(up[(size_t)m*H_], h_lds[m], a);
      fh[cb + (size_t)j*H_ + tid] = a;
    }
    __syncthreads();
  }
}

// ---------------- split-bf16 MFMA GEMM v3: 2-deep register prefetch ----------------
template<int OUTBF, int NT>
__global__ __launch_bounds__(256) void k_gemm_bf(
    const ushort_t* __restrict__ Ah, const ushort_t* __restrict__ Al, int AS,
    const ushort_t* __restrict__ Wh, const ushort_t* __restrict__ Wl, int WS,
    const float* __restrict__ bias, float* __restrict__ C,
    ushort_t* __restrict__ Ch, ushort_t* __restrict__ Cl, int CS,
    int N, int act)
{
  __shared__ ushort_t sAh[128*32], sAl[128*32], sWh[128*32], sWl[128*32];  // 32 KB
  int tid = threadIdx.x;
  int bn = blockIdx.x * 128, bm = blockIdx.y * 128;
  int lane = tid & 63, wave = tid >> 6;
  int wr = (wave >> 1) * 64, wc = (wave & 1) * 64;
  int lrow = lane & 15, q = lane >> 4;

  int srow = tid >> 1, half = tid & 1;
  int ssw = (srow >> 1) & 3;
  int sg0 = ((2*half) ^ ssw) * 8, sg1 = ((2*half+1) ^ ssw) * 8;
  int sbase = srow * 32;
  const ushort_t* pAh = Ah + (size_t)(bm + srow)*AS + half*16;
  const ushort_t* pAl = Al + (size_t)(bm + srow)*AS + half*16;
  int wrow = bn + srow;
  int wsafe = (wrow < N) ? wrow : 0;
  const ushort_t* pWh = Wh + (size_t)wsafe*WS + half*16;
  const ushort_t* pWl = Wl + (size_t)wsafe*WS + half*16;

  // two named register staging sets (compile-time selected)
  bf16x8 aA0,aA1,aA2,aA3,aW0,aW1,aW2,aW3;   // set A
  bf16x8 bA0,bA1,bA2,bA3,bW0,bW1,bW2,bW3;   // set B

#define ISSUE_SET(P,t) { int kb = (t)*32; \
    P##A0 = *(const bf16x8*)(pAh + kb); P##A1 = *(const bf16x8*)(pAh + kb + 8); \
    P##A2 = *(const bf16x8*)(pAl + kb); P##A3 = *(const bf16x8*)(pAl + kb + 8); \
    P##W0 = *(const bf16x8*)(pWh + kb); P##W1 = *(const bf16x8*)(pWh + kb + 8); \
    P##W2 = *(const bf16x8*)(pWl + kb); P##W3 = *(const bf16x8*)(pWl + kb + 8); }
#define COMMIT_SET(P) { \
    *(bf16x8*)&sAh[sbase + sg0] = P##A0; *(bf16x8*)&sAh[sbase + sg1] = P##A1; \
    *(bf16x8*)&sAl[sbase + sg0] = P##A2; *(bf16x8*)&sAl[sbase + sg1] = P##A3; \
    *(bf16x8*)&sWh[sbase + sg0] = P##W0; *(bf16x8*)&sWh[sbase + sg1] = P##W1; \
    *(bf16x8*)&sWl[sbase + sg0] = P##W2; *(bf16x8*)&sWl[sbase + sg1] = P##W3; }

  f32x4 acc[4][4];
  #pragma unroll
  for (int m = 0; m < 4; ++m)
    #pragma unroll
    for (int n = 0; n < 4; ++n) acc[m][n] = (f32x4){0.f,0.f,0.f,0.f};

#define FRAG_MFMA() { \
    bf16x8 ah[4], al[4], bh[4], bl[4]; \
    _Pragma("unroll") \
    for (int m = 0; m < 4; ++m) { \
      int R = wr + m*16 + lrow; \
      int o = R*32 + ((q ^ ((R>>1)&3)) * 8); \
      ah[m] = *(const bf16x8*)&sAh[o]; \
      al[m] = *(const bf16x8*)&sAl[o]; \
    } \
    _Pragma("unroll") \
    for (int n = 0; n < 4; ++n) { \
      int R = wc + n*16 + lrow; \
      int o = R*32 + ((q ^ ((R>>1)&3)) * 8); \
      bh[n] = *(const bf16x8*)&sWh[o]; \
      bl[n] = *(const bf16x8*)&sWl[o]; \
    } \
    _Pragma("unroll") \
    for (int m = 0; m < 4; ++m) \
      _Pragma("unroll") \
      for (int n = 0; n < 4; ++n) { \
        acc[m][n] = __builtin_amdgcn_mfma_f32_16x16x32_bf16(ah[m], bh[n], acc[m][n], 0,0,0); \
        acc[m][n] = __builtin_amdgcn_mfma_f32_16x16x32_bf16(ah[m], bl[n], acc[m][n], 0,0,0); \
        acc[m][n] = __builtin_amdgcn_mfma_f32_16x16x32_bf16(al[m], bh[n], acc[m][n], 0,0,0); \
      } }

  ISSUE_SET(a, 0); COMMIT_SET(a);
  __syncthreads();
  if (NT > 1) ISSUE_SET(b, 1);
  #pragma unroll
  for (int t = 0; t < NT; t += 2) {
    // even iteration t: LDS holds tile t; set b holds tile t+1
    FRAG_MFMA();
    if (t+2 < NT) ISSUE_SET(a, t+2);
    __syncthreads();
    if (t+1 < NT) COMMIT_SET(b);
    __syncthreads();
    // odd iteration t+1: LDS holds tile t+1; set a holds tile t+2
    if (t+1 < NT) {
      FRAG_MFMA();
      if (t+3 < NT) ISSUE_SET(b, t+3);
      __syncthreads();
      if (t+2 < NT) COMMIT_SET(a);
      __syncthreads();
    }
  }
#undef ISSUE_SET
#undef COMMIT_SET
#undef FRAG_MFMA

  #pragma unroll
  for (int m = 0; m < 4; ++m) {
    int row0 = bm + wr + m*16 + (lane >> 4)*4;
    #pragma unroll
    for (int n = 0; n < 4; ++n) {
      int col = bn + wc + n*16 + lrow;
      if (OUTBF) {
        if (col < CS) {
          float bv = (col < N) ? bias[col] : 0.f;
          #pragma unroll
          for (int r = 0; r < 4; ++r) {
            float v = 0.f;
            if (col < N) { v = acc[m][n][r] + bv; if (act) v = fmaxf(v, 0.f); }
            ushort_t h = f2bf(v);
            Ch[(size_t)(row0 + r)*CS + col] = h;
            Cl[(size_t)(row0 + r)*CS + col] = f2bf(v - bf2f(h));
          }
        }
      } else {
        if (col < N) {
          float bv = bias[col];
          #pragma unroll
          for (int r = 0; r < 4; ++r) {
            float v = acc[m][n][r] + bv;
            if (act) v = fmaxf(v, 0.f);
            C[(size_t)(row0 + r)*N + col] = v;
          }
        }
      }
    }
  }
}

// ---------------- fused MFMA attention v2: bf16 pre-split inputs (round-13) ----------------
__global__ __launch_bounds__(256) void k_attn_mfma(
    const ushort_t* __restrict__ HH, const ushort_t* __restrict__ HL,
    const int* __restrict__ plen, const int* __restrict__ hlen,
    float* __restrict__ ATT)
{
  __shared__ float regA_f[12800];
  __shared__ ushort_t pbuf[2*64*136];
  ushort_t* regA = (ushort_t*)regA_f;

  int tid = threadIdx.x;
  int lane = tid & 63, wave = tid >> 6;
  int lrow = lane & 15, koff = (lane >> 4) * 8;
  int d = blockIdx.x, b = blockIdx.y, q0 = blockIdx.z * 64;
  int qbase = (d*B_ + b)*T_ + q0;
  int kbase = ((1-d)*B_ + b)*T_;
  float* outp = ATT + ((size_t)(d*B_ + b)*T_ + q0) * H_;
  int klen = (d == 0) ? hlen[b] : plen[b];

  ushort_t* sQh = regA;            // [64][40]
  ushort_t* sQl = regA + 2560;
  ushort_t* sKh = regA + 5120;     // [128][40]
  ushort_t* sKl = regA + 10240;
  int qrow = tid >> 2, qo = (tid & 3) * 8;
  int krow = tid >> 1, ko = (tid & 1) * 16;
  const ushort_t* Qh = HH + (size_t)(qbase + qrow)*320 + qo;
  const ushort_t* Ql = HL + (size_t)(qbase + qrow)*320 + qo;
  const ushort_t* Kh = HH + (size_t)(kbase + krow)*320 + ko;
  const ushort_t* Kl = HL + (size_t)(kbase + krow)*320 + ko;

  bf16x8 rqh, rql, rkh0, rkh1, rkl0, rkl1;
  auto issue1 = [&](int t){
    int kb = t*32;
    rqh  = *(const bf16x8*)(Qh + kb);
    rql  = *(const bf16x8*)(Ql + kb);
    rkh0 = *(const bf16x8*)(Kh + kb); rkh1 = *(const bf16x8*)(Kh + kb + 8);
    rkl0 = *(const bf16x8*)(Kl + kb); rkl1 = *(const bf16x8*)(Kl + kb + 8);
  };
  auto commit1 = [&](){
    *(bf16x8*)&sQh[qrow*40 + qo] = rqh;
    *(bf16x8*)&sQl[qrow*40 + qo] = rql;
    *(bf16x8*)&sKh[krow*40 + ko] = rkh0; *(bf16x8*)&sKh[krow*40 + ko + 8] = rkh1;
    *(bf16x8*)&sKl[krow*40 + ko] = rkl0; *(bf16x8*)&sKl[krow*40 + ko + 8] = rkl1;
  };

  f32x4 acc1[4][2];
  #pragma unroll
  for (int m = 0; m < 4; ++m)
    #pragma unroll
    for (int n = 0; n < 2; ++n) acc1[m][n] = (f32x4){0.f,0.f,0.f,0.f};
  int wc = wave * 32;

  issue1(0); commit1();
  __syncthreads();
  for (int t = 0; t < 10; ++t) {
    bool more = (t < 9);
    bf16x8 ah[4], al[4], bh[2], bl[2];
    #pragma unroll
    for (int m = 0; m < 4; ++m) {
      int o = (m*16 + lrow)*40 + koff;
      ah[m] = *(const bf16x8*)&sQh[o];
      al[m] = *(const bf16x8*)&sQl[o];
    }
    #pragma unroll
    for (int n = 0; n < 2; ++n) {
      int o = (wc + n*16 + lrow)*40 + koff;
      bh[n] = *(const bf16x8*)&sKh[o];
      bl[n] = *(const bf16x8*)&sKl[o];
    }
    if (more) issue1(t+1);
    __syncthreads();
    if (more) commit1();
    #pragma unroll
    for (int m = 0; m < 4; ++m)
      #pragma unroll
      for (int n = 0; n < 2; ++n) {
        acc1[m][n] = __builtin_amdgcn_mfma_f32_16x16x32_bf16(ah[m], bh[n], acc1[m][n], 0,0,0);
        acc1[m][n] = __builtin_amdgcn_mfma_f32_16x16x32_bf16(ah[m], bl[n], acc1[m][n], 0,0,0);
        acc1[m][n] = __builtin_amdgcn_mfma_f32_16x16x32_bf16(al[m], bh[n], acc1[m][n], 0,0,0);
      }
    __syncthreads();
  }
  float* sim = regA_f;
  #pragma unroll
  for (int m = 0; m < 4; ++m)
    #pragma unroll
    for (int n = 0; n < 2; ++n)
      #pragma unroll
      for (int r = 0; r < 4; ++r)
        sim[(m*16 + (lane>>4)*4 + r)*132 + wc + n*16 + lrow] = acc1[m][n][r];
  __syncthreads();

  {
    int row = tid >> 2, qtr = (tid & 3) * 32;
    const float* sr = sim + row*132;
    float mx = NEGV;
    for (int c = 0; c < 32; ++c) { int cg = qtr + c; float s = (cg < klen) ? sr[cg] : NEGV; mx = fmaxf(mx, s); }
    mx = fmaxf(mx, __shfl_xor(mx, 1));
    mx = fmaxf(mx, __shfl_xor(mx, 2));
    float sum = 0.f;
    for (int c = 0; c < 32; ++c) { int cg = qtr + c; if (cg < klen) sum += expf(sr[cg] - mx); }
    sum += __shfl_xor(sum, 1);
    sum += __shfl_xor(sum, 2);
    float rinv = 1.f / sum;
    for (int c = 0; c < 32; ++c) {
      int cg = qtr + c;
      float p = (cg < klen) ? expf(sr[cg] - mx) * rinv : 0.f;
      ushort_t h = f2bf(p);
      pbuf[row*136 + cg] = h;
      pbuf[64*136 + row*136 + cg] = f2bf(p - bf2f(h));
    }
  }
  __syncthreads();

  ushort_t* kth = regA;            // [320][40]
  ushort_t* ktl = regA + 12800;
  int wr2 = (wave & 1) * 32;
  int wcf = (wave >> 1) * 160;
  f32x4 acc3[2][10];
  #pragma unroll
  for (int m = 0; m < 2; ++m)
    #pragma unroll
    for (int n = 0; n < 10; ++n) acc3[m][n] = (f32x4){0.f,0.f,0.f,0.f};
  int skey = tid >> 3, sf8 = tid & 7;

  for (int kc = 0; kc < 4; ++kc) {
    __syncthreads();
    int key = kbase + kc*32 + skey;
    const ushort_t* krh = HH + (size_t)key*320;
    const ushort_t* krl = HL + (size_t)key*320;
    for (int f8 = sf8; f8 < 40; f8 += 8) {
      bf16x8 vh = *(const bf16x8*)(krh + f8*8);
      bf16x8 vl = *(const bf16x8*)(krl + f8*8);
      #pragma unroll
      for (int i = 0; i < 8; ++i) {
        int feat = f8*8 + i;
        kth[feat*40 + skey] = (ushort_t)vh[i];
        ktl[feat*40 + skey] = (ushort_t)vl[i];
      }
    }
    __syncthreads();
    bf16x8 ph[2], pl[2], kh[10], kl[10];
    #pragma unroll
    for (int m = 0; m < 2; ++m) {
      int o = (wr2 + m*16 + lrow)*136 + kc*32 + koff;
      ph[m] = *(const bf16x8*)&pbuf[o];
      pl[m] = *(const bf16x8*)&pbuf[64*136 + o];
    }
    #pragma unroll
    for (int n = 0; n < 10; ++n) {
      int o = (wcf + n*16 + lrow)*40 + koff;
      kh[n] = *(const bf16x8*)&kth[o];
      kl[n] = *(const bf16x8*)&ktl[o];
    }
    #pragma unroll
    for (int m = 0; m < 2; ++m)
      #pragma unroll
      for (int n = 0; n < 10; ++n) {
        acc3[m][n] = __builtin_amdgcn_mfma_f32_16x16x32_bf16(ph[m], kh[n], acc3[m][n], 0,0,0);
        acc3[m][n] = __builtin_amdgcn_mfma_f32_16x16x32_bf16(ph[m], kl[n], acc3[m][n], 0,0,0);
        acc3[m][n] = __builtin_amdgcn_mfma_f32_16x16x32_bf16(pl[m], kh[n], acc3[m][n], 0,0,0);
      }
  }
  #pragma unroll
  for (int m = 0; m < 2; ++m) {
    int row0 = wr2 + m*16 + (lane >> 4)*4;
    #pragma unroll
    for (int n = 0; n < 10; ++n) {
      int col = wcf + n*16 + lrow;
      if (col < H_) {
        #pragma unroll
        for (int r = 0; r < 4; ++r)
          outp[(size_t)(row0 + r)*H_ + col] = acc3[m][n][r];
      }
    }
  }
}

// ---------------- pool stage 1 ----------------
__global__ __launch_bounds__(320) void k_pool(const float* __restrict__ H,
    const int* __restrict__ plen, const int* __restrict__ hlen,
    float* __restrict__ psum, float* __restrict__ pmax)
{
  int chain = blockIdx.x; int s = chain >> 5, b = chain & 31;
  int c = blockIdx.y; int t0 = c * 16;
  int len = (s == 0 ? plen[b] : hlen[b]);
  int tid = threadIdx.x;
  __shared__ float buf[16*H_];
  const float* hp = H + (size_t)chain*T_*H_ + (size_t)t0*H_;
  for (int i = tid; i < 16*H_; i += 320) buf[i] = hp[i];
  __syncthreads();
  if (tid < H_) {
    int tmax = len - t0; if (tmax > 16) tmax = 16;
    float sum = 0.f, mx = NEGV;
    for (int t = 0; t < tmax; ++t) { float x = buf[t*H_ + tid]; sum += x; mx = fmaxf(mx, x); }
    int o = (chain*8 + c)*H_ + tid;
    psum[o] = sum; pmax[o] = mx;
  }
}

// ---------------- pool stage 2 + classifier ----------------
__global__ __launch_bounds__(320) void k_classify(
    const float* __restrict__ psum, const float* __restrict__ pmax,
    const int* __restrict__ plen, const int* __restrict__ hlen,
    const float* __restrict__ w1t, const float* __restrict__ b1,
    const float* __restrict__ w2, const float* __restrict__ b2,
    float* __restrict__ out)
{
  int b = blockIdx.x;
  int tid = threadIdx.x;
  __shared__ float v[HG];
  __shared__ float hid[H_];
  for (int s = 0; s < 2; ++s) {
    int chain = s*B_ + b;
    int len = (s == 0 ? plen[b] : hlen[b]);
    if (tid < H_) {
      float sum = 0.f, mx = NEGV;
      #pragma unroll
      for (int c = 0; c < 8; ++c) {
        int o = (chain*8 + c)*H_ + tid;
        sum += psum[o]; mx = fmaxf(mx, pmax[o]);
      }
      v[s*600 + tid]       = sum / (float)len;
      v[s*600 + 300 + tid] = mx;
    }
  }
  __syncthreads();
  if (tid < H_) {
    float a0 = b1[tid], a1 = 0.f, a2 = 0.f, a3 = 0.f;
    for (int m = 0; m < HG; m += 4) {
      a0 = fmaf(v[m+0], w1t[(size_t)(m+0)*H_ + tid], a0);
      a1 = fmaf(v[m+1], w1t[(size_t)(m+1)*H_ + tid], a1);
      a2 = fmaf(v[m+2], w1t[(size_t)(m+2)*H_ + tid], a2);
      a3 = fmaf(v[m+3], w1t[(size_t)(m+3)*H_ + tid], a3);
    }
    hid[tid] = tanhf(a0 + a1 + a2 + a3);
  }
  __syncthreads();
  if (tid < 3) {
    float a = b2[tid];
    const float* wr = w2 + (size_t)tid*H_;
    for (int n = 0; n < H_; ++n) a = fmaf(hid[n], wr[n], a);
    out[b*3 + tid] = a;
  }
}

// ---------------- launch ----------------
extern "C" void kernel_launch(void* const* d_in, const int* in_sizes, int n_in,
                              void* d_out, int out_size, void* d_ws, size_t ws_size,
                              hipStream_t stream) {
  const int*   prem    = (const int*)d_in[0];
  const int*   plen    = (const int*)d_in[1];
  const int*   hyp     = (const int*)d_in[2];
  const int*   hlen    = (const int*)d_in[3];
  const float* lg      = (const float*)d_in[4];
  const float* rg      = (const float*)d_in[5];
  const float* emb     = (const float*)d_in[6];
  const float* enc_wx  = (const float*)d_in[7];
  const float* enc_bx  = (const float*)d_in[8];
  const float* enc_uh  = (const float*)d_in[9];
  const float* enc_bh  = (const float*)d_in[10];
  const float* comp_wx = (const float*)d_in[11];
  const float* comp_bx = (const float*)d_in[12];
  const float* comp_uh = (const float*)d_in[13];
  const float* comp_bh = (const float*)d_in[14];
  const float* proj_w  = (const float*)d_in[15];
  const float* proj_b  = (const float*)d_in[16];
  const float* cls_w1  = (const float*)d_in[17];
  const float* cls_b1  = (const float*)d_in[18];
  const float* cls_w2  = (const float*)d_in[19];
  const float* cls_b2  = (const float*)d_in[20];
  float* outp = (float*)d_out;

  // workspace layout (floats); ENH bf16 aliases XG; PROJ/H-split bf16 alias EH/EL
  float* XG  = (float*)d_ws;                       // 9,830,400 f
  ushort_t* EH = (ushort_t*)(XG + 9830400);        // [8192][320] hi (emb -> h-split -> PROJ)
  ushort_t* EL = EH + 2621440;                     // [8192][320] lo
  float* H1  = XG + 9830400 + 2621440;
  float* CH  = H1 + 2457600;                       // ATT alias
  float* FH  = CH + 2457600;
  float* UTE = FH + 2457600;
  float* UTC = UTE + 90000;
  float* W1T = UTC + 90000;
  ushort_t* WencH  = (ushort_t*)(W1T + 360000);
  ushort_t* WencL  = WencH + 384000;
  ushort_t* WcompH = WencL + 384000;
  ushort_t* WcompL = WcompH + 384000;
  ushort_t* WPH    = WcompL + 384000;
  ushort_t* WPL    = WPH + 278400;
  float* PSUM = W1T + 360000 + 1046400;
  float* PMAX = PSUM + 153600;
  float* EW   = PMAX + 153600;
  int* EIDX   = (int*)(EW + 64*ECAP);
  int* CNT    = EIDX + 64*ECAP;
  int* COFF   = CNT + 64*T_;
  int* DEPTH  = COFF + 64*T_;
  int* HASP   = DEPTH + 64*T_;
  int* MAXD   = HASP + 64*T_;
  int* LVLCNT = MAXD + 64;
  int* WL     = LVLCNT + TAILD;
  float* ATT  = CH;
  ushort_t* ENH_H = (ushort_t*)XG;                 // [8192][928] hi (after enc scan, XG dead)
  ushort_t* ENH_L = ENH_H + 7602176;

  hipMemsetAsync(LVLCNT, 0, TAILD*sizeof(int), stream);
  // 1. weight prep + graph analysis + embedding split
  k_prep_all<<<(1496400 + 255)/256, 256, 0, stream>>>(enc_uh, comp_uh, enc_wx, comp_wx, proj_w, cls_w1,
      UTE, UTC, W1T, WencH, WencL, WcompH, WcompL, WPH, WPL);
  k_build<<<64, 256, 0, stream>>>(lg, rg, CNT, COFF, EIDX, EW, HASP, DEPTH, MAXD, LVLCNT, WL);
  k_embed_split<<<10240, 256, 0, stream>>>(prem, hyp, emb, EH, EL);
  // 2. enc xg = emb @ enc_wx^T + enc_bx
  k_gemm_bf<0,10><<<dim3(10, 64), 256, 0, stream>>>(EH, EL, 320, WencH, WencL, 320,
      enc_bx, XG, nullptr, nullptr, 0, HG, 0);
  // 3. enc tree scan (levels 0..3 parallel, depth>=4 serial tail)
  for (int L = 0; L < TAILD; ++L)
    k_level<<<640, 1024, 0, stream>>>(XG, enc_bh, UTE, CNT, COFF, EIDX, EW, HASP, LVLCNT, WL, L, H1, CH, FH);
  k_tail<<<64, 320, 0, stream>>>(XG, enc_bh, UTE, CNT, COFF, EIDX, EW, HASP, DEPTH, MAXD, H1, CH, FH);
  // 4. h-split + attention (CH dead -> ATT)
  k_h_split<<<10240, 256, 0, stream>>>(H1, EH, EL);
  k_attn_mfma<<<dim3(2, B_, 2), 256, 0, stream>>>(EH, EL, plen, hlen, ATT);
  // 5. enhance split (enc-xg dead), proj GEMM -> PROJ bf16 hi/lo (overwrites EH/EL)
  k_enh_split<<<29696, 256, 0, stream>>>(H1, ATT, ENH_H, ENH_L);
  k_gemm_bf<1,29><<<dim3(3, 64), 256, 0, stream>>>(ENH_H, ENH_L, 928, WPH, WPL, 928,
      proj_b, nullptr, EH, EL, 320, H_, 1);
  // 6. comp xg = proj @ comp_wx^T + comp_bx (overwrites XG)
  k_gemm_bf<0,10><<<dim3(10, 64), 256, 0, stream>>>(EH, EL, 320, WcompH, WcompL, 320,
      comp_bx, XG, nullptr, nullptr, 0, HG, 0);
  // 7. comp tree scan
  for (int L = 0; L < TAILD; ++L)
    k_level<<<640, 1024, 0, stream>>>(XG, comp_bh, UTC, CNT, COFF, EIDX, EW, HASP, LVLCNT, WL, L, H1, CH, FH);
  k_tail<<<64, 320, 0, stream>>>(XG, comp_bh, UTC, CNT, COFF, EIDX, EW, HASP, DEPTH, MAXD, H1, CH, FH);
  // 8. pool + classifier
  k_pool<<<dim3(64, 8), 320, 0, stream>>>(H1, plen, hlen, PSUM, PMAX);
  k_classify<<<B_, 320, 0, stream>>>(PSUM, PMAX, plen, hlen, W1T, cls_b1, cls_w2, cls_b2, outp);
}

// Round 17
// 482.376 us; speedup vs baseline: 1.1612x; 1.0208x over previous
//
#include <hip/hip_runtime.h>
#include <math.h>

#define B_ 32
#define T_ 128
#define H_ 300
#define HG 1200   // 4*H
#define TAILD 4   // levels >= TAILD handled by serial per-chain tail
#define WLCAP 8192
#define ECAP 2048
#define NEGV -10000000.0f

typedef __attribute__((ext_vector_type(8))) short bf16x8;
typedef __attribute__((ext_vector_type(4))) float f32x4;
typedef unsigned short ushort_t;

__device__ __forceinline__ float sigm(float x){ return 1.f/(1.f+expf(-x)); }

__device__ __forceinline__ unsigned short f2bf(float x){
  union { float f; unsigned int u; } c; c.f = x;
  unsigned int u = c.u;
  return (unsigned short)((u + 0x7fffu + ((u >> 16) & 1u)) >> 16);
}
__device__ __forceinline__ float bf2f(unsigned short h){
  union { unsigned int u; float f; } c; c.u = ((unsigned int)h) << 16;
  return c.f;
}

// ---------------- fused weight prep: fp32 transposes + bf16 hi/lo padded weights ----------------
__global__ __launch_bounds__(256) void k_prep_all(
    const float* __restrict__ enc_uh, const float* __restrict__ comp_uh,
    const float* __restrict__ enc_wx, const float* __restrict__ comp_wx,
    const float* __restrict__ pw, const float* __restrict__ cw1,
    float* __restrict__ te, float* __restrict__ tc, float* __restrict__ w1t,
    ushort_t* __restrict__ WencH, ushort_t* __restrict__ WencL,
    ushort_t* __restrict__ WcompH, ushort_t* __restrict__ WcompL,
    ushort_t* __restrict__ WPH, ushort_t* __restrict__ WPL)
{
  int i = blockIdx.x*256 + threadIdx.x;
  if (i < 90000) {                       // uh1 transposes: te/tc[m][k] = uh[1][k][m]
    int m = i / H_, k = i - m*H_;
    te[i] = enc_uh[H_*H_ + (size_t)k*H_ + m];
    tc[i] = comp_uh[H_*H_ + (size_t)k*H_ + m];
  } else if (i < 450000) {               // w1t (1200 x 300): w1t[m][k] = cw1[k][m]
    int i2 = i - 90000;
    int m = i2 / H_, k = i2 - m*H_;
    w1t[i2] = cw1[(size_t)k*HG + m];
  } else if (i < 834000) {               // Wenc hi/lo [1200][320], zero-padded
    int i2 = i - 450000;
    int n = i2 / 320, k = i2 - n*320;
    float v = (k < 300) ? enc_wx[(size_t)n*300 + k] : 0.f;
    ushort_t h = f2bf(v);
    WencH[i2] = h; WencL[i2] = f2bf(v - bf2f(h));
  } else if (i < 1218000) {              // Wcomp hi/lo [1200][320]
    int i2 = i - 834000;
    int n = i2 / 320, k = i2 - n*320;
    float v = (k < 300) ? comp_wx[(size_t)n*300 + k] : 0.f;
    ushort_t h = f2bf(v);
    WcompH[i2] = h; WcompL[i2] = f2bf(v - bf2f(h));
  } else if (i < 1496400) {              // folded proj W hi/lo [300][928]
    int i2 = i - 1218000;
    int n = i2 / 928, k = i2 - n*928;
    const float* r = pw + (size_t)n*HG;
    float v = 0.f;
    if (k < 300)      v = r[k] + r[600+k];
    else if (k < 600) v = r[k] - r[k+300];
    else if (k < 900) v = r[k+300];
    ushort_t h = f2bf(v);
    WPH[i2] = h; WPL[i2] = f2bf(v - bf2f(h));
  }
}

// ---------------- embedding gather + bf16 split: [8192][320] hi/lo ----------------
__global__ __launch_bounds__(256) void k_embed_split(const int* __restrict__ prem, const int* __restrict__ hyp,
    const float* __restrict__ emb, ushort_t* __restrict__ EH, ushort_t* __restrict__ EL)
{
  int i = blockIdx.x*256 + threadIdx.x;      // over 8192*320
  int bt = i / 320, k = i - bt*320;
  int side = bt >> 12, bt2 = bt & 4095;
  float v = 0.f;
  if (k < 300) {
    int tok = (side == 0 ? prem : hyp)[bt2];
    v = emb[(size_t)tok*H_ + k];
  }
  ushort_t h = f2bf(v);
  EH[i] = h; EL[i] = f2bf(v - bf2f(h));
}

// ---------------- H1 -> bf16 hi/lo split: [8192][320] (aliases dead EH/EL) ----------------
__global__ __launch_bounds__(256) void k_h_split(const float* __restrict__ H1,
    ushort_t* __restrict__ HH, ushort_t* __restrict__ HL)
{
  int i = blockIdx.x*256 + threadIdx.x;      // over 8192*320
  int r = i / 320, k = i - r*320;
  float v = (k < 300) ? H1[(size_t)r*H_ + k] : 0.f;
  ushort_t h = f2bf(v);
  HH[i] = h; HL[i] = f2bf(v - bf2f(h));
}

// ---------------- enhance + bf16 split: A=[H1|ATT|H1*ATT] -> [8192][928] hi/lo ----------------
__global__ __launch_bounds__(256) void k_enh_split(const float* __restrict__ H1, const float* __restrict__ ATT,
    ushort_t* __restrict__ AH, ushort_t* __restrict__ AL)
{
  int i = blockIdx.x*256 + threadIdx.x;      // over 8192*928
  int r = i / 928, k = i - r*928;
  float v = 0.f;
  if (k < 300)      v = H1[(size_t)r*H_ + k];
  else if (k < 600) v = ATT[(size_t)r*H_ + k - 300];
  else if (k < 900) { int kk = k - 600; v = H1[(size_t)r*H_ + kk] * ATT[(size_t)r*H_ + kk]; }
  ushort_t h = f2bf(v);
  AH[i] = h; AL[i] = f2bf(v - bf2f(h));
}

// ---------------- graph analysis v4: parented-first worklists + compact deep-node lists ----------------
__global__ __launch_bounds__(256) void k_build(const float* __restrict__ lg, const float* __restrict__ rg,
    int* __restrict__ cnt_g, int* __restrict__ coff_g, int* __restrict__ eidx_g, float* __restrict__ ew_g,
    int* __restrict__ hasp_g, int* __restrict__ depth_g,
    int* __restrict__ lvlcnt_g, int* __restrict__ wl_g,
    int* __restrict__ dcnt_g, int* __restrict__ dlist_g)
{
  int chain = blockIdx.x; int s = chain >> 5, b = chain & 31;
  const float* graph = (s ? rg : lg) + (size_t)b*T_*T_;
  int tid = threadIdx.x;
  __shared__ float gbuf[T_*T_];            // 64 KB
  __shared__ int cnt[T_], coff[T_], depth[T_], hasp[T_];
  __shared__ short eidx[ECAP];
  __shared__ float ew[ECAP];
  __shared__ int lcnt[TAILD], lbase[TAILD], lppos[TAILD], lnpos[TAILD];
  __shared__ int etot_s;

  #pragma unroll
  for (int k = 0; k < 16; ++k)
    ((float4*)gbuf)[tid + k*256] = ((const float4*)graph)[tid + k*256];
  if (tid < T_) hasp[tid] = 0;
  if (tid < TAILD) { lcnt[tid] = 0; lppos[tid] = 0; lnpos[tid] = 0; }
  __syncthreads();
  if (tid < T_) {
    int j = tid, c = 0;
    const float* gr = gbuf + j*T_;
    for (int t = 0; t < j; ++t) c += (gr[t] != 0.f) ? 1 : 0;
    cnt[j] = c;
  }
  __syncthreads();
  if (tid == 0) { int a = 0; for (int j = 0; j < T_; ++j) { coff[j] = a; a += cnt[j]; } etot_s = a; }
  __syncthreads();
  if (tid < T_) {
    int j = tid, p = coff[j];
    const float* gr = gbuf + j*T_;
    for (int t = 0; t < j; ++t) {
      float g = gr[t];
      if (g != 0.f && p < ECAP) { eidx[p] = (short)t; ew[p] = g; hasp[t] = 1; ++p; }
    }
  }
  __syncthreads();
  if (tid == 0) {
    int md = 0, dc = 0;
    for (int j = 0; j < T_; ++j) {
      int d = 0, e0 = coff[j], e1 = coff[j] + cnt[j];
      if (e1 > ECAP) e1 = ECAP;
      for (int k = e0; k < e1; ++k) { int dd = depth[eidx[k]] + 1; d = dd > d ? dd : d; }
      depth[j] = d; md = d > md ? d : md;
      if (d >= TAILD) dlist_g[chain*T_ + dc++] = j;   // compact deep list (position order)
    }
    dcnt_g[chain] = dc;
  }
  __syncthreads();
  if (tid < T_) { int L = depth[tid]; if (L < TAILD) atomicAdd(&lcnt[L], 1); }
  __syncthreads();
  if (tid < TAILD && lcnt[tid] > 0) lbase[tid] = atomicAdd(&lvlcnt_g[tid], lcnt[tid]);
  __syncthreads();
  // fill worklist chunk: parented nodes from the front, unparented from the back
  if (tid < T_) {
    int L = depth[tid];
    if (L < TAILD) {
      int pos;
      if (hasp[tid]) { int p = atomicAdd(&lppos[L], 1); pos = p; }
      else           { int p = atomicAdd(&lnpos[L], 1); pos = lcnt[L] - 1 - p; }
      wl_g[L*WLCAP + lbase[L] + pos] = (chain << 8) | tid;
    }
  }
  int base = chain * T_;
  if (tid < T_) {
    cnt_g[base+tid] = cnt[tid]; coff_g[base+tid] = coff[tid];
    hasp_g[base+tid] = hasp[tid]; depth_g[base+tid] = depth[tid];
  }
  int etot = etot_s; if (etot > ECAP) etot = ECAP;
  for (int i = tid; i < etot; i += 256) { eidx_g[chain*ECAP + i] = eidx[i]; ew_g[chain*ECAP + i] = ew[i]; }
}

// ---------------- per-level tree-LSTM (round-10 proven: 4 nodes/block, scalar matvec) ----------------
__global__ __launch_bounds__(1024) void k_level(
    const float* __restrict__ xg, const float* __restrict__ bhv, const float* __restrict__ uh1T,
    const int* __restrict__ cnt_g, const int* __restrict__ coff_g,
    const int* __restrict__ eidx_g, const float* __restrict__ ew_g,
    const int* __restrict__ hasp_g, const int* __restrict__ lvlcnt_g, const int* __restrict__ wl_g,
    int L, float* __restrict__ hout, float* __restrict__ chist, float* __restrict__ fh)
{
  int count = lvlcnt_g[L];
  int nblk = (count + 3) >> 2;
  int tid = threadIdx.x;
  __shared__ float h_s[4][H_];
  __shared__ float psum[3][4][H_];
  __shared__ int nodes[4];
  __shared__ int anyp;
  for (int blk = blockIdx.x; blk < nblk; blk += gridDim.x) {
    int base = blk * 4;
    int nn = count - base; if (nn > 4) nn = 4;
    if (tid == 0) anyp = 0;
    __syncthreads();
    if (tid < 4) {
      int pk = (tid < nn) ? wl_g[L*WLCAP + base + tid] : -1;
      nodes[tid] = pk;
      if (pk >= 0 && hasp_g[(pk >> 8)*T_ + (pk & 255)]) atomicAdd(&anyp, 1);
    }
    __syncthreads();
    for (int w = tid; w < nn*H_; w += 1024) {
      int n = w / H_, e = w - n*H_;
      int pk = nodes[n]; int chain = pk >> 8, j = pk & 255;
      size_t cb = (size_t)chain*T_*H_, xb = (size_t)chain*T_*HG;
      const float* xp = xg + xb + (size_t)j*HG;
      float x0 = xp[e], x1 = xp[H_+e], x2 = xp[2*H_+e], x3 = xp[3*H_+e];
      float iu  = sigm(x0 + bhv[e]) * tanhf(x3 + bhv[3*H_+e]);
      float og  = sigm(x2 + bhv[2*H_+e]);
      float x1b = x1 + bhv[H_+e];
      float acc = iu;
      int c0 = coff_g[chain*T_+j], c1 = c0 + cnt_g[chain*T_+j];
      const int* ei = eidx_g + chain*ECAP;
      const float* ewp = ew_g + chain*ECAP;
      for (int k = c0; k < c1; ++k) {
        int t = ei[k];
        acc += ewp[k] * sigm(x1b + fh[cb + (size_t)t*H_ + e]) * chist[cb + (size_t)t*H_ + e];
      }
      chist[cb + (size_t)j*H_ + e] = acc;
      float hv = og * tanhf(acc);
      hout[cb + (size_t)j*H_ + e] = hv;
      h_s[n][e] = hv;
    }
    __syncthreads();
    if (anyp > 0) {
      if (tid < 3*H_) {
        int g = tid / H_, e = tid - g*H_;
        float a0=0.f, a1=0.f, a2=0.f, a3=0.f;
        const float* up = uh1T + e;
        int m0 = g*100, m1 = m0 + 100;
        #pragma unroll 4
        for (int m = m0; m < m1; ++m) {
          float u = up[(size_t)m*H_];
          a0 = fmaf(u, h_s[0][m], a0);
          a1 = fmaf(u, h_s[1][m], a1);
          a2 = fmaf(u, h_s[2][m], a2);
          a3 = fmaf(u, h_s[3][m], a3);
        }
        psum[g][0][e]=a0; psum[g][1][e]=a1; psum[g][2][e]=a2; psum[g][3][e]=a3;
      }
      __syncthreads();
      for (int w = tid; w < nn*H_; w += 1024) {
        int n = w / H_, e = w - n*H_;
        int pk = nodes[n]; int chain = pk >> 8, j = pk & 255;
        if (hasp_g[chain*T_+j]) {
          size_t cb = (size_t)chain*T_*H_;
          fh[cb + (size_t)j*H_ + e] = psum[0][n][e] + psum[1][n][e] + psum[2][n][e];
        }
      }
    }
    __syncthreads();
  }
}

// ---------------- serial tail v2: compact deep-node list (inline gates) ----------------
__global__ __launch_bounds__(320) void k_tail(const float* __restrict__ xg, const float* __restrict__ bhv,
    const float* __restrict__ uh1T, const int* __restrict__ cnt_g, const int* __restrict__ coff_g,
    const int* __restrict__ eidx_g, const float* __restrict__ ew_g, const int* __restrict__ hasp_g,
    const int* __restrict__ dcnt_g, const int* __restrict__ dlist_g,
    float* __restrict__ hout, float* __restrict__ chist, float* __restrict__ fh)
{
  int chain = blockIdx.x;
  int dc = dcnt_g[chain];
  if (dc == 0) return;
  int tid = threadIdx.x;
  bool act = tid < H_;
  float bh0=0.f,bh1=0.f,bh2=0.f,bh3=0.f;
  if (act) { bh0=bhv[tid]; bh1=bhv[H_+tid]; bh2=bhv[2*H_+tid]; bh3=bhv[3*H_+tid]; }
  __shared__ float h_lds[H_];
  __shared__ int djs[T_];
  if (tid < dc) djs[tid] = dlist_g[chain*T_ + tid];
  __syncthreads();
  size_t cb = (size_t)chain*T_*H_, xb = (size_t)chain*T_*HG;
  const int* ei = eidx_g + chain*ECAP;
  const float* ewp = ew_g + chain*ECAP;
  for (int di = 0; di < dc; ++di) {
    int j = djs[di];
    if (act) {
      const float* xp = xg + xb + (size_t)j*HG;
      float x0 = xp[tid], x1 = xp[H_+tid], x2 = xp[2*H_+tid], x3 = xp[3*H_+tid];
      float acc = sigm(x0+bh0) * tanhf(x3+bh3);
      float og  = sigm(x2+bh2);
      float x1b = x1 + bh1;
      int c0 = coff_g[chain*T_+j], c1 = c0 + cnt_g[chain*T_+j];
      for (int k = c0; k < c1; ++k) {
        int t = ei[k];
        acc += ewp[k] * sigm(x1b + fh[cb + (size_t)t*H_ + tid]) * chist[cb + (size_t)t*H_ + tid];
      }
      chist[cb + (size_t)j*H_ + tid] = acc;
      float hv = og * tanhf(acc);
      hout[cb + (size_t)j*H_ + tid] = hv;
      h_lds[tid] = hv;
    }
    __syncthreads();
    if (hasp_g[chain*T_+j] && act) {
      float a = 0.f;
      const float* up = uh1T + tid;
      #pragma unroll 4
      for (int m = 0; m < H_; ++m) a = fmaf(up[(size_t)m*H_], h_lds[m], a);
      fh[cb + (size_t)j*H_ + tid] = a;
    }
    __syncthreads();
  }
}

// ---------------- split-bf16 MFMA GEMM v3: 2-deep register prefetch (round-16 proven) ----------------
template<int OUTBF, int NT>
__global__ __launch_bounds__(256) void k_gemm_bf(
    const ushort_t* __restrict__ Ah, const ushort_t* __restrict__ Al, int AS,
    const ushort_t* __restrict__ Wh, const ushort_t* __restrict__ Wl, int WS,
    const float* __restrict__ bias, float* __restrict__ C,
    ushort_t* __restrict__ Ch, ushort_t* __restrict__ Cl, int CS,
    int N, int act)
{
  __shared__ ushort_t sAh[128*32], sAl[128*32], sWh[128*32], sWl[128*32];  // 32 KB
  int tid = threadIdx.x;
  int bn = blockIdx.x * 128, bm = blockIdx.y * 128;
  int lane = tid & 63, wave = tid >> 6;
  int wr = (wave >> 1) * 64, wc = (wave & 1) * 64;
  int lrow = lane & 15, q = lane >> 4;

  int srow = tid >> 1, half = tid & 1;
  int ssw = (srow >> 1) & 3;
  int sg0 = ((2*half) ^ ssw) * 8, sg1 = ((2*half+1) ^ ssw) * 8;
  int sbase = srow * 32;
  const ushort_t* pAh = Ah + (size_t)(bm + srow)*AS + half*16;
  const ushort_t* pAl = Al + (size_t)(bm + srow)*AS + half*16;
  int wrow = bn + srow;
  int wsafe = (wrow < N) ? wrow : 0;
  const ushort_t* pWh = Wh + (size_t)wsafe*WS + half*16;
  const ushort_t* pWl = Wl + (size_t)wsafe*WS + half*16;

  bf16x8 aA0,aA1,aA2,aA3,aW0,aW1,aW2,aW3;   // set A
  bf16x8 bA0,bA1,bA2,bA3,bW0,bW1,bW2,bW3;   // set B

#define ISSUE_SET(P,t) { int kb = (t)*32; \
    P##A0 = *(const bf16x8*)(pAh + kb); P##A1 = *(const bf16x8*)(pAh + kb + 8); \
    P##A2 = *(const bf16x8*)(pAl + kb); P##A3 = *(const bf16x8*)(pAl + kb + 8); \
    P##W0 = *(const bf16x8*)(pWh + kb); P##W1 = *(const bf16x8*)(pWh + kb + 8); \
    P##W2 = *(const bf16x8*)(pWl + kb); P##W3 = *(const bf16x8*)(pWl + kb + 8); }
#define COMMIT_SET(P) { \
    *(bf16x8*)&sAh[sbase + sg0] = P##A0; *(bf16x8*)&sAh[sbase + sg1] = P##A1; \
    *(bf16x8*)&sAl[sbase + sg0] = P##A2; *(bf16x8*)&sAl[sbase + sg1] = P##A3; \
    *(bf16x8*)&sWh[sbase + sg0] = P##W0; *(bf16x8*)&sWh[sbase + sg1] = P##W1; \
    *(bf16x8*)&sWl[sbase + sg0] = P##W2; *(bf16x8*)&sWl[sbase + sg1] = P##W3; }

  f32x4 acc[4][4];
  #pragma unroll
  for (int m = 0; m < 4; ++m)
    #pragma unroll
    for (int n = 0; n < 4; ++n) acc[m][n] = (f32x4){0.f,0.f,0.f,0.f};

#define FRAG_MFMA() { \
    bf16x8 ah[4], al[4], bh[4], bl[4]; \
    _Pragma("unroll") \
    for (int m = 0; m < 4; ++m) { \
      int R = wr + m*16 + lrow; \
      int o = R*32 + ((q ^ ((R>>1)&3)) * 8); \
      ah[m] = *(const bf16x8*)&sAh[o]; \
      al[m] = *(const bf16x8*)&sAl[o]; \
    } \
    _Pragma("unroll") \
    for (int n = 0; n < 4; ++n) { \
      int R = wc + n*16 + lrow; \
      int o = R*32 + ((q ^ ((R>>1)&3)) * 8); \
      bh[n] = *(const bf16x8*)&sWh[o]; \
      bl[n] = *(const bf16x8*)&sWl[o]; \
    } \
    _Pragma("unroll") \
    for (int m = 0; m < 4; ++m) \
      _Pragma("unroll") \
      for (int n = 0; n < 4; ++n) { \
        acc[m][n] = __builtin_amdgcn_mfma_f32_16x16x32_bf16(ah[m], bh[n], acc[m][n], 0,0,0); \
        acc[m][n] = __builtin_amdgcn_mfma_f32_16x16x32_bf16(ah[m], bl[n], acc[m][n], 0,0,0); \
        acc[m][n] = __builtin_amdgcn_mfma_f32_16x16x32_bf16(al[m], bh[n], acc[m][n], 0,0,0); \
      } }

  ISSUE_SET(a, 0); COMMIT_SET(a);
  __syncthreads();
  if (NT > 1) ISSUE_SET(b, 1);
  #pragma unroll
  for (int t = 0; t < NT; t += 2) {
    FRAG_MFMA();
    if (t+2 < NT) ISSUE_SET(a, t+2);
    __syncthreads();
    if (t+1 < NT) COMMIT_SET(b);
    __syncthreads();
    if (t+1 < NT) {
      FRAG_MFMA();
      if (t+3 < NT) ISSUE_SET(b, t+3);
      __syncthreads();
      if (t+2 < NT) COMMIT_SET(a);
      __syncthreads();
    }
  }
#undef ISSUE_SET
#undef COMMIT_SET
#undef FRAG_MFMA

  #pragma unroll
  for (int m = 0; m < 4; ++m) {
    int row0 = bm + wr + m*16 + (lane >> 4)*4;
    #pragma unroll
    for (int n = 0; n < 4; ++n) {
      int col = bn + wc + n*16 + lrow;
      if (OUTBF) {
        if (col < CS) {
          float bv = (col < N) ? bias[col] : 0.f;
          #pragma unroll
          for (int r = 0; r < 4; ++r) {
            float v = 0.f;
            if (col < N) { v = acc[m][n][r] + bv; if (act) v = fmaxf(v, 0.f); }
            ushort_t h = f2bf(v);
            Ch[(size_t)(row0 + r)*CS + col] = h;
            Cl[(size_t)(row0 + r)*CS + col] = f2bf(v - bf2f(h));
          }
        }
      } else {
        if (col < N) {
          float bv = bias[col];
          #pragma unroll
          for (int r = 0; r < 4; ++r) {
            float v = acc[m][n][r] + bv;
            if (act) v = fmaxf(v, 0.f);
            C[(size_t)(row0 + r)*N + col] = v;
          }
        }
      }
    }
  }
}

// ---------------- fused MFMA attention v2: bf16 pre-split inputs (round-13) ----------------
__global__ __launch_bounds__(256) void k_attn_mfma(
    const ushort_t* __restrict__ HH, const ushort_t* __restrict__ HL,
    const int* __restrict__ plen, const int* __restrict__ hlen,
    float* __restrict__ ATT)
{
  __shared__ float regA_f[12800];
  __shared__ ushort_t pbuf[2*64*136];
  ushort_t* regA = (ushort_t*)regA_f;

  int tid = threadIdx.x;
  int lane = tid & 63, wave = tid >> 6;
  int lrow = lane & 15, koff = (lane >> 4) * 8;
  int d = blockIdx.x, b = blockIdx.y, q0 = blockIdx.z * 64;
  int qbase = (d*B_ + b)*T_ + q0;
  int kbase = ((1-d)*B_ + b)*T_;
  float* outp = ATT + ((size_t)(d*B_ + b)*T_ + q0) * H_;
  int klen = (d == 0) ? hlen[b] : plen[b];

  ushort_t* sQh = regA;            // [64][40]
  ushort_t* sQl = regA + 2560;
  ushort_t* sKh = regA + 5120;     // [128][40]
  ushort_t* sKl = regA + 10240;
  int qrow = tid >> 2, qo = (tid & 3) * 8;
  int krow = tid >> 1, ko = (tid & 1) * 16;
  const ushort_t* Qh = HH + (size_t)(qbase + qrow)*320 + qo;
  const ushort_t* Ql = HL + (size_t)(qbase + qrow)*320 + qo;
  const ushort_t* Kh = HH + (size_t)(kbase + krow)*320 + ko;
  const ushort_t* Kl = HL + (size_t)(kbase + krow)*320 + ko;

  bf16x8 rqh, rql, rkh0, rkh1, rkl0, rkl1;
  auto issue1 = [&](int t){
    int kb = t*32;
    rqh  = *(const bf16x8*)(Qh + kb);
    rql  = *(const bf16x8*)(Ql + kb);
    rkh0 = *(const bf16x8*)(Kh + kb); rkh1 = *(const bf16x8*)(Kh + kb + 8);
    rkl0 = *(const bf16x8*)(Kl + kb); rkl1 = *(const bf16x8*)(Kl + kb + 8);
  };
  auto commit1 = [&](){
    *(bf16x8*)&sQh[qrow*40 + qo] = rqh;
    *(bf16x8*)&sQl[qrow*40 + qo] = rql;
    *(bf16x8*)&sKh[krow*40 + ko] = rkh0; *(bf16x8*)&sKh[krow*40 + ko + 8] = rkh1;
    *(bf16x8*)&sKl[krow*40 + ko] = rkl0; *(bf16x8*)&sKl[krow*40 + ko + 8] = rkl1;
  };

  f32x4 acc1[4][2];
  #pragma unroll
  for (int m = 0; m < 4; ++m)
    #pragma unroll
    for (int n = 0; n < 2; ++n) acc1[m][n] = (f32x4){0.f,0.f,0.f,0.f};
  int wc = wave * 32;

  issue1(0); commit1();
  __syncthreads();
  for (int t = 0; t < 10; ++t) {
    bool more = (t < 9);
    bf16x8 ah[4], al[4], bh[2], bl[2];
    #pragma unroll
    for (int m = 0; m < 4; ++m) {
      int o = (m*16 + lrow)*40 + koff;
      ah[m] = *(const bf16x8*)&sQh[o];
      al[m] = *(const bf16x8*)&sQl[o];
    }
    #pragma unroll
    for (int n = 0; n < 2; ++n) {
      int o = (wc + n*16 + lrow)*40 + koff;
      bh[n] = *(const bf16x8*)&sKh[o];
      bl[n] = *(const bf16x8*)&sKl[o];
    }
    if (more) issue1(t+1);
    __syncthreads();
    if (more) commit1();
    #pragma unroll
    for (int m = 0; m < 4; ++m)
      #pragma unroll
      for (int n = 0; n < 2; ++n) {
        acc1[m][n] = __builtin_amdgcn_mfma_f32_16x16x32_bf16(ah[m], bh[n], acc1[m][n], 0,0,0);
        acc1[m][n] = __builtin_amdgcn_mfma_f32_16x16x32_bf16(ah[m], bl[n], acc1[m][n], 0,0,0);
        acc1[m][n] = __builtin_amdgcn_mfma_f32_16x16x32_bf16(al[m], bh[n], acc1[m][n], 0,0,0);
      }
    __syncthreads();
  }
  float* sim = regA_f;
  #pragma unroll
  for (int m = 0; m < 4; ++m)
    #pragma unroll
    for (int n = 0; n < 2; ++n)
      #pragma unroll
      for (int r = 0; r < 4; ++r)
        sim[(m*16 + (lane>>4)*4 + r)*132 + wc + n*16 + lrow] = acc1[m][n][r];
  __syncthreads();

  {
    int row = tid >> 2, qtr = (tid & 3) * 32;
    const float* sr = sim + row*132;
    float mx = NEGV;
    for (int c = 0; c < 32; ++c) { int cg = qtr + c; float s = (cg < klen) ? sr[cg] : NEGV; mx = fmaxf(mx, s); }
    mx = fmaxf(mx, __shfl_xor(mx, 1));
    mx = fmaxf(mx, __shfl_xor(mx, 2));
    float sum = 0.f;
    for (int c = 0; c < 32; ++c) { int cg = qtr + c; if (cg < klen) sum += expf(sr[cg] - mx); }
    sum += __shfl_xor(sum, 1);
    sum += __shfl_xor(sum, 2);
    float rinv = 1.f / sum;
    for (int c = 0; c < 32; ++c) {
      int cg = qtr + c;
      float p = (cg < klen) ? expf(sr[cg] - mx) * rinv : 0.f;
      ushort_t h = f2bf(p);
      pbuf[row*136 + cg] = h;
      pbuf[64*136 + row*136 + cg] = f2bf(p - bf2f(h));
    }
  }
  __syncthreads();

  ushort_t* kth = regA;            // [320][40]
  ushort_t* ktl = regA + 12800;
  int wr2 = (wave & 1) * 32;
  int wcf = (wave >> 1) * 160;
  f32x4 acc3[2][10];
  #pragma unroll
  for (int m = 0; m < 2; ++m)
    #pragma unroll
    for (int n = 0; n < 10; ++n) acc3[m][n] = (f32x4){0.f,0.f,0.f,0.f};
  int skey = tid >> 3, sf8 = tid & 7;

  for (int kc = 0; kc < 4; ++kc) {
    __syncthreads();
    int key = kbase + kc*32 + skey;
    const ushort_t* krh = HH + (size_t)key*320;
    const ushort_t* krl = HL + (size_t)key*320;
    for (int f8 = sf8; f8 < 40; f8 += 8) {
      bf16x8 vh = *(const bf16x8*)(krh + f8*8);
      bf16x8 vl = *(const bf16x8*)(krl + f8*8);
      #pragma unroll
      for (int i = 0; i < 8; ++i) {
        int feat = f8*8 + i;
        kth[feat*40 + skey] = (ushort_t)vh[i];
        ktl[feat*40 + skey] = (ushort_t)vl[i];
      }
    }
    __syncthreads();
    bf16x8 ph[2], pl[2], kh[10], kl[10];
    #pragma unroll
    for (int m = 0; m < 2; ++m) {
      int o = (wr2 + m*16 + lrow)*136 + kc*32 + koff;
      ph[m] = *(const bf16x8*)&pbuf[o];
      pl[m] = *(const bf16x8*)&pbuf[64*136 + o];
    }
    #pragma unroll
    for (int n = 0; n < 10; ++n) {
      int o = (wcf + n*16 + lrow)*40 + koff;
      kh[n] = *(const bf16x8*)&kth[o];
      kl[n] = *(const bf16x8*)&ktl[o];
    }
    #pragma unroll
    for (int m = 0; m < 2; ++m)
      #pragma unroll
      for (int n = 0; n < 10; ++n) {
        acc3[m][n] = __builtin_amdgcn_mfma_f32_16x16x32_bf16(ph[m], kh[n], acc3[m][n], 0,0,0);
        acc3[m][n] = __builtin_amdgcn_mfma_f32_16x16x32_bf16(ph[m], kl[n], acc3[m][n], 0,0,0);
        acc3[m][n] = __builtin_amdgcn_mfma_f32_16x16x32_bf16(pl[m], kh[n], acc3[m][n], 0,0,0);
      }
  }
  #pragma unroll
  for (int m = 0; m < 2; ++m) {
    int row0 = wr2 + m*16 + (lane >> 4)*4;
    #pragma unroll
    for (int n = 0; n < 10; ++n) {
      int col = wcf + n*16 + lrow;
      if (col < H_) {
        #pragma unroll
        for (int r = 0; r < 4; ++r)
          outp[(size_t)(row0 + r)*H_ + col] = acc3[m][n][r];
      }
    }
  }
}

// ---------------- pool stage 1 ----------------
__global__ __launch_bounds__(320) void k_pool(const float* __restrict__ H,
    const int* __restrict__ plen, const int* __restrict__ hlen,
    float* __restrict__ psum, float* __restrict__ pmax)
{
  int chain = blockIdx.x; int s = chain >> 5, b = chain & 31;
  int c = blockIdx.y; int t0 = c * 16;
  int len = (s == 0 ? plen[b] : hlen[b]);
  int tid = threadIdx.x;
  __shared__ float buf[16*H_];
  const float* hp = H + (size_t)chain*T_*H_ + (size_t)t0*H_;
  for (int i = tid; i < 16*H_; i += 320) buf[i] = hp[i];
  __syncthreads();
  if (tid < H_) {
    int tmax = len - t0; if (tmax > 16) tmax = 16;
    float sum = 0.f, mx = NEGV;
    for (int t = 0; t < tmax; ++t) { float x = buf[t*H_ + tid]; sum += x; mx = fmaxf(mx, x); }
    int o = (chain*8 + c)*H_ + tid;
    psum[o] = sum; pmax[o] = mx;
  }
}

// ---------------- pool stage 2 + classifier ----------------
__global__ __launch_bounds__(320) void k_classify(
    const float* __restrict__ psum, const float* __restrict__ pmax,
    const int* __restrict__ plen, const int* __restrict__ hlen,
    const float* __restrict__ w1t, const float* __restrict__ b1,
    const float* __restrict__ w2, const float* __restrict__ b2,
    float* __restrict__ out)
{
  int b = blockIdx.x;
  int tid = threadIdx.x;
  __shared__ float v[HG];
  __shared__ float hid[H_];
  for (int s = 0; s < 2; ++s) {
    int chain = s*B_ + b;
    int len = (s == 0 ? plen[b] : hlen[b]);
    if (tid < H_) {
      float sum = 0.f, mx = NEGV;
      #pragma unroll
      for (int c = 0; c < 8; ++c) {
        int o = (chain*8 + c)*H_ + tid;
        sum += psum[o]; mx = fmaxf(mx, pmax[o]);
      }
      v[s*600 + tid]       = sum / (float)len;
      v[s*600 + 300 + tid] = mx;
    }
  }
  __syncthreads();
  if (tid < H_) {
    float a0 = b1[tid], a1 = 0.f, a2 = 0.f, a3 = 0.f;
    for (int m = 0; m < HG; m += 4) {
      a0 = fmaf(v[m+0], w1t[(size_t)(m+0)*H_ + tid], a0);
      a1 = fmaf(v[m+1], w1t[(size_t)(m+1)*H_ + tid], a1);
      a2 = fmaf(v[m+2], w1t[(size_t)(m+2)*H_ + tid], a2);
      a3 = fmaf(v[m+3], w1t[(size_t)(m+3)*H_ + tid], a3);
    }
    hid[tid] = tanhf(a0 + a1 + a2 + a3);
  }
  __syncthreads();
  if (tid < 3) {
    float a = b2[tid];
    const float* wr = w2 + (size_t)tid*H_;
    for (int n = 0; n < H_; ++n) a = fmaf(hid[n], wr[n], a);
    out[b*3 + tid] = a;
  }
}

// ---------------- launch ----------------
extern "C" void kernel_launch(void* const* d_in, const int* in_sizes, int n_in,
                              void* d_out, int out_size, void* d_ws, size_t ws_size,
                              hipStream_t stream) {
  const int*   prem    = (const int*)d_in[0];
  const int*   plen    = (const int*)d_in[1];
  const int*   hyp     = (const int*)d_in[2];
  const int*   hlen    = (const int*)d_in[3];
  const float* lg      = (const float*)d_in[4];
  const float* rg      = (const float*)d_in[5];
  const float* emb     = (const float*)d_in[6];
  const float* enc_wx  = (const float*)d_in[7];
  const float* enc_bx  = (const float*)d_in[8];
  const float* enc_uh  = (const float*)d_in[9];
  const float* enc_bh  = (const float*)d_in[10];
  const float* comp_wx = (const float*)d_in[11];
  const float* comp_bx = (const float*)d_in[12];
  const float* comp_uh = (const float*)d_in[13];
  const float* comp_bh = (const float*)d_in[14];
  const float* proj_w  = (const float*)d_in[15];
  const float* proj_b  = (const float*)d_in[16];
  const float* cls_w1  = (const float*)d_in[17];
  const float* cls_b1  = (const float*)d_in[18];
  const float* cls_w2  = (const float*)d_in[19];
  const float* cls_b2  = (const float*)d_in[20];
  float* outp = (float*)d_out;

  // workspace layout (floats); ENH bf16 aliases XG; PROJ/H-split bf16 alias EH/EL
  float* XG  = (float*)d_ws;                       // 9,830,400 f
  ushort_t* EH = (ushort_t*)(XG + 9830400);        // [8192][320] hi (emb -> h-split -> PROJ)
  ushort_t* EL = EH + 2621440;                     // [8192][320] lo
  float* H1  = XG + 9830400 + 2621440;
  float* CH  = H1 + 2457600;                       // ATT alias
  float* FH  = CH + 2457600;
  float* UTE = FH + 2457600;
  float* UTC = UTE + 90000;
  float* W1T = UTC + 90000;
  ushort_t* WencH  = (ushort_t*)(W1T + 360000);
  ushort_t* WencL  = WencH + 384000;
  ushort_t* WcompH = WencL + 384000;
  ushort_t* WcompL = WcompH + 384000;
  ushort_t* WPH    = WcompL + 384000;
  ushort_t* WPL    = WPH + 278400;
  float* PSUM = W1T + 360000 + 1046400;
  float* PMAX = PSUM + 153600;
  float* EW   = PMAX + 153600;
  int* EIDX   = (int*)(EW + 64*ECAP);
  int* CNT    = EIDX + 64*ECAP;
  int* COFF   = CNT + 64*T_;
  int* DEPTH  = COFF + 64*T_;
  int* HASP   = DEPTH + 64*T_;
  int* LVLCNT = HASP + 64*T_;
  int* WL     = LVLCNT + TAILD;
  int* DCNT   = WL + TAILD*WLCAP;
  int* DLIST  = DCNT + 64;
  float* ATT  = CH;
  ushort_t* ENH_H = (ushort_t*)XG;                 // [8192][928] hi (after enc scan, XG dead)
  ushort_t* ENH_L = ENH_H + 7602176;

  hipMemsetAsync(LVLCNT, 0, TAILD*sizeof(int), stream);
  // 1. weight prep + graph analysis + embedding split
  k_prep_all<<<(1496400 + 255)/256, 256, 0, stream>>>(enc_uh, comp_uh, enc_wx, comp_wx, proj_w, cls_w1,
      UTE, UTC, W1T, WencH, WencL, WcompH, WcompL, WPH, WPL);
  k_build<<<64, 256, 0, stream>>>(lg, rg, CNT, COFF, EIDX, EW, HASP, DEPTH, LVLCNT, WL, DCNT, DLIST);
  k_embed_split<<<10240, 256, 0, stream>>>(prem, hyp, emb, EH, EL);
  // 2. enc xg = emb @ enc_wx^T + enc_bx
  k_gemm_bf<0,10><<<dim3(10, 64), 256, 0, stream>>>(EH, EL, 320, WencH, WencL, 320,
      enc_bx, XG, nullptr, nullptr, 0, HG, 0);
  // 3. enc tree scan (levels 0..3 parallel, deep nodes via compact-list serial tail)
  for (int L = 0; L < TAILD; ++L)
    k_level<<<640, 1024, 0, stream>>>(XG, enc_bh, UTE, CNT, COFF, EIDX, EW, HASP, LVLCNT, WL, L, H1, CH, FH);
  k_tail<<<64, 320, 0, stream>>>(XG, enc_bh, UTE, CNT, COFF, EIDX, EW, HASP, DCNT, DLIST, H1, CH, FH);
  // 4. h-split + attention (CH dead -> ATT)
  k_h_split<<<10240, 256, 0, stream>>>(H1, EH, EL);
  k_attn_mfma<<<dim3(2, B_, 2), 256, 0, stream>>>(EH, EL, plen, hlen, ATT);
  // 5. enhance split (enc-xg dead), proj GEMM -> PROJ bf16 hi/lo (overwrites EH/EL)
  k_enh_split<<<29696, 256, 0, stream>>>(H1, ATT, ENH_H, ENH_L);
  k_gemm_bf<1,29><<<dim3(3, 64), 256, 0, stream>>>(ENH_H, ENH_L, 928, WPH, WPL, 928,
      proj_b, nullptr, EH, EL, 320, H_, 1);
  // 6. comp xg = proj @ comp_wx^T + comp_bx (overwrites XG)
  k_gemm_bf<0,10><<<dim3(10, 64), 256, 0, stream>>>(EH, EL, 320, WcompH, WcompL, 320,
      comp_bx, XG, nullptr, nullptr, 0, HG, 0);
  // 7. comp tree scan
  for (int L = 0; L < TAILD; ++L)
    k_level<<<640, 1024, 0, stream>>>(XG, comp_bh, UTC, CNT, COFF, EIDX, EW, HASP, LVLCNT, WL, L, H1, CH, FH);
  k_tail<<<64, 320, 0, stream>>>(XG, comp_bh, UTC, CNT, COFF, EIDX, EW, HASP, DCNT, DLIST, H1, CH, FH);
  // 8. pool + classifier
  k_pool<<<dim3(64, 8), 320, 0, stream>>>(H1, plen, hlen, PSUM, PMAX);
  k_classify<<<B_, 320, 0, stream>>>(PSUM, PMAX, plen, hlen, W1T, cls_b1, cls_w2, cls_b2, outp);
}

// Round 18
// 476.894 us; speedup vs baseline: 1.1746x; 1.0115x over previous
//
#include <hip/hip_runtime.h>
#include <math.h>

#define B_ 32
#define T_ 128
#define H_ 300
#define HG 1200   // 4*H
#define TAILD 4   // levels >= TAILD handled by serial per-chain tail
#define WLCAP 8192
#define ECAP 2048
#define NEGV -10000000.0f

typedef __attribute__((ext_vector_type(8))) short bf16x8;
typedef __attribute__((ext_vector_type(4))) float f32x4;
typedef unsigned short ushort_t;

__device__ __forceinline__ float sigm(float x){ return 1.f/(1.f+expf(-x)); }

__device__ __forceinline__ unsigned short f2bf(float x){
  union { float f; unsigned int u; } c; c.f = x;
  unsigned int u = c.u;
  return (unsigned short)((u + 0x7fffu + ((u >> 16) & 1u)) >> 16);
}
__device__ __forceinline__ float bf2f(unsigned short h){
  union { unsigned int u; float f; } c; c.u = ((unsigned int)h) << 16;
  return c.f;
}

// ---------------- fused weight prep: fp32 transposes + bf16 hi/lo padded weights ----------------
__global__ __launch_bounds__(256) void k_prep_all(
    const float* __restrict__ enc_uh, const float* __restrict__ comp_uh,
    const float* __restrict__ enc_wx, const float* __restrict__ comp_wx,
    const float* __restrict__ pw, const float* __restrict__ cw1,
    float* __restrict__ te, float* __restrict__ tc, float* __restrict__ w1t,
    ushort_t* __restrict__ WencH, ushort_t* __restrict__ WencL,
    ushort_t* __restrict__ WcompH, ushort_t* __restrict__ WcompL,
    ushort_t* __restrict__ WPH, ushort_t* __restrict__ WPL)
{
  int i = blockIdx.x*256 + threadIdx.x;
  if (i < 90000) {                       // uh1 transposes: te/tc[m][k] = uh[1][k][m]
    int m = i / H_, k = i - m*H_;
    te[i] = enc_uh[H_*H_ + (size_t)k*H_ + m];
    tc[i] = comp_uh[H_*H_ + (size_t)k*H_ + m];
  } else if (i < 450000) {               // w1t (1200 x 300): w1t[m][k] = cw1[k][m]
    int i2 = i - 90000;
    int m = i2 / H_, k = i2 - m*H_;
    w1t[i2] = cw1[(size_t)k*HG + m];
  } else if (i < 834000) {               // Wenc hi/lo [1200][320], zero-padded
    int i2 = i - 450000;
    int n = i2 / 320, k = i2 - n*320;
    float v = (k < 300) ? enc_wx[(size_t)n*300 + k] : 0.f;
    ushort_t h = f2bf(v);
    WencH[i2] = h; WencL[i2] = f2bf(v - bf2f(h));
  } else if (i < 1218000) {              // Wcomp hi/lo [1200][320]
    int i2 = i - 834000;
    int n = i2 / 320, k = i2 - n*320;
    float v = (k < 300) ? comp_wx[(size_t)n*300 + k] : 0.f;
    ushort_t h = f2bf(v);
    WcompH[i2] = h; WcompL[i2] = f2bf(v - bf2f(h));
  } else if (i < 1496400) {              // folded proj W hi/lo [300][928]
    int i2 = i - 1218000;
    int n = i2 / 928, k = i2 - n*928;
    const float* r = pw + (size_t)n*HG;
    float v = 0.f;
    if (k < 300)      v = r[k] + r[600+k];
    else if (k < 600) v = r[k] - r[k+300];
    else if (k < 900) v = r[k+300];
    ushort_t h = f2bf(v);
    WPH[i2] = h; WPL[i2] = f2bf(v - bf2f(h));
  }
}

// ---------------- embedding gather + bf16 split: [8192][320] hi/lo ----------------
__global__ __launch_bounds__(256) void k_embed_split(const int* __restrict__ prem, const int* __restrict__ hyp,
    const float* __restrict__ emb, ushort_t* __restrict__ EH, ushort_t* __restrict__ EL)
{
  int i = blockIdx.x*256 + threadIdx.x;      // over 8192*320
  int bt = i / 320, k = i - bt*320;
  int side = bt >> 12, bt2 = bt & 4095;
  float v = 0.f;
  if (k < 300) {
    int tok = (side == 0 ? prem : hyp)[bt2];
    v = emb[(size_t)tok*H_ + k];
  }
  ushort_t h = f2bf(v);
  EH[i] = h; EL[i] = f2bf(v - bf2f(h));
}

// ---------------- H1 -> bf16 hi/lo split: [8192][320] (aliases dead EH/EL) ----------------
__global__ __launch_bounds__(256) void k_h_split(const float* __restrict__ H1,
    ushort_t* __restrict__ HH, ushort_t* __restrict__ HL)
{
  int i = blockIdx.x*256 + threadIdx.x;      // over 8192*320
  int r = i / 320, k = i - r*320;
  float v = (k < 300) ? H1[(size_t)r*H_ + k] : 0.f;
  ushort_t h = f2bf(v);
  HH[i] = h; HL[i] = f2bf(v - bf2f(h));
}

// ---------------- enhance + bf16 split: A=[H1|ATT|H1*ATT] -> [8192][928] hi/lo ----------------
__global__ __launch_bounds__(256) void k_enh_split(const float* __restrict__ H1, const float* __restrict__ ATT,
    ushort_t* __restrict__ AH, ushort_t* __restrict__ AL)
{
  int i = blockIdx.x*256 + threadIdx.x;      // over 8192*928
  int r = i / 928, k = i - r*928;
  float v = 0.f;
  if (k < 300)      v = H1[(size_t)r*H_ + k];
  else if (k < 600) v = ATT[(size_t)r*H_ + k - 300];
  else if (k < 900) { int kk = k - 600; v = H1[(size_t)r*H_ + kk] * ATT[(size_t)r*H_ + kk]; }
  ushort_t h = f2bf(v);
  AH[i] = h; AL[i] = f2bf(v - bf2f(h));
}

// ---------------- graph analysis v4: parented-first worklists + compact deep-node lists ----------------
__global__ __launch_bounds__(256) void k_build(const float* __restrict__ lg, const float* __restrict__ rg,
    int* __restrict__ cnt_g, int* __restrict__ coff_g, int* __restrict__ eidx_g, float* __restrict__ ew_g,
    int* __restrict__ hasp_g, int* __restrict__ depth_g,
    int* __restrict__ lvlcnt_g, int* __restrict__ wl_g,
    int* __restrict__ dcnt_g, int* __restrict__ dlist_g)
{
  int chain = blockIdx.x; int s = chain >> 5, b = chain & 31;
  const float* graph = (s ? rg : lg) + (size_t)b*T_*T_;
  int tid = threadIdx.x;
  __shared__ float gbuf[T_*T_];            // 64 KB
  __shared__ int cnt[T_], coff[T_], depth[T_], hasp[T_];
  __shared__ short eidx[ECAP];
  __shared__ float ew[ECAP];
  __shared__ int lcnt[TAILD], lbase[TAILD], lppos[TAILD], lnpos[TAILD];
  __shared__ int etot_s;

  #pragma unroll
  for (int k = 0; k < 16; ++k)
    ((float4*)gbuf)[tid + k*256] = ((const float4*)graph)[tid + k*256];
  if (tid < T_) hasp[tid] = 0;
  if (tid < TAILD) { lcnt[tid] = 0; lppos[tid] = 0; lnpos[tid] = 0; }
  __syncthreads();
  if (tid < T_) {
    int j = tid, c = 0;
    const float* gr = gbuf + j*T_;
    for (int t = 0; t < j; ++t) c += (gr[t] != 0.f) ? 1 : 0;
    cnt[j] = c;
  }
  __syncthreads();
  if (tid == 0) { int a = 0; for (int j = 0; j < T_; ++j) { coff[j] = a; a += cnt[j]; } etot_s = a; }
  __syncthreads();
  if (tid < T_) {
    int j = tid, p = coff[j];
    const float* gr = gbuf + j*T_;
    for (int t = 0; t < j; ++t) {
      float g = gr[t];
      if (g != 0.f && p < ECAP) { eidx[p] = (short)t; ew[p] = g; hasp[t] = 1; ++p; }
    }
  }
  __syncthreads();
  if (tid == 0) {
    int md = 0, dc = 0;
    for (int j = 0; j < T_; ++j) {
      int d = 0, e0 = coff[j], e1 = coff[j] + cnt[j];
      if (e1 > ECAP) e1 = ECAP;
      for (int k = e0; k < e1; ++k) { int dd = depth[eidx[k]] + 1; d = dd > d ? dd : d; }
      depth[j] = d; md = d > md ? d : md;
      if (d >= TAILD) dlist_g[chain*T_ + dc++] = j;   // compact deep list (position order)
    }
    dcnt_g[chain] = dc;
  }
  __syncthreads();
  if (tid < T_) { int L = depth[tid]; if (L < TAILD) atomicAdd(&lcnt[L], 1); }
  __syncthreads();
  if (tid < TAILD && lcnt[tid] > 0) lbase[tid] = atomicAdd(&lvlcnt_g[tid], lcnt[tid]);
  __syncthreads();
  // fill worklist chunk: parented nodes from the front, unparented from the back
  if (tid < T_) {
    int L = depth[tid];
    if (L < TAILD) {
      int pos;
      if (hasp[tid]) { int p = atomicAdd(&lppos[L], 1); pos = p; }
      else           { int p = atomicAdd(&lnpos[L], 1); pos = lcnt[L] - 1 - p; }
      wl_g[L*WLCAP + lbase[L] + pos] = (chain << 8) | tid;
    }
  }
  int base = chain * T_;
  if (tid < T_) {
    cnt_g[base+tid] = cnt[tid]; coff_g[base+tid] = coff[tid];
    hasp_g[base+tid] = hasp[tid]; depth_g[base+tid] = depth[tid];
  }
  int etot = etot_s; if (etot > ECAP) etot = ECAP;
  for (int i = tid; i < etot; i += 256) { eidx_g[chain*ECAP + i] = eidx[i]; ew_g[chain*ECAP + i] = ew[i]; }
}

// ---------------- per-level tree-LSTM (round-10 proven: 4 nodes/block, scalar matvec) ----------------
__global__ __launch_bounds__(1024) void k_level(
    const float* __restrict__ xg, const float* __restrict__ bhv, const float* __restrict__ uh1T,
    const int* __restrict__ cnt_g, const int* __restrict__ coff_g,
    const int* __restrict__ eidx_g, const float* __restrict__ ew_g,
    const int* __restrict__ hasp_g, const int* __restrict__ lvlcnt_g, const int* __restrict__ wl_g,
    int L, float* __restrict__ hout, float* __restrict__ chist, float* __restrict__ fh)
{
  int count = lvlcnt_g[L];
  int nblk = (count + 3) >> 2;
  int tid = threadIdx.x;
  __shared__ float h_s[4][H_];
  __shared__ float psum[3][4][H_];
  __shared__ int nodes[4];
  __shared__ int anyp;
  for (int blk = blockIdx.x; blk < nblk; blk += gridDim.x) {
    int base = blk * 4;
    int nn = count - base; if (nn > 4) nn = 4;
    if (tid == 0) anyp = 0;
    __syncthreads();
    if (tid < 4) {
      int pk = (tid < nn) ? wl_g[L*WLCAP + base + tid] : -1;
      nodes[tid] = pk;
      if (pk >= 0 && hasp_g[(pk >> 8)*T_ + (pk & 255)]) atomicAdd(&anyp, 1);
    }
    __syncthreads();
    for (int w = tid; w < nn*H_; w += 1024) {
      int n = w / H_, e = w - n*H_;
      int pk = nodes[n]; int chain = pk >> 8, j = pk & 255;
      size_t cb = (size_t)chain*T_*H_, xb = (size_t)chain*T_*HG;
      const float* xp = xg + xb + (size_t)j*HG;
      float x0 = xp[e], x1 = xp[H_+e], x2 = xp[2*H_+e], x3 = xp[3*H_+e];
      float iu  = sigm(x0 + bhv[e]) * tanhf(x3 + bhv[3*H_+e]);
      float og  = sigm(x2 + bhv[2*H_+e]);
      float x1b = x1 + bhv[H_+e];
      float acc = iu;
      int c0 = coff_g[chain*T_+j], c1 = c0 + cnt_g[chain*T_+j];
      const int* ei = eidx_g + chain*ECAP;
      const float* ewp = ew_g + chain*ECAP;
      for (int k = c0; k < c1; ++k) {
        int t = ei[k];
        acc += ewp[k] * sigm(x1b + fh[cb + (size_t)t*H_ + e]) * chist[cb + (size_t)t*H_ + e];
      }
      chist[cb + (size_t)j*H_ + e] = acc;
      float hv = og * tanhf(acc);
      hout[cb + (size_t)j*H_ + e] = hv;
      h_s[n][e] = hv;
    }
    __syncthreads();
    if (anyp > 0) {
      if (tid < 3*H_) {
        int g = tid / H_, e = tid - g*H_;
        float a0=0.f, a1=0.f, a2=0.f, a3=0.f;
        const float* up = uh1T + e;
        int m0 = g*100, m1 = m0 + 100;
        #pragma unroll 4
        for (int m = m0; m < m1; ++m) {
          float u = up[(size_t)m*H_];
          a0 = fmaf(u, h_s[0][m], a0);
          a1 = fmaf(u, h_s[1][m], a1);
          a2 = fmaf(u, h_s[2][m], a2);
          a3 = fmaf(u, h_s[3][m], a3);
        }
        psum[g][0][e]=a0; psum[g][1][e]=a1; psum[g][2][e]=a2; psum[g][3][e]=a3;
      }
      __syncthreads();
      for (int w = tid; w < nn*H_; w += 1024) {
        int n = w / H_, e = w - n*H_;
        int pk = nodes[n]; int chain = pk >> 8, j = pk & 255;
        if (hasp_g[chain*T_+j]) {
          size_t cb = (size_t)chain*T_*H_;
          fh[cb + (size_t)j*H_ + e] = psum[0][n][e] + psum[1][n][e] + psum[2][n][e];
        }
      }
    }
    __syncthreads();
  }
}

// ---------------- serial tail v3: compact list + 900-thread contiguous-row matvec ----------------
__global__ __launch_bounds__(1024) void k_tail(const float* __restrict__ xg, const float* __restrict__ bhv,
    const float* __restrict__ uh1row,   // raw uh[1] row-major [k][m] (k=output, m=input)
    const int* __restrict__ cnt_g, const int* __restrict__ coff_g,
    const int* __restrict__ eidx_g, const float* __restrict__ ew_g, const int* __restrict__ hasp_g,
    const int* __restrict__ dcnt_g, const int* __restrict__ dlist_g,
    float* __restrict__ hout, float* __restrict__ chist, float* __restrict__ fh)
{
  int chain = blockIdx.x;
  int dc = dcnt_g[chain];
  if (dc == 0) return;
  int tid = threadIdx.x;
  bool act = tid < H_;
  float bh0=0.f,bh1=0.f,bh2=0.f,bh3=0.f;
  if (act) { bh0=bhv[tid]; bh1=bhv[H_+tid]; bh2=bhv[2*H_+tid]; bh3=bhv[3*H_+tid]; }
  __shared__ float h_lds[H_];
  __shared__ float psum[3][H_];
  __shared__ int djs[T_];
  if (tid < dc) djs[tid] = dlist_g[chain*T_ + tid];
  __syncthreads();
  size_t cb = (size_t)chain*T_*H_, xb = (size_t)chain*T_*HG;
  const int* ei = eidx_g + chain*ECAP;
  const float* ewp = ew_g + chain*ECAP;
  for (int di = 0; di < dc; ++di) {
    int j = djs[di];
    if (act) {
      const float* xp = xg + xb + (size_t)j*HG;
      float x0 = xp[tid], x1 = xp[H_+tid], x2 = xp[2*H_+tid], x3 = xp[3*H_+tid];
      float acc = sigm(x0+bh0) * tanhf(x3+bh3);
      float og  = sigm(x2+bh2);
      float x1b = x1 + bh1;
      int c0 = coff_g[chain*T_+j], c1 = c0 + cnt_g[chain*T_+j];
      for (int k = c0; k < c1; ++k) {
        int t = ei[k];
        acc += ewp[k] * sigm(x1b + fh[cb + (size_t)t*H_ + tid]) * chist[cb + (size_t)t*H_ + tid];
      }
      chist[cb + (size_t)j*H_ + tid] = acc;
      float hv = og * tanhf(acc);
      hout[cb + (size_t)j*H_ + tid] = hv;
      h_lds[tid] = hv;
    }
    __syncthreads();
    if (hasp_g[chain*T_+j]) {
      if (tid < 3*H_) {
        int g = tid / H_, e = tid - g*H_;
        float a = 0.f;
        const float* ur = uh1row + (size_t)e*H_ + g*100;   // contiguous 400B chunk
        #pragma unroll 5
        for (int m = 0; m < 100; m += 4) {
          float4 u4 = *(const float4*)(ur + m);
          float4 h4 = *(const float4*)&h_lds[g*100 + m];
          a = fmaf(u4.x, h4.x, a); a = fmaf(u4.y, h4.y, a);
          a = fmaf(u4.z, h4.z, a); a = fmaf(u4.w, h4.w, a);
        }
        psum[g][e] = a;
      }
      __syncthreads();
      if (act) fh[cb + (size_t)j*H_ + tid] = psum[0][tid] + psum[1][tid] + psum[2][tid];
    }
    __syncthreads();
  }
}

// ---------------- split-bf16 MFMA GEMM v3: 2-deep register prefetch (round-16 proven) ----------------
template<int OUTBF, int NT>
__global__ __launch_bounds__(256) void k_gemm_bf(
    const ushort_t* __restrict__ Ah, const ushort_t* __restrict__ Al, int AS,
    const ushort_t* __restrict__ Wh, const ushort_t* __restrict__ Wl, int WS,
    const float* __restrict__ bias, float* __restrict__ C,
    ushort_t* __restrict__ Ch, ushort_t* __restrict__ Cl, int CS,
    int N, int act)
{
  __shared__ ushort_t sAh[128*32], sAl[128*32], sWh[128*32], sWl[128*32];  // 32 KB
  int tid = threadIdx.x;
  int bn = blockIdx.x * 128, bm = blockIdx.y * 128;
  int lane = tid & 63, wave = tid >> 6;
  int wr = (wave >> 1) * 64, wc = (wave & 1) * 64;
  int lrow = lane & 15, q = lane >> 4;

  int srow = tid >> 1, half = tid & 1;
  int ssw = (srow >> 1) & 3;
  int sg0 = ((2*half) ^ ssw) * 8, sg1 = ((2*half+1) ^ ssw) * 8;
  int sbase = srow * 32;
  const ushort_t* pAh = Ah + (size_t)(bm + srow)*AS + half*16;
  const ushort_t* pAl = Al + (size_t)(bm + srow)*AS + half*16;
  int wrow = bn + srow;
  int wsafe = (wrow < N) ? wrow : 0;
  const ushort_t* pWh = Wh + (size_t)wsafe*WS + half*16;
  const ushort_t* pWl = Wl + (size_t)wsafe*WS + half*16;

  bf16x8 aA0,aA1,aA2,aA3,aW0,aW1,aW2,aW3;   // set A
  bf16x8 bA0,bA1,bA2,bA3,bW0,bW1,bW2,bW3;   // set B

#define ISSUE_SET(P,t) { int kb = (t)*32; \
    P##A0 = *(const bf16x8*)(pAh + kb); P##A1 = *(const bf16x8*)(pAh + kb + 8); \
    P##A2 = *(const bf16x8*)(pAl + kb); P##A3 = *(const bf16x8*)(pAl + kb + 8); \
    P##W0 = *(const bf16x8*)(pWh + kb); P##W1 = *(const bf16x8*)(pWh + kb + 8); \
    P##W2 = *(const bf16x8*)(pWl + kb); P##W3 = *(const bf16x8*)(pWl + kb + 8); }
#define COMMIT_SET(P) { \
    *(bf16x8*)&sAh[sbase + sg0] = P##A0; *(bf16x8*)&sAh[sbase + sg1] = P##A1; \
    *(bf16x8*)&sAl[sbase + sg0] = P##A2; *(bf16x8*)&sAl[sbase + sg1] = P##A3; \
    *(bf16x8*)&sWh[sbase + sg0] = P##W0; *(bf16x8*)&sWh[sbase + sg1] = P##W1; \
    *(bf16x8*)&sWl[sbase + sg0] = P##W2; *(bf16x8*)&sWl[sbase + sg1] = P##W3; }

  f32x4 acc[4][4];
  #pragma unroll
  for (int m = 0; m < 4; ++m)
    #pragma unroll
    for (int n = 0; n < 4; ++n) acc[m][n] = (f32x4){0.f,0.f,0.f,0.f};

#define FRAG_MFMA() { \
    bf16x8 ah[4], al[4], bh[4], bl[4]; \
    _Pragma("unroll") \
    for (int m = 0; m < 4; ++m) { \
      int R = wr + m*16 + lrow; \
      int o = R*32 + ((q ^ ((R>>1)&3)) * 8); \
      ah[m] = *(const bf16x8*)&sAh[o]; \
      al[m] = *(const bf16x8*)&sAl[o]; \
    } \
    _Pragma("unroll") \
    for (int n = 0; n < 4; ++n) { \
      int R = wc + n*16 + lrow; \
      int o = R*32 + ((q ^ ((R>>1)&3)) * 8); \
      bh[n] = *(const bf16x8*)&sWh[o]; \
      bl[n] = *(const bf16x8*)&sWl[o]; \
    } \
    _Pragma("unroll") \
    for (int m = 0; m < 4; ++m) \
      _Pragma("unroll") \
      for (int n = 0; n < 4; ++n) { \
        acc[m][n] = __builtin_amdgcn_mfma_f32_16x16x32_bf16(ah[m], bh[n], acc[m][n], 0,0,0); \
        acc[m][n] = __builtin_amdgcn_mfma_f32_16x16x32_bf16(ah[m], bl[n], acc[m][n], 0,0,0); \
        acc[m][n] = __builtin_amdgcn_mfma_f32_16x16x32_bf16(al[m], bh[n], acc[m][n], 0,0,0); \
      } }

  ISSUE_SET(a, 0); COMMIT_SET(a);
  __syncthreads();
  if (NT > 1) ISSUE_SET(b, 1);
  #pragma unroll
  for (int t = 0; t < NT; t += 2) {
    FRAG_MFMA();
    if (t+2 < NT) ISSUE_SET(a, t+2);
    __syncthreads();
    if (t+1 < NT) COMMIT_SET(b);
    __syncthreads();
    if (t+1 < NT) {
      FRAG_MFMA();
      if (t+3 < NT) ISSUE_SET(b, t+3);
      __syncthreads();
      if (t+2 < NT) COMMIT_SET(a);
      __syncthreads();
    }
  }
#undef ISSUE_SET
#undef COMMIT_SET
#undef FRAG_MFMA

  #pragma unroll
  for (int m = 0; m < 4; ++m) {
    int row0 = bm + wr + m*16 + (lane >> 4)*4;
    #pragma unroll
    for (int n = 0; n < 4; ++n) {
      int col = bn + wc + n*16 + lrow;
      if (OUTBF) {
        if (col < CS) {
          float bv = (col < N) ? bias[col] : 0.f;
          #pragma unroll
          for (int r = 0; r < 4; ++r) {
            float v = 0.f;
            if (col < N) { v = acc[m][n][r] + bv; if (act) v = fmaxf(v, 0.f); }
            ushort_t h = f2bf(v);
            Ch[(size_t)(row0 + r)*CS + col] = h;
            Cl[(size_t)(row0 + r)*CS + col] = f2bf(v - bf2f(h));
          }
        }
      } else {
        if (col < N) {
          float bv = bias[col];
          #pragma unroll
          for (int r = 0; r < 4; ++r) {
            float v = acc[m][n][r] + bv;
            if (act) v = fmaxf(v, 0.f);
            C[(size_t)(row0 + r)*N + col] = v;
          }
        }
      }
    }
  }
}

// ---------------- fused MFMA attention v2: bf16 pre-split inputs (round-13) ----------------
__global__ __launch_bounds__(256) void k_attn_mfma(
    const ushort_t* __restrict__ HH, const ushort_t* __restrict__ HL,
    const int* __restrict__ plen, const int* __restrict__ hlen,
    float* __restrict__ ATT)
{
  __shared__ float regA_f[12800];
  __shared__ ushort_t pbuf[2*64*136];
  ushort_t* regA = (ushort_t*)regA_f;

  int tid = threadIdx.x;
  int lane = tid & 63, wave = tid >> 6;
  int lrow = lane & 15, koff = (lane >> 4) * 8;
  int d = blockIdx.x, b = blockIdx.y, q0 = blockIdx.z * 64;
  int qbase = (d*B_ + b)*T_ + q0;
  int kbase = ((1-d)*B_ + b)*T_;
  float* outp = ATT + ((size_t)(d*B_ + b)*T_ + q0) * H_;
  int klen = (d == 0) ? hlen[b] : plen[b];

  ushort_t* sQh = regA;            // [64][40]
  ushort_t* sQl = regA + 2560;
  ushort_t* sKh = regA + 5120;     // [128][40]
  ushort_t* sKl = regA + 10240;
  int qrow = tid >> 2, qo = (tid & 3) * 8;
  int krow = tid >> 1, ko = (tid & 1) * 16;
  const ushort_t* Qh = HH + (size_t)(qbase + qrow)*320 + qo;
  const ushort_t* Ql = HL + (size_t)(qbase + qrow)*320 + qo;
  const ushort_t* Kh = HH + (size_t)(kbase + krow)*320 + ko;
  const ushort_t* Kl = HL + (size_t)(kbase + krow)*320 + ko;

  bf16x8 rqh, rql, rkh0, rkh1, rkl0, rkl1;
  auto issue1 = [&](int t){
    int kb = t*32;
    rqh  = *(const bf16x8*)(Qh + kb);
    rql  = *(const bf16x8*)(Ql + kb);
    rkh0 = *(const bf16x8*)(Kh + kb); rkh1 = *(const bf16x8*)(Kh + kb + 8);
    rkl0 = *(const bf16x8*)(Kl + kb); rkl1 = *(const bf16x8*)(Kl + kb + 8);
  };
  auto commit1 = [&](){
    *(bf16x8*)&sQh[qrow*40 + qo] = rqh;
    *(bf16x8*)&sQl[qrow*40 + qo] = rql;
    *(bf16x8*)&sKh[krow*40 + ko] = rkh0; *(bf16x8*)&sKh[krow*40 + ko + 8] = rkh1;
    *(bf16x8*)&sKl[krow*40 + ko] = rkl0; *(bf16x8*)&sKl[krow*40 + ko + 8] = rkl1;
  };

  f32x4 acc1[4][2];
  #pragma unroll
  for (int m = 0; m < 4; ++m)
    #pragma unroll
    for (int n = 0; n < 2; ++n) acc1[m][n] = (f32x4){0.f,0.f,0.f,0.f};
  int wc = wave * 32;

  issue1(0); commit1();
  __syncthreads();
  for (int t = 0; t < 10; ++t) {
    bool more = (t < 9);
    bf16x8 ah[4], al[4], bh[2], bl[2];
    #pragma unroll
    for (int m = 0; m < 4; ++m) {
      int o = (m*16 + lrow)*40 + koff;
      ah[m] = *(const bf16x8*)&sQh[o];
      al[m] = *(const bf16x8*)&sQl[o];
    }
    #pragma unroll
    for (int n = 0; n < 2; ++n) {
      int o = (wc + n*16 + lrow)*40 + koff;
      bh[n] = *(const bf16x8*)&sKh[o];
      bl[n] = *(const bf16x8*)&sKl[o];
    }
    if (more) issue1(t+1);
    __syncthreads();
    if (more) commit1();
    #pragma unroll
    for (int m = 0; m < 4; ++m)
      #pragma unroll
      for (int n = 0; n < 2; ++n) {
        acc1[m][n] = __builtin_amdgcn_mfma_f32_16x16x32_bf16(ah[m], bh[n], acc1[m][n], 0,0,0);
        acc1[m][n] = __builtin_amdgcn_mfma_f32_16x16x32_bf16(ah[m], bl[n], acc1[m][n], 0,0,0);
        acc1[m][n] = __builtin_amdgcn_mfma_f32_16x16x32_bf16(al[m], bh[n], acc1[m][n], 0,0,0);
      }
    __syncthreads();
  }
  float* sim = regA_f;
  #pragma unroll
  for (int m = 0; m < 4; ++m)
    #pragma unroll
    for (int n = 0; n < 2; ++n)
      #pragma unroll
      for (int r = 0; r < 4; ++r)
        sim[(m*16 + (lane>>4)*4 + r)*132 + wc + n*16 + lrow] = acc1[m][n][r];
  __syncthreads();

  {
    int row = tid >> 2, qtr = (tid & 3) * 32;
    const float* sr = sim + row*132;
    float mx = NEGV;
    for (int c = 0; c < 32; ++c) { int cg = qtr + c; float s = (cg < klen) ? sr[cg] : NEGV; mx = fmaxf(mx, s); }
    mx = fmaxf(mx, __shfl_xor(mx, 1));
    mx = fmaxf(mx, __shfl_xor(mx, 2));
    float sum = 0.f;
    for (int c = 0; c < 32; ++c) { int cg = qtr + c; if (cg < klen) sum += expf(sr[cg] - mx); }
    sum += __shfl_xor(sum, 1);
    sum += __shfl_xor(sum, 2);
    float rinv = 1.f / sum;
    for (int c = 0; c < 32; ++c) {
      int cg = qtr + c;
      float p = (cg < klen) ? expf(sr[cg] - mx) * rinv : 0.f;
      ushort_t h = f2bf(p);
      pbuf[row*136 + cg] = h;
      pbuf[64*136 + row*136 + cg] = f2bf(p - bf2f(h));
    }
  }
  __syncthreads();

  ushort_t* kth = regA;            // [320][40]
  ushort_t* ktl = regA + 12800;
  int wr2 = (wave & 1) * 32;
  int wcf = (wave >> 1) * 160;
  f32x4 acc3[2][10];
  #pragma unroll
  for (int m = 0; m < 2; ++m)
    #pragma unroll
    for (int n = 0; n < 10; ++n) acc3[m][n] = (f32x4){0.f,0.f,0.f,0.f};
  int skey = tid >> 3, sf8 = tid & 7;

  for (int kc = 0; kc < 4; ++kc) {
    __syncthreads();
    int key = kbase + kc*32 + skey;
    const ushort_t* krh = HH + (size_t)key*320;
    const ushort_t* krl = HL + (size_t)key*320;
    for (int f8 = sf8; f8 < 40; f8 += 8) {
      bf16x8 vh = *(const bf16x8*)(krh + f8*8);
      bf16x8 vl = *(const bf16x8*)(krl + f8*8);
      #pragma unroll
      for (int i = 0; i < 8; ++i) {
        int feat = f8*8 + i;
        kth[feat*40 + skey] = (ushort_t)vh[i];
        ktl[feat*40 + skey] = (ushort_t)vl[i];
      }
    }
    __syncthreads();
    bf16x8 ph[2], pl[2], kh[10], kl[10];
    #pragma unroll
    for (int m = 0; m < 2; ++m) {
      int o = (wr2 + m*16 + lrow)*136 + kc*32 + koff;
      ph[m] = *(const bf16x8*)&pbuf[o];
      pl[m] = *(const bf16x8*)&pbuf[64*136 + o];
    }
    #pragma unroll
    for (int n = 0; n < 10; ++n) {
      int o = (wcf + n*16 + lrow)*40 + koff;
      kh[n] = *(const bf16x8*)&kth[o];
      kl[n] = *(const bf16x8*)&ktl[o];
    }
    #pragma unroll
    for (int m = 0; m < 2; ++m)
      #pragma unroll
      for (int n = 0; n < 10; ++n) {
        acc3[m][n] = __builtin_amdgcn_mfma_f32_16x16x32_bf16(ph[m], kh[n], acc3[m][n], 0,0,0);
        acc3[m][n] = __builtin_amdgcn_mfma_f32_16x16x32_bf16(ph[m], kl[n], acc3[m][n], 0,0,0);
        acc3[m][n] = __builtin_amdgcn_mfma_f32_16x16x32_bf16(pl[m], kh[n], acc3[m][n], 0,0,0);
      }
  }
  #pragma unroll
  for (int m = 0; m < 2; ++m) {
    int row0 = wr2 + m*16 + (lane >> 4)*4;
    #pragma unroll
    for (int n = 0; n < 10; ++n) {
      int col = wcf + n*16 + lrow;
      if (col < H_) {
        #pragma unroll
        for (int r = 0; r < 4; ++r)
          outp[(size_t)(row0 + r)*H_ + col] = acc3[m][n][r];
      }
    }
  }
}

// ---------------- pool stage 1 ----------------
__global__ __launch_bounds__(320) void k_pool(const float* __restrict__ H,
    const int* __restrict__ plen, const int* __restrict__ hlen,
    float* __restrict__ psum, float* __restrict__ pmax)
{
  int chain = blockIdx.x; int s = chain >> 5, b = chain & 31;
  int c = blockIdx.y; int t0 = c * 16;
  int len = (s == 0 ? plen[b] : hlen[b]);
  int tid = threadIdx.x;
  __shared__ float buf[16*H_];
  const float* hp = H + (size_t)chain*T_*H_ + (size_t)t0*H_;
  for (int i = tid; i < 16*H_; i += 320) buf[i] = hp[i];
  __syncthreads();
  if (tid < H_) {
    int tmax = len - t0; if (tmax > 16) tmax = 16;
    float sum = 0.f, mx = NEGV;
    for (int t = 0; t < tmax; ++t) { float x = buf[t*H_ + tid]; sum += x; mx = fmaxf(mx, x); }
    int o = (chain*8 + c)*H_ + tid;
    psum[o] = sum; pmax[o] = mx;
  }
}

// ---------------- pool stage 2 + classifier ----------------
__global__ __launch_bounds__(320) void k_classify(
    const float* __restrict__ psum, const float* __restrict__ pmax,
    const int* __restrict__ plen, const int* __restrict__ hlen,
    const float* __restrict__ w1t, const float* __restrict__ b1,
    const float* __restrict__ w2, const float* __restrict__ b2,
    float* __restrict__ out)
{
  int b = blockIdx.x;
  int tid = threadIdx.x;
  __shared__ float v[HG];
  __shared__ float hid[H_];
  for (int s = 0; s < 2; ++s) {
    int chain = s*B_ + b;
    int len = (s == 0 ? plen[b] : hlen[b]);
    if (tid < H_) {
      float sum = 0.f, mx = NEGV;
      #pragma unroll
      for (int c = 0; c < 8; ++c) {
        int o = (chain*8 + c)*H_ + tid;
        sum += psum[o]; mx = fmaxf(mx, pmax[o]);
      }
      v[s*600 + tid]       = sum / (float)len;
      v[s*600 + 300 + tid] = mx;
    }
  }
  __syncthreads();
  if (tid < H_) {
    float a0 = b1[tid], a1 = 0.f, a2 = 0.f, a3 = 0.f;
    for (int m = 0; m < HG; m += 4) {
      a0 = fmaf(v[m+0], w1t[(size_t)(m+0)*H_ + tid], a0);
      a1 = fmaf(v[m+1], w1t[(size_t)(m+1)*H_ + tid], a1);
      a2 = fmaf(v[m+2], w1t[(size_t)(m+2)*H_ + tid], a2);
      a3 = fmaf(v[m+3], w1t[(size_t)(m+3)*H_ + tid], a3);
    }
    hid[tid] = tanhf(a0 + a1 + a2 + a3);
  }
  __syncthreads();
  if (tid < 3) {
    float a = b2[tid];
    const float* wr = w2 + (size_t)tid*H_;
    for (int n = 0; n < H_; ++n) a = fmaf(hid[n], wr[n], a);
    out[b*3 + tid] = a;
  }
}

// ---------------- launch ----------------
extern "C" void kernel_launch(void* const* d_in, const int* in_sizes, int n_in,
                              void* d_out, int out_size, void* d_ws, size_t ws_size,
                              hipStream_t stream) {
  const int*   prem    = (const int*)d_in[0];
  const int*   plen    = (const int*)d_in[1];
  const int*   hyp     = (const int*)d_in[2];
  const int*   hlen    = (const int*)d_in[3];
  const float* lg      = (const float*)d_in[4];
  const float* rg      = (const float*)d_in[5];
  const float* emb     = (const float*)d_in[6];
  const float* enc_wx  = (const float*)d_in[7];
  const float* enc_bx  = (const float*)d_in[8];
  const float* enc_uh  = (const float*)d_in[9];
  const float* enc_bh  = (const float*)d_in[10];
  const float* comp_wx = (const float*)d_in[11];
  const float* comp_bx = (const float*)d_in[12];
  const float* comp_uh = (const float*)d_in[13];
  const float* comp_bh = (const float*)d_in[14];
  const float* proj_w  = (const float*)d_in[15];
  const float* proj_b  = (const float*)d_in[16];
  const float* cls_w1  = (const float*)d_in[17];
  const float* cls_b1  = (const float*)d_in[18];
  const float* cls_w2  = (const float*)d_in[19];
  const float* cls_b2  = (const float*)d_in[20];
  float* outp = (float*)d_out;

  // workspace layout (floats); ENH bf16 aliases XG; PROJ/H-split bf16 alias EH/EL
  float* XG  = (float*)d_ws;                       // 9,830,400 f
  ushort_t* EH = (ushort_t*)(XG + 9830400);        // [8192][320] hi (emb -> h-split -> PROJ)
  ushort_t* EL = EH + 2621440;                     // [8192][320] lo
  float* H1  = XG + 9830400 + 2621440;
  float* CH  = H1 + 2457600;                       // ATT alias
  float* FH  = CH + 2457600;
  float* UTE = FH + 2457600;
  float* UTC = UTE + 90000;
  float* W1T = UTC + 90000;
  ushort_t* WencH  = (ushort_t*)(W1T + 360000);
  ushort_t* WencL  = WencH + 384000;
  ushort_t* WcompH = WencL + 384000;
  ushort_t* WcompL = WcompH + 384000;
  ushort_t* WPH    = WcompL + 384000;
  ushort_t* WPL    = WPH + 278400;
  float* PSUM = W1T + 360000 + 1046400;
  float* PMAX = PSUM + 153600;
  float* EW   = PMAX + 153600;
  int* EIDX   = (int*)(EW + 64*ECAP);
  int* CNT    = EIDX + 64*ECAP;
  int* COFF   = CNT + 64*T_;
  int* DEPTH  = COFF + 64*T_;
  int* HASP   = DEPTH + 64*T_;
  int* LVLCNT = HASP + 64*T_;
  int* WL     = LVLCNT + TAILD;
  int* DCNT   = WL + TAILD*WLCAP;
  int* DLIST  = DCNT + 64;
  float* ATT  = CH;
  ushort_t* ENH_H = (ushort_t*)XG;                 // [8192][928] hi (after enc scan, XG dead)
  ushort_t* ENH_L = ENH_H + 7602176;

  hipMemsetAsync(LVLCNT, 0, TAILD*sizeof(int), stream);
  // 1. weight prep + graph analysis + embedding split
  k_prep_all<<<(1496400 + 255)/256, 256, 0, stream>>>(enc_uh, comp_uh, enc_wx, comp_wx, proj_w, cls_w1,
      UTE, UTC, W1T, WencH, WencL, WcompH, WcompL, WPH, WPL);
  k_build<<<64, 256, 0, stream>>>(lg, rg, CNT, COFF, EIDX, EW, HASP, DEPTH, LVLCNT, WL, DCNT, DLIST);
  k_embed_split<<<10240, 256, 0, stream>>>(prem, hyp, emb, EH, EL);
  // 2. enc xg = emb @ enc_wx^T + enc_bx
  k_gemm_bf<0,10><<<dim3(10, 64), 256, 0, stream>>>(EH, EL, 320, WencH, WencL, 320,
      enc_bx, XG, nullptr, nullptr, 0, HG, 0);
  // 3. enc tree scan (levels 0..3 parallel, deep nodes via compact-list parallel-matvec tail)
  for (int L = 0; L < TAILD; ++L)
    k_level<<<640, 1024, 0, stream>>>(XG, enc_bh, UTE, CNT, COFF, EIDX, EW, HASP, LVLCNT, WL, L, H1, CH, FH);
  k_tail<<<64, 1024, 0, stream>>>(XG, enc_bh, enc_uh + H_*H_, CNT, COFF, EIDX, EW, HASP, DCNT, DLIST, H1, CH, FH);
  // 4. h-split + attention (CH dead -> ATT)
  k_h_split<<<10240, 256, 0, stream>>>(H1, EH, EL);
  k_attn_mfma<<<dim3(2, B_, 2), 256, 0, stream>>>(EH, EL, plen, hlen, ATT);
  // 5. enhance split (enc-xg dead), proj GEMM -> PROJ bf16 hi/lo (overwrites EH/EL)
  k_enh_split<<<29696, 256, 0, stream>>>(H1, ATT, ENH_H, ENH_L);
  k_gemm_bf<1,29><<<dim3(3, 64), 256, 0, stream>>>(ENH_H, ENH_L, 928, WPH, WPL, 928,
      proj_b, nullptr, EH, EL, 320, H_, 1);
  // 6. comp xg = proj @ comp_wx^T + comp_bx (overwrites XG)
  k_gemm_bf<0,10><<<dim3(10, 64), 256, 0, stream>>>(EH, EL, 320, WcompH, WcompL, 320,
      comp_bx, XG, nullptr, nullptr, 0, HG, 0);
  // 7. comp tree scan
  for (int L = 0; L < TAILD; ++L)
    k_level<<<640, 1024, 0, stream>>>(XG, comp_bh, UTC, CNT, COFF, EIDX, EW, HASP, LVLCNT, WL, L, H1, CH, FH);
  k_tail<<<64, 1024, 0, stream>>>(XG, comp_bh, comp_uh + H_*H_, CNT, COFF, EIDX, EW, HASP, DCNT, DLIST, H1, CH, FH);
  // 8. pool + classifier
  k_pool<<<dim3(64, 8), 320, 0, stream>>>(H1, plen, hlen, PSUM, PMAX);
  k_classify<<<B_, 320, 0, stream>>>(PSUM, PMAX, plen, hlen, W1T, cls_b1, cls_w2, cls_b2, outp);
}

// Round 19
// 460.817 us; speedup vs baseline: 1.2156x; 1.0349x over previous
//
#include <hip/hip_runtime.h>
#include <math.h>

#define B_ 32
#define T_ 128
#define H_ 300
#define HG 1200   // 4*H
#define TAILD 4   // levels >= TAILD handled by serial per-chain tail
#define WLCAP 8192
#define ECAP 2048
#define GLD 133   // gbuf row stride (floats): bank=(5j+t)%32, conflict-free across 32 lanes
#define NEGV -10000000.0f

typedef __attribute__((ext_vector_type(8))) short bf16x8;
typedef __attribute__((ext_vector_type(4))) float f32x4;
typedef unsigned short ushort_t;

__device__ __forceinline__ float sigm(float x){ return 1.f/(1.f+expf(-x)); }

__device__ __forceinline__ unsigned short f2bf(float x){
  union { float f; unsigned int u; } c; c.f = x;
  unsigned int u = c.u;
  return (unsigned short)((u + 0x7fffu + ((u >> 16) & 1u)) >> 16);
}
__device__ __forceinline__ float bf2f(unsigned short h){
  union { unsigned int u; float f; } c; c.u = ((unsigned int)h) << 16;
  return c.f;
}

// ---------------- fused weight prep: fp32 transposes + bf16 hi/lo padded weights ----------------
__global__ __launch_bounds__(256) void k_prep_all(
    const float* __restrict__ enc_uh, const float* __restrict__ comp_uh,
    const float* __restrict__ enc_wx, const float* __restrict__ comp_wx,
    const float* __restrict__ pw, const float* __restrict__ cw1,
    float* __restrict__ te, float* __restrict__ tc, float* __restrict__ w1t,
    ushort_t* __restrict__ WencH, ushort_t* __restrict__ WencL,
    ushort_t* __restrict__ WcompH, ushort_t* __restrict__ WcompL,
    ushort_t* __restrict__ WPH, ushort_t* __restrict__ WPL)
{
  int i = blockIdx.x*256 + threadIdx.x;
  if (i < 90000) {                       // uh1 transposes: te/tc[m][k] = uh[1][k][m]
    int m = i / H_, k = i - m*H_;
    te[i] = enc_uh[H_*H_ + (size_t)k*H_ + m];
    tc[i] = comp_uh[H_*H_ + (size_t)k*H_ + m];
  } else if (i < 450000) {               // w1t (1200 x 300): w1t[m][k] = cw1[k][m]
    int i2 = i - 90000;
    int m = i2 / H_, k = i2 - m*H_;
    w1t[i2] = cw1[(size_t)k*HG + m];
  } else if (i < 834000) {               // Wenc hi/lo [1200][320], zero-padded
    int i2 = i - 450000;
    int n = i2 / 320, k = i2 - n*320;
    float v = (k < 300) ? enc_wx[(size_t)n*300 + k] : 0.f;
    ushort_t h = f2bf(v);
    WencH[i2] = h; WencL[i2] = f2bf(v - bf2f(h));
  } else if (i < 1218000) {              // Wcomp hi/lo [1200][320]
    int i2 = i - 834000;
    int n = i2 / 320, k = i2 - n*320;
    float v = (k < 300) ? comp_wx[(size_t)n*300 + k] : 0.f;
    ushort_t h = f2bf(v);
    WcompH[i2] = h; WcompL[i2] = f2bf(v - bf2f(h));
  } else if (i < 1496400) {              // folded proj W hi/lo [300][928]
    int i2 = i - 1218000;
    int n = i2 / 928, k = i2 - n*928;
    const float* r = pw + (size_t)n*HG;
    float v = 0.f;
    if (k < 300)      v = r[k] + r[600+k];
    else if (k < 600) v = r[k] - r[k+300];
    else if (k < 900) v = r[k+300];
    ushort_t h = f2bf(v);
    WPH[i2] = h; WPL[i2] = f2bf(v - bf2f(h));
  }
}

// ---------------- embedding gather + bf16 split: [8192][320] hi/lo ----------------
__global__ __launch_bounds__(256) void k_embed_split(const int* __restrict__ prem, const int* __restrict__ hyp,
    const float* __restrict__ emb, ushort_t* __restrict__ EH, ushort_t* __restrict__ EL)
{
  int i = blockIdx.x*256 + threadIdx.x;      // over 8192*320
  int bt = i / 320, k = i - bt*320;
  int side = bt >> 12, bt2 = bt & 4095;
  float v = 0.f;
  if (k < 300) {
    int tok = (side == 0 ? prem : hyp)[bt2];
    v = emb[(size_t)tok*H_ + k];
  }
  ushort_t h = f2bf(v);
  EH[i] = h; EL[i] = f2bf(v - bf2f(h));
}

// ---------------- H1 -> bf16 hi/lo split: [8192][320] (aliases dead EH/EL) ----------------
__global__ __launch_bounds__(256) void k_h_split(const float* __restrict__ H1,
    ushort_t* __restrict__ HH, ushort_t* __restrict__ HL)
{
  int i = blockIdx.x*256 + threadIdx.x;      // over 8192*320
  int r = i / 320, k = i - r*320;
  float v = (k < 300) ? H1[(size_t)r*H_ + k] : 0.f;
  ushort_t h = f2bf(v);
  HH[i] = h; HL[i] = f2bf(v - bf2f(h));
}

// ---------------- enhance + bf16 split: A=[H1|ATT|H1*ATT] -> [8192][928] hi/lo ----------------
__global__ __launch_bounds__(256) void k_enh_split(const float* __restrict__ H1, const float* __restrict__ ATT,
    ushort_t* __restrict__ AH, ushort_t* __restrict__ AL)
{
  int i = blockIdx.x*256 + threadIdx.x;      // over 8192*928
  int r = i / 928, k = i - r*928;
  float v = 0.f;
  if (k < 300)      v = H1[(size_t)r*H_ + k];
  else if (k < 600) v = ATT[(size_t)r*H_ + k - 300];
  else if (k < 900) { int kk = k - 600; v = H1[(size_t)r*H_ + kk] * ATT[(size_t)r*H_ + kk]; }
  ushort_t h = f2bf(v);
  AH[i] = h; AL[i] = f2bf(v - bf2f(h));
}

// ---------------- graph analysis v5: stride-133 LDS + parallel depth relaxation ----------------
__global__ __launch_bounds__(256) void k_build(const float* __restrict__ lg, const float* __restrict__ rg,
    int* __restrict__ cnt_g, int* __restrict__ coff_g, int* __restrict__ eidx_g, float* __restrict__ ew_g,
    int* __restrict__ hasp_g, int* __restrict__ depth_g,
    int* __restrict__ lvlcnt_g, int* __restrict__ wl_g,
    int* __restrict__ dcnt_g, int* __restrict__ dlist_g)
{
  int chain = blockIdx.x; int s = chain >> 5, b = chain & 31;
  const float* graph = (s ? rg : lg) + (size_t)b*T_*T_;
  int tid = threadIdx.x;
  __shared__ float gbuf[T_*GLD];           // ~68 KB, bank-conflict-free row reads
  __shared__ int cnt[T_], coff[T_], depth[T_], hasp[T_];
  __shared__ short eidx[ECAP];
  __shared__ float ew[ECAP];
  __shared__ int lcnt[TAILD], lbase[TAILD], lppos[TAILD], lnpos[TAILD];
  __shared__ int etot_s, changed;

  // stage graph: coalesced global float4 reads -> padded LDS rows (scalar writes)
  for (int i = tid; i < 4096; i += 256) {  // 4096 float4s = 128x128
    float4 v = ((const float4*)graph)[i];
    int row = i >> 5, c0 = (i & 31) * 4;
    float* dst = gbuf + row*GLD + c0;
    dst[0] = v.x; dst[1] = v.y; dst[2] = v.z; dst[3] = v.w;
  }
  if (tid < T_) { hasp[tid] = 0; depth[tid] = 0; }
  if (tid < TAILD) { lcnt[tid] = 0; lppos[tid] = 0; lnpos[tid] = 0; }
  __syncthreads();
  // count children (conflict-free row reads)
  if (tid < T_) {
    int j = tid, c = 0;
    const float* gr = gbuf + j*GLD;
    for (int t = 0; t < j; ++t) c += (gr[t] != 0.f) ? 1 : 0;
    cnt[j] = c;
  }
  __syncthreads();
  if (tid == 0) { int a = 0; for (int j = 0; j < T_; ++j) { coff[j] = a; a += cnt[j]; } etot_s = a; }
  __syncthreads();
  // fill edge lists + parent flags
  if (tid < T_) {
    int j = tid, p = coff[j];
    const float* gr = gbuf + j*GLD;
    for (int t = 0; t < j; ++t) {
      float g = gr[t];
      if (g != 0.f && p < ECAP) { eidx[p] = (short)t; ew[p] = g; hasp[t] = 1; ++p; }
    }
  }
  __syncthreads();
  // parallel depth relaxation (monotone; converges in critical-path sweeps)
  for (int iter = 0; iter < T_; ++iter) {
    if (tid == 0) changed = 0;
    __syncthreads();
    if (tid < T_) {
      int j = tid;
      int d = 0, e0 = coff[j], e1 = e0 + cnt[j];
      if (e1 > ECAP) e1 = ECAP;
      for (int k = e0; k < e1; ++k) { int dd = depth[eidx[k]] + 1; d = dd > d ? dd : d; }
      if (d > depth[j]) { depth[j] = d; changed = 1; }
    }
    __syncthreads();
    if (changed == 0) break;
  }
  // compact deep-node list (position order; ~2 nodes/chain)
  if (tid == 0) {
    int dc = 0;
    for (int j = 0; j < T_; ++j)
      if (depth[j] >= TAILD) dlist_g[chain*T_ + dc++] = j;
    dcnt_g[chain] = dc;
  }
  if (tid < T_) { int L = depth[tid]; if (L < TAILD) atomicAdd(&lcnt[L], 1); }
  __syncthreads();
  if (tid < TAILD && lcnt[tid] > 0) lbase[tid] = atomicAdd(&lvlcnt_g[tid], lcnt[tid]);
  __syncthreads();
  // fill worklist chunk: parented nodes from the front, unparented from the back
  if (tid < T_) {
    int L = depth[tid];
    if (L < TAILD) {
      int pos;
      if (hasp[tid]) { int p = atomicAdd(&lppos[L], 1); pos = p; }
      else           { int p = atomicAdd(&lnpos[L], 1); pos = lcnt[L] - 1 - p; }
      wl_g[L*WLCAP + lbase[L] + pos] = (chain << 8) | tid;
    }
  }
  int base = chain * T_;
  if (tid < T_) {
    cnt_g[base+tid] = cnt[tid]; coff_g[base+tid] = coff[tid];
    hasp_g[base+tid] = hasp[tid]; depth_g[base+tid] = depth[tid];
  }
  int etot = etot_s; if (etot > ECAP) etot = ECAP;
  for (int i = tid; i < etot; i += 256) { eidx_g[chain*ECAP + i] = eidx[i]; ew_g[chain*ECAP + i] = ew[i]; }
}

// ---------------- per-level tree-LSTM (round-10 proven: 4 nodes/block, scalar matvec) ----------------
__global__ __launch_bounds__(1024) void k_level(
    const float* __restrict__ xg, const float* __restrict__ bhv, const float* __restrict__ uh1T,
    const int* __restrict__ cnt_g, const int* __restrict__ coff_g,
    const int* __restrict__ eidx_g, const float* __restrict__ ew_g,
    const int* __restrict__ hasp_g, const int* __restrict__ lvlcnt_g, const int* __restrict__ wl_g,
    int L, float* __restrict__ hout, float* __restrict__ chist, float* __restrict__ fh)
{
  int count = lvlcnt_g[L];
  int nblk = (count + 3) >> 2;
  int tid = threadIdx.x;
  __shared__ float h_s[4][H_];
  __shared__ float psum[3][4][H_];
  __shared__ int nodes[4];
  __shared__ int anyp;
  for (int blk = blockIdx.x; blk < nblk; blk += gridDim.x) {
    int base = blk * 4;
    int nn = count - base; if (nn > 4) nn = 4;
    if (tid == 0) anyp = 0;
    __syncthreads();
    if (tid < 4) {
      int pk = (tid < nn) ? wl_g[L*WLCAP + base + tid] : -1;
      nodes[tid] = pk;
      if (pk >= 0 && hasp_g[(pk >> 8)*T_ + (pk & 255)]) atomicAdd(&anyp, 1);
    }
    __syncthreads();
    for (int w = tid; w < nn*H_; w += 1024) {
      int n = w / H_, e = w - n*H_;
      int pk = nodes[n]; int chain = pk >> 8, j = pk & 255;
      size_t cb = (size_t)chain*T_*H_, xb = (size_t)chain*T_*HG;
      const float* xp = xg + xb + (size_t)j*HG;
      float x0 = xp[e], x1 = xp[H_+e], x2 = xp[2*H_+e], x3 = xp[3*H_+e];
      float iu  = sigm(x0 + bhv[e]) * tanhf(x3 + bhv[3*H_+e]);
      float og  = sigm(x2 + bhv[2*H_+e]);
      float x1b = x1 + bhv[H_+e];
      float acc = iu;
      int c0 = coff_g[chain*T_+j], c1 = c0 + cnt_g[chain*T_+j];
      const int* ei = eidx_g + chain*ECAP;
      const float* ewp = ew_g + chain*ECAP;
      for (int k = c0; k < c1; ++k) {
        int t = ei[k];
        acc += ewp[k] * sigm(x1b + fh[cb + (size_t)t*H_ + e]) * chist[cb + (size_t)t*H_ + e];
      }
      chist[cb + (size_t)j*H_ + e] = acc;
      float hv = og * tanhf(acc);
      hout[cb + (size_t)j*H_ + e] = hv;
      h_s[n][e] = hv;
    }
    __syncthreads();
    if (anyp > 0) {
      if (tid < 3*H_) {
        int g = tid / H_, e = tid - g*H_;
        float a0=0.f, a1=0.f, a2=0.f, a3=0.f;
        const float* up = uh1T + e;
        int m0 = g*100, m1 = m0 + 100;
        #pragma unroll 4
        for (int m = m0; m < m1; ++m) {
          float u = up[(size_t)m*H_];
          a0 = fmaf(u, h_s[0][m], a0);
          a1 = fmaf(u, h_s[1][m], a1);
          a2 = fmaf(u, h_s[2][m], a2);
          a3 = fmaf(u, h_s[3][m], a3);
        }
        psum[g][0][e]=a0; psum[g][1][e]=a1; psum[g][2][e]=a2; psum[g][3][e]=a3;
      }
      __syncthreads();
      for (int w = tid; w < nn*H_; w += 1024) {
        int n = w / H_, e = w - n*H_;
        int pk = nodes[n]; int chain = pk >> 8, j = pk & 255;
        if (hasp_g[chain*T_+j]) {
          size_t cb = (size_t)chain*T_*H_;
          fh[cb + (size_t)j*H_ + e] = psum[0][n][e] + psum[1][n][e] + psum[2][n][e];
        }
      }
    }
    __syncthreads();
  }
}

// ---------------- serial tail v3: compact list + 900-thread contiguous-row matvec ----------------
__global__ __launch_bounds__(1024) void k_tail(const float* __restrict__ xg, const float* __restrict__ bhv,
    const float* __restrict__ uh1row,   // raw uh[1] row-major [k][m] (k=output, m=input)
    const int* __restrict__ cnt_g, const int* __restrict__ coff_g,
    const int* __restrict__ eidx_g, const float* __restrict__ ew_g, const int* __restrict__ hasp_g,
    const int* __restrict__ dcnt_g, const int* __restrict__ dlist_g,
    float* __restrict__ hout, float* __restrict__ chist, float* __restrict__ fh)
{
  int chain = blockIdx.x;
  int dc = dcnt_g[chain];
  if (dc == 0) return;
  int tid = threadIdx.x;
  bool act = tid < H_;
  float bh0=0.f,bh1=0.f,bh2=0.f,bh3=0.f;
  if (act) { bh0=bhv[tid]; bh1=bhv[H_+tid]; bh2=bhv[2*H_+tid]; bh3=bhv[3*H_+tid]; }
  __shared__ float h_lds[H_];
  __shared__ float psum[3][H_];
  __shared__ int djs[T_];
  if (tid < dc) djs[tid] = dlist_g[chain*T_ + tid];
  __syncthreads();
  size_t cb = (size_t)chain*T_*H_, xb = (size_t)chain*T_*HG;
  const int* ei = eidx_g + chain*ECAP;
  const float* ewp = ew_g + chain*ECAP;
  for (int di = 0; di < dc; ++di) {
    int j = djs[di];
    if (act) {
      const float* xp = xg + xb + (size_t)j*HG;
      float x0 = xp[tid], x1 = xp[H_+tid], x2 = xp[2*H_+tid], x3 = xp[3*H_+tid];
      float acc = sigm(x0+bh0) * tanhf(x3+bh3);
      float og  = sigm(x2+bh2);
      float x1b = x1 + bh1;
      int c0 = coff_g[chain*T_+j], c1 = c0 + cnt_g[chain*T_+j];
      for (int k = c0; k < c1; ++k) {
        int t = ei[k];
        acc += ewp[k] * sigm(x1b + fh[cb + (size_t)t*H_ + tid]) * chist[cb + (size_t)t*H_ + tid];
      }
      chist[cb + (size_t)j*H_ + tid] = acc;
      float hv = og * tanhf(acc);
      hout[cb + (size_t)j*H_ + tid] = hv;
      h_lds[tid] = hv;
    }
    __syncthreads();
    if (hasp_g[chain*T_+j]) {
      if (tid < 3*H_) {
        int g = tid / H_, e = tid - g*H_;
        float a = 0.f;
        const float* ur = uh1row + (size_t)e*H_ + g*100;   // contiguous 400B chunk
        #pragma unroll 5
        for (int m = 0; m < 100; m += 4) {
          float4 u4 = *(const float4*)(ur + m);
          float4 h4 = *(const float4*)&h_lds[g*100 + m];
          a = fmaf(u4.x, h4.x, a); a = fmaf(u4.y, h4.y, a);
          a = fmaf(u4.z, h4.z, a); a = fmaf(u4.w, h4.w, a);
        }
        psum[g][e] = a;
      }
      __syncthreads();
      if (act) fh[cb + (size_t)j*H_ + tid] = psum[0][tid] + psum[1][tid] + psum[2][tid];
    }
    __syncthreads();
  }
}

// ---------------- split-bf16 MFMA GEMM v3: 2-deep register prefetch (round-16 proven) ----------------
template<int OUTBF, int NT>
__global__ __launch_bounds__(256) void k_gemm_bf(
    const ushort_t* __restrict__ Ah, const ushort_t* __restrict__ Al, int AS,
    const ushort_t* __restrict__ Wh, const ushort_t* __restrict__ Wl, int WS,
    const float* __restrict__ bias, float* __restrict__ C,
    ushort_t* __restrict__ Ch, ushort_t* __restrict__ Cl, int CS,
    int N, int act)
{
  __shared__ ushort_t sAh[128*32], sAl[128*32], sWh[128*32], sWl[128*32];  // 32 KB
  int tid = threadIdx.x;
  int bn = blockIdx.x * 128, bm = blockIdx.y * 128;
  int lane = tid & 63, wave = tid >> 6;
  int wr = (wave >> 1) * 64, wc = (wave & 1) * 64;
  int lrow = lane & 15, q = lane >> 4;

  int srow = tid >> 1, half = tid & 1;
  int ssw = (srow >> 1) & 3;
  int sg0 = ((2*half) ^ ssw) * 8, sg1 = ((2*half+1) ^ ssw) * 8;
  int sbase = srow * 32;
  const ushort_t* pAh = Ah + (size_t)(bm + srow)*AS + half*16;
  const ushort_t* pAl = Al + (size_t)(bm + srow)*AS + half*16;
  int wrow = bn + srow;
  int wsafe = (wrow < N) ? wrow : 0;
  const ushort_t* pWh = Wh + (size_t)wsafe*WS + half*16;
  const ushort_t* pWl = Wl + (size_t)wsafe*WS + half*16;

  bf16x8 aA0,aA1,aA2,aA3,aW0,aW1,aW2,aW3;   // set A
  bf16x8 bA0,bA1,bA2,bA3,bW0,bW1,bW2,bW3;   // set B

#define ISSUE_SET(P,t) { int kb = (t)*32; \
    P##A0 = *(const bf16x8*)(pAh + kb); P##A1 = *(const bf16x8*)(pAh + kb + 8); \
    P##A2 = *(const bf16x8*)(pAl + kb); P##A3 = *(const bf16x8*)(pAl + kb + 8); \
    P##W0 = *(const bf16x8*)(pWh + kb); P##W1 = *(const bf16x8*)(pWh + kb + 8); \
    P##W2 = *(const bf16x8*)(pWl + kb); P##W3 = *(const bf16x8*)(pWl + kb + 8); }
#define COMMIT_SET(P) { \
    *(bf16x8*)&sAh[sbase + sg0] = P##A0; *(bf16x8*)&sAh[sbase + sg1] = P##A1; \
    *(bf16x8*)&sAl[sbase + sg0] = P##A2; *(bf16x8*)&sAl[sbase + sg1] = P##A3; \
    *(bf16x8*)&sWh[sbase + sg0] = P##W0; *(bf16x8*)&sWh[sbase + sg1] = P##W1; \
    *(bf16x8*)&sWl[sbase + sg0] = P##W2; *(bf16x8*)&sWl[sbase + sg1] = P##W3; }

  f32x4 acc[4][4];
  #pragma unroll
  for (int m = 0; m < 4; ++m)
    #pragma unroll
    for (int n = 0; n < 4; ++n) acc[m][n] = (f32x4){0.f,0.f,0.f,0.f};

#define FRAG_MFMA() { \
    bf16x8 ah[4], al[4], bh[4], bl[4]; \
    _Pragma("unroll") \
    for (int m = 0; m < 4; ++m) { \
      int R = wr + m*16 + lrow; \
      int o = R*32 + ((q ^ ((R>>1)&3)) * 8); \
      ah[m] = *(const bf16x8*)&sAh[o]; \
      al[m] = *(const bf16x8*)&sAl[o]; \
    } \
    _Pragma("unroll") \
    for (int n = 0; n < 4; ++n) { \
      int R = wc + n*16 + lrow; \
      int o = R*32 + ((q ^ ((R>>1)&3)) * 8); \
      bh[n] = *(const bf16x8*)&sWh[o]; \
      bl[n] = *(const bf16x8*)&sWl[o]; \
    } \
    _Pragma("unroll") \
    for (int m = 0; m < 4; ++m) \
      _Pragma("unroll") \
      for (int n = 0; n < 4; ++n) { \
        acc[m][n] = __builtin_amdgcn_mfma_f32_16x16x32_bf16(ah[m], bh[n], acc[m][n], 0,0,0); \
        acc[m][n] = __builtin_amdgcn_mfma_f32_16x16x32_bf16(ah[m], bl[n], acc[m][n], 0,0,0); \
        acc[m][n] = __builtin_amdgcn_mfma_f32_16x16x32_bf16(al[m], bh[n], acc[m][n], 0,0,0); \
      } }

  ISSUE_SET(a, 0); COMMIT_SET(a);
  __syncthreads();
  if (NT > 1) ISSUE_SET(b, 1);
  #pragma unroll
  for (int t = 0; t < NT; t += 2) {
    FRAG_MFMA();
    if (t+2 < NT) ISSUE_SET(a, t+2);
    __syncthreads();
    if (t+1 < NT) COMMIT_SET(b);
    __syncthreads();
    if (t+1 < NT) {
      FRAG_MFMA();
      if (t+3 < NT) ISSUE_SET(b, t+3);
      __syncthreads();
      if (t+2 < NT) COMMIT_SET(a);
      __syncthreads();
    }
  }
#undef ISSUE_SET
#undef COMMIT_SET
#undef FRAG_MFMA

  #pragma unroll
  for (int m = 0; m < 4; ++m) {
    int row0 = bm + wr + m*16 + (lane >> 4)*4;
    #pragma unroll
    for (int n = 0; n < 4; ++n) {
      int col = bn + wc + n*16 + lrow;
      if (OUTBF) {
        if (col < CS) {
          float bv = (col < N) ? bias[col] : 0.f;
          #pragma unroll
          for (int r = 0; r < 4; ++r) {
            float v = 0.f;
            if (col < N) { v = acc[m][n][r] + bv; if (act) v = fmaxf(v, 0.f); }
            ushort_t h = f2bf(v);
            Ch[(size_t)(row0 + r)*CS + col] = h;
            Cl[(size_t)(row0 + r)*CS + col] = f2bf(v - bf2f(h));
          }
        }
      } else {
        if (col < N) {
          float bv = bias[col];
          #pragma unroll
          for (int r = 0; r < 4; ++r) {
            float v = acc[m][n][r] + bv;
            if (act) v = fmaxf(v, 0.f);
            C[(size_t)(row0 + r)*N + col] = v;
          }
        }
      }
    }
  }
}

// ---------------- fused MFMA attention v2: bf16 pre-split inputs (round-13) ----------------
__global__ __launch_bounds__(256) void k_attn_mfma(
    const ushort_t* __restrict__ HH, const ushort_t* __restrict__ HL,
    const int* __restrict__ plen, const int* __restrict__ hlen,
    float* __restrict__ ATT)
{
  __shared__ float regA_f[12800];
  __shared__ ushort_t pbuf[2*64*136];
  ushort_t* regA = (ushort_t*)regA_f;

  int tid = threadIdx.x;
  int lane = tid & 63, wave = tid >> 6;
  int lrow = lane & 15, koff = (lane >> 4) * 8;
  int d = blockIdx.x, b = blockIdx.y, q0 = blockIdx.z * 64;
  int qbase = (d*B_ + b)*T_ + q0;
  int kbase = ((1-d)*B_ + b)*T_;
  float* outp = ATT + ((size_t)(d*B_ + b)*T_ + q0) * H_;
  int klen = (d == 0) ? hlen[b] : plen[b];

  ushort_t* sQh = regA;            // [64][40]
  ushort_t* sQl = regA + 2560;
  ushort_t* sKh = regA + 5120;     // [128][40]
  ushort_t* sKl = regA + 10240;
  int qrow = tid >> 2, qo = (tid & 3) * 8;
  int krow = tid >> 1, ko = (tid & 1) * 16;
  const ushort_t* Qh = HH + (size_t)(qbase + qrow)*320 + qo;
  const ushort_t* Ql = HL + (size_t)(qbase + qrow)*320 + qo;
  const ushort_t* Kh = HH + (size_t)(kbase + krow)*320 + ko;
  const ushort_t* Kl = HL + (size_t)(kbase + krow)*320 + ko;

  bf16x8 rqh, rql, rkh0, rkh1, rkl0, rkl1;
  auto issue1 = [&](int t){
    int kb = t*32;
    rqh  = *(const bf16x8*)(Qh + kb);
    rql  = *(const bf16x8*)(Ql + kb);
    rkh0 = *(const bf16x8*)(Kh + kb); rkh1 = *(const bf16x8*)(Kh + kb + 8);
    rkl0 = *(const bf16x8*)(Kl + kb); rkl1 = *(const bf16x8*)(Kl + kb + 8);
  };
  auto commit1 = [&](){
    *(bf16x8*)&sQh[qrow*40 + qo] = rqh;
    *(bf16x8*)&sQl[qrow*40 + qo] = rql;
    *(bf16x8*)&sKh[krow*40 + ko] = rkh0; *(bf16x8*)&sKh[krow*40 + ko + 8] = rkh1;
    *(bf16x8*)&sKl[krow*40 + ko] = rkl0; *(bf16x8*)&sKl[krow*40 + ko + 8] = rkl1;
  };

  f32x4 acc1[4][2];
  #pragma unroll
  for (int m = 0; m < 4; ++m)
    #pragma unroll
    for (int n = 0; n < 2; ++n) acc1[m][n] = (f32x4){0.f,0.f,0.f,0.f};
  int wc = wave * 32;

  issue1(0); commit1();
  __syncthreads();
  for (int t = 0; t < 10; ++t) {
    bool more = (t < 9);
    bf16x8 ah[4], al[4], bh[2], bl[2];
    #pragma unroll
    for (int m = 0; m < 4; ++m) {
      int o = (m*16 + lrow)*40 + koff;
      ah[m] = *(const bf16x8*)&sQh[o];
      al[m] = *(const bf16x8*)&sQl[o];
    }
    #pragma unroll
    for (int n = 0; n < 2; ++n) {
      int o = (wc + n*16 + lrow)*40 + koff;
      bh[n] = *(const bf16x8*)&sKh[o];
      bl[n] = *(const bf16x8*)&sKl[o];
    }
    if (more) issue1(t+1);
    __syncthreads();
    if (more) commit1();
    #pragma unroll
    for (int m = 0; m < 4; ++m)
      #pragma unroll
      for (int n = 0; n < 2; ++n) {
        acc1[m][n] = __builtin_amdgcn_mfma_f32_16x16x32_bf16(ah[m], bh[n], acc1[m][n], 0,0,0);
        acc1[m][n] = __builtin_amdgcn_mfma_f32_16x16x32_bf16(ah[m], bl[n], acc1[m][n], 0,0,0);
        acc1[m][n] = __builtin_amdgcn_mfma_f32_16x16x32_bf16(al[m], bh[n], acc1[m][n], 0,0,0);
      }
    __syncthreads();
  }
  float* sim = regA_f;
  #pragma unroll
  for (int m = 0; m < 4; ++m)
    #pragma unroll
    for (int n = 0; n < 2; ++n)
      #pragma unroll
      for (int r = 0; r < 4; ++r)
        sim[(m*16 + (lane>>4)*4 + r)*132 + wc + n*16 + lrow] = acc1[m][n][r];
  __syncthreads();

  {
    int row = tid >> 2, qtr = (tid & 3) * 32;
    const float* sr = sim + row*132;
    float mx = NEGV;
    for (int c = 0; c < 32; ++c) { int cg = qtr + c; float s = (cg < klen) ? sr[cg] : NEGV; mx = fmaxf(mx, s); }
    mx = fmaxf(mx, __shfl_xor(mx, 1));
    mx = fmaxf(mx, __shfl_xor(mx, 2));
    float sum = 0.f;
    for (int c = 0; c < 32; ++c) { int cg = qtr + c; if (cg < klen) sum += expf(sr[cg] - mx); }
    sum += __shfl_xor(sum, 1);
    sum += __shfl_xor(sum, 2);
    float rinv = 1.f / sum;
    for (int c = 0; c < 32; ++c) {
      int cg = qtr + c;
      float p = (cg < klen) ? expf(sr[cg] - mx) * rinv : 0.f;
      ushort_t h = f2bf(p);
      pbuf[row*136 + cg] = h;
      pbuf[64*136 + row*136 + cg] = f2bf(p - bf2f(h));
    }
  }
  __syncthreads();

  ushort_t* kth = regA;            // [320][40]
  ushort_t* ktl = regA + 12800;
  int wr2 = (wave & 1) * 32;
  int wcf = (wave >> 1) * 160;
  f32x4 acc3[2][10];
  #pragma unroll
  for (int m = 0; m < 2; ++m)
    #pragma unroll
    for (int n = 0; n < 10; ++n) acc3[m][n] = (f32x4){0.f,0.f,0.f,0.f};
  int skey = tid >> 3, sf8 = tid & 7;

  for (int kc = 0; kc < 4; ++kc) {
    __syncthreads();
    int key = kbase + kc*32 + skey;
    const ushort_t* krh = HH + (size_t)key*320;
    const ushort_t* krl = HL + (size_t)key*320;
    for (int f8 = sf8; f8 < 40; f8 += 8) {
      bf16x8 vh = *(const bf16x8*)(krh + f8*8);
      bf16x8 vl = *(const bf16x8*)(krl + f8*8);
      #pragma unroll
      for (int i = 0; i < 8; ++i) {
        int feat = f8*8 + i;
        kth[feat*40 + skey] = (ushort_t)vh[i];
        ktl[feat*40 + skey] = (ushort_t)vl[i];
      }
    }
    __syncthreads();
    bf16x8 ph[2], pl[2], kh[10], kl[10];
    #pragma unroll
    for (int m = 0; m < 2; ++m) {
      int o = (wr2 + m*16 + lrow)*136 + kc*32 + koff;
      ph[m] = *(const bf16x8*)&pbuf[o];
      pl[m] = *(const bf16x8*)&pbuf[64*136 + o];
    }
    #pragma unroll
    for (int n = 0; n < 10; ++n) {
      int o = (wcf + n*16 + lrow)*40 + koff;
      kh[n] = *(const bf16x8*)&kth[o];
      kl[n] = *(const bf16x8*)&ktl[o];
    }
    #pragma unroll
    for (int m = 0; m < 2; ++m)
      #pragma unroll
      for (int n = 0; n < 10; ++n) {
        acc3[m][n] = __builtin_amdgcn_mfma_f32_16x16x32_bf16(ph[m], kh[n], acc3[m][n], 0,0,0);
        acc3[m][n] = __builtin_amdgcn_mfma_f32_16x16x32_bf16(ph[m], kl[n], acc3[m][n], 0,0,0);
        acc3[m][n] = __builtin_amdgcn_mfma_f32_16x16x32_bf16(pl[m], kh[n], acc3[m][n], 0,0,0);
      }
  }
  #pragma unroll
  for (int m = 0; m < 2; ++m) {
    int row0 = wr2 + m*16 + (lane >> 4)*4;
    #pragma unroll
    for (int n = 0; n < 10; ++n) {
      int col = wcf + n*16 + lrow;
      if (col < H_) {
        #pragma unroll
        for (int r = 0; r < 4; ++r)
          outp[(size_t)(row0 + r)*H_ + col] = acc3[m][n][r];
      }
    }
  }
}

// ---------------- pool stage 1 ----------------
__global__ __launch_bounds__(320) void k_pool(const float* __restrict__ H,
    const int* __restrict__ plen, const int* __restrict__ hlen,
    float* __restrict__ psum, float* __restrict__ pmax)
{
  int chain = blockIdx.x; int s = chain >> 5, b = chain & 31;
  int c = blockIdx.y; int t0 = c * 16;
  int len = (s == 0 ? plen[b] : hlen[b]);
  int tid = threadIdx.x;
  __shared__ float buf[16*H_];
  const float* hp = H + (size_t)chain*T_*H_ + (size_t)t0*H_;
  for (int i = tid; i < 16*H_; i += 320) buf[i] = hp[i];
  __syncthreads();
  if (tid < H_) {
    int tmax = len - t0; if (tmax > 16) tmax = 16;
    float sum = 0.f, mx = NEGV;
    for (int t = 0; t < tmax; ++t) { float x = buf[t*H_ + tid]; sum += x; mx = fmaxf(mx, x); }
    int o = (chain*8 + c)*H_ + tid;
    psum[o] = sum; pmax[o] = mx;
  }
}

// ---------------- pool stage 2 + classifier ----------------
__global__ __launch_bounds__(320) void k_classify(
    const float* __restrict__ psum, const float* __restrict__ pmax,
    const int* __restrict__ plen, const int* __restrict__ hlen,
    const float* __restrict__ w1t, const float* __restrict__ b1,
    const float* __restrict__ w2, const float* __restrict__ b2,
    float* __restrict__ out)
{
  int b = blockIdx.x;
  int tid = threadIdx.x;
  __shared__ float v[HG];
  __shared__ float hid[H_];
  for (int s = 0; s < 2; ++s) {
    int chain = s*B_ + b;
    int len = (s == 0 ? plen[b] : hlen[b]);
    if (tid < H_) {
      float sum = 0.f, mx = NEGV;
      #pragma unroll
      for (int c = 0; c < 8; ++c) {
        int o = (chain*8 + c)*H_ + tid;
        sum += psum[o]; mx = fmaxf(mx, pmax[o]);
      }
      v[s*600 + tid]       = sum / (float)len;
      v[s*600 + 300 + tid] = mx;
    }
  }
  __syncthreads();
  if (tid < H_) {
    float a0 = b1[tid], a1 = 0.f, a2 = 0.f, a3 = 0.f;
    for (int m = 0; m < HG; m += 4) {
      a0 = fmaf(v[m+0], w1t[(size_t)(m+0)*H_ + tid], a0);
      a1 = fmaf(v[m+1], w1t[(size_t)(m+1)*H_ + tid], a1);
      a2 = fmaf(v[m+2], w1t[(size_t)(m+2)*H_ + tid], a2);
      a3 = fmaf(v[m+3], w1t[(size_t)(m+3)*H_ + tid], a3);
    }
    hid[tid] = tanhf(a0 + a1 + a2 + a3);
  }
  __syncthreads();
  if (tid < 3) {
    float a = b2[tid];
    const float* wr = w2 + (size_t)tid*H_;
    for (int n = 0; n < H_; ++n) a = fmaf(hid[n], wr[n], a);
    out[b*3 + tid] = a;
  }
}

// ---------------- launch ----------------
extern "C" void kernel_launch(void* const* d_in, const int* in_sizes, int n_in,
                              void* d_out, int out_size, void* d_ws, size_t ws_size,
                              hipStream_t stream) {
  const int*   prem    = (const int*)d_in[0];
  const int*   plen    = (const int*)d_in[1];
  const int*   hyp     = (const int*)d_in[2];
  const int*   hlen    = (const int*)d_in[3];
  const float* lg      = (const float*)d_in[4];
  const float* rg      = (const float*)d_in[5];
  const float* emb     = (const float*)d_in[6];
  const float* enc_wx  = (const float*)d_in[7];
  const float* enc_bx  = (const float*)d_in[8];
  const float* enc_uh  = (const float*)d_in[9];
  const float* enc_bh  = (const float*)d_in[10];
  const float* comp_wx = (const float*)d_in[11];
  const float* comp_bx = (const float*)d_in[12];
  const float* comp_uh = (const float*)d_in[13];
  const float* comp_bh = (const float*)d_in[14];
  const float* proj_w  = (const float*)d_in[15];
  const float* proj_b  = (const float*)d_in[16];
  const float* cls_w1  = (const float*)d_in[17];
  const float* cls_b1  = (const float*)d_in[18];
  const float* cls_w2  = (const float*)d_in[19];
  const float* cls_b2  = (const float*)d_in[20];
  float* outp = (float*)d_out;

  // workspace layout (floats); ENH bf16 aliases XG; PROJ/H-split bf16 alias EH/EL
  float* XG  = (float*)d_ws;                       // 9,830,400 f
  ushort_t* EH = (ushort_t*)(XG + 9830400);        // [8192][320] hi (emb -> h-split -> PROJ)
  ushort_t* EL = EH + 2621440;                     // [8192][320] lo
  float* H1  = XG + 9830400 + 2621440;
  float* CH  = H1 + 2457600;                       // ATT alias
  float* FH  = CH + 2457600;
  float* UTE = FH + 2457600;
  float* UTC = UTE + 90000;
  float* W1T = UTC + 90000;
  ushort_t* WencH  = (ushort_t*)(W1T + 360000);
  ushort_t* WencL  = WencH + 384000;
  ushort_t* WcompH = WencL + 384000;
  ushort_t* WcompL = WcompH + 384000;
  ushort_t* WPH    = WcompL + 384000;
  ushort_t* WPL    = WPH + 278400;
  float* PSUM = W1T + 360000 + 1046400;
  float* PMAX = PSUM + 153600;
  float* EW   = PMAX + 153600;
  int* EIDX   = (int*)(EW + 64*ECAP);
  int* CNT    = EIDX + 64*ECAP;
  int* COFF   = CNT + 64*T_;
  int* DEPTH  = COFF + 64*T_;
  int* HASP   = DEPTH + 64*T_;
  int* LVLCNT = HASP + 64*T_;
  int* WL     = LVLCNT + TAILD;
  int* DCNT   = WL + TAILD*WLCAP;
  int* DLIST  = DCNT + 64;
  float* ATT  = CH;
  ushort_t* ENH_H = (ushort_t*)XG;                 // [8192][928] hi (after enc scan, XG dead)
  ushort_t* ENH_L = ENH_H + 7602176;

  hipMemsetAsync(LVLCNT, 0, TAILD*sizeof(int), stream);
  // 1. weight prep + graph analysis + embedding split
  k_prep_all<<<(1496400 + 255)/256, 256, 0, stream>>>(enc_uh, comp_uh, enc_wx, comp_wx, proj_w, cls_w1,
      UTE, UTC, W1T, WencH, WencL, WcompH, WcompL, WPH, WPL);
  k_build<<<64, 256, 0, stream>>>(lg, rg, CNT, COFF, EIDX, EW, HASP, DEPTH, LVLCNT, WL, DCNT, DLIST);
  k_embed_split<<<10240, 256, 0, stream>>>(prem, hyp, emb, EH, EL);
  // 2. enc xg = emb @ enc_wx^T + enc_bx
  k_gemm_bf<0,10><<<dim3(10, 64), 256, 0, stream>>>(EH, EL, 320, WencH, WencL, 320,
      enc_bx, XG, nullptr, nullptr, 0, HG, 0);
  // 3. enc tree scan (levels 0..3 parallel, deep nodes via compact-list parallel-matvec tail)
  for (int L = 0; L < TAILD; ++L)
    k_level<<<640, 1024, 0, stream>>>(XG, enc_bh, UTE, CNT, COFF, EIDX, EW, HASP, LVLCNT, WL, L, H1, CH, FH);
  k_tail<<<64, 1024, 0, stream>>>(XG, enc_bh, enc_uh + H_*H_, CNT, COFF, EIDX, EW, HASP, DCNT, DLIST, H1, CH, FH);
  // 4. h-split + attention (CH dead -> ATT)
  k_h_split<<<10240, 256, 0, stream>>>(H1, EH, EL);
  k_attn_mfma<<<dim3(2, B_, 2), 256, 0, stream>>>(EH, EL, plen, hlen, ATT);
  // 5. enhance split (enc-xg dead), proj GEMM -> PROJ bf16 hi/lo (overwrites EH/EL)
  k_enh_split<<<29696, 256, 0, stream>>>(H1, ATT, ENH_H, ENH_L);
  k_gemm_bf<1,29><<<dim3(3, 64), 256, 0, stream>>>(ENH_H, ENH_L, 928, WPH, WPL, 928,
      proj_b, nullptr, EH, EL, 320, H_, 1);
  // 6. comp xg = proj @ comp_wx^T + comp_bx (overwrites XG)
  k_gemm_bf<0,10><<<dim3(10, 64), 256, 0, stream>>>(EH, EL, 320, WcompH, WcompL, 320,
      comp_bx, XG, nullptr, nullptr, 0, HG, 0);
  // 7. comp tree scan
  for (int L = 0; L < TAILD; ++L)
    k_level<<<640, 1024, 0, stream>>>(XG, comp_bh, UTC, CNT, COFF, EIDX, EW, HASP, LVLCNT, WL, L, H1, CH, FH);
  k_tail<<<64, 1024, 0, stream>>>(XG, comp_bh, comp_uh + H_*H_, CNT, COFF, EIDX, EW, HASP, DCNT, DLIST, H1, CH, FH);
  // 8. pool + classifier
  k_pool<<<dim3(64, 8), 320, 0, stream>>>(H1, plen, hlen, PSUM, PMAX);
  k_classify<<<B_, 320, 0, stream>>>(PSUM, PMAX, plen, hlen, W1T, cls_b1, cls_w2, cls_b2, outp);
}

// Round 20
// 453.150 us; speedup vs baseline: 1.2361x; 1.0169x over previous
//
#include <hip/hip_runtime.h>
#include <math.h>

#define B_ 32
#define T_ 128
#define H_ 300
#define HG 1200   // 4*H
#define TAILD 4   // levels >= TAILD handled by serial per-chain tail
#define WLCAP 8192
#define ECAP 2048
#define GLD 133   // gbuf row stride (floats): bank=(5j+t)%32, conflict-free across 32 lanes
#define NEGV -10000000.0f

typedef __attribute__((ext_vector_type(8))) short bf16x8;
typedef __attribute__((ext_vector_type(4))) float f32x4;
typedef unsigned short ushort_t;

__device__ __forceinline__ float sigm(float x){ return 1.f/(1.f+expf(-x)); }

__device__ __forceinline__ unsigned short f2bf(float x){
  union { float f; unsigned int u; } c; c.f = x;
  unsigned int u = c.u;
  return (unsigned short)((u + 0x7fffu + ((u >> 16) & 1u)) >> 16);
}
__device__ __forceinline__ float bf2f(unsigned short h){
  union { unsigned int u; float f; } c; c.u = ((unsigned int)h) << 16;
  return c.f;
}

// ---------------- fused weight prep: fp32 transposes + bf16 hi/lo padded weights ----------------
__global__ __launch_bounds__(256) void k_prep_all(
    const float* __restrict__ enc_uh, const float* __restrict__ comp_uh,
    const float* __restrict__ enc_wx, const float* __restrict__ comp_wx,
    const float* __restrict__ pw, const float* __restrict__ cw1,
    float* __restrict__ te, float* __restrict__ tc, float* __restrict__ w1t,
    ushort_t* __restrict__ WencH, ushort_t* __restrict__ WencL,
    ushort_t* __restrict__ WcompH, ushort_t* __restrict__ WcompL,
    ushort_t* __restrict__ WPH, ushort_t* __restrict__ WPL)
{
  int i = blockIdx.x*256 + threadIdx.x;
  if (i < 90000) {                       // uh1 transposes: te/tc[m][k] = uh[1][k][m]
    int m = i / H_, k = i - m*H_;
    te[i] = enc_uh[H_*H_ + (size_t)k*H_ + m];
    tc[i] = comp_uh[H_*H_ + (size_t)k*H_ + m];
  } else if (i < 450000) {               // w1t (1200 x 300): w1t[m][k] = cw1[k][m]
    int i2 = i - 90000;
    int m = i2 / H_, k = i2 - m*H_;
    w1t[i2] = cw1[(size_t)k*HG + m];
  } else if (i < 834000) {               // Wenc hi/lo [1200][320], zero-padded
    int i2 = i - 450000;
    int n = i2 / 320, k = i2 - n*320;
    float v = (k < 300) ? enc_wx[(size_t)n*300 + k] : 0.f;
    ushort_t h = f2bf(v);
    WencH[i2] = h; WencL[i2] = f2bf(v - bf2f(h));
  } else if (i < 1218000) {              // Wcomp hi/lo [1200][320]
    int i2 = i - 834000;
    int n = i2 / 320, k = i2 - n*320;
    float v = (k < 300) ? comp_wx[(size_t)n*300 + k] : 0.f;
    ushort_t h = f2bf(v);
    WcompH[i2] = h; WcompL[i2] = f2bf(v - bf2f(h));
  } else if (i < 1496400) {              // folded proj W hi/lo [300][928]
    int i2 = i - 1218000;
    int n = i2 / 928, k = i2 - n*928;
    const float* r = pw + (size_t)n*HG;
    float v = 0.f;
    if (k < 300)      v = r[k] + r[600+k];
    else if (k < 600) v = r[k] - r[k+300];
    else if (k < 900) v = r[k+300];
    ushort_t h = f2bf(v);
    WPH[i2] = h; WPL[i2] = f2bf(v - bf2f(h));
  }
}

// ---------------- embedding gather + bf16 split: [8192][320] hi/lo ----------------
__global__ __launch_bounds__(256) void k_embed_split(const int* __restrict__ prem, const int* __restrict__ hyp,
    const float* __restrict__ emb, ushort_t* __restrict__ EH, ushort_t* __restrict__ EL)
{
  int i = blockIdx.x*256 + threadIdx.x;      // over 8192*320
  int bt = i / 320, k = i - bt*320;
  int side = bt >> 12, bt2 = bt & 4095;
  float v = 0.f;
  if (k < 300) {
    int tok = (side == 0 ? prem : hyp)[bt2];
    v = emb[(size_t)tok*H_ + k];
  }
  ushort_t h = f2bf(v);
  EH[i] = h; EL[i] = f2bf(v - bf2f(h));
}

// ---------------- H1 -> bf16 hi/lo split: [8192][320] (aliases dead EH/EL) ----------------
__global__ __launch_bounds__(256) void k_h_split(const float* __restrict__ H1,
    ushort_t* __restrict__ HH, ushort_t* __restrict__ HL)
{
  int i = blockIdx.x*256 + threadIdx.x;      // over 8192*320
  int r = i / 320, k = i - r*320;
  float v = (k < 300) ? H1[(size_t)r*H_ + k] : 0.f;
  ushort_t h = f2bf(v);
  HH[i] = h; HL[i] = f2bf(v - bf2f(h));
}

// ---------------- enhance + bf16 split: A=[H1|ATT|H1*ATT] -> [8192][928] hi/lo ----------------
__global__ __launch_bounds__(256) void k_enh_split(const float* __restrict__ H1, const float* __restrict__ ATT,
    ushort_t* __restrict__ AH, ushort_t* __restrict__ AL)
{
  int i = blockIdx.x*256 + threadIdx.x;      // over 8192*928
  int r = i / 928, k = i - r*928;
  float v = 0.f;
  if (k < 300)      v = H1[(size_t)r*H_ + k];
  else if (k < 600) v = ATT[(size_t)r*H_ + k - 300];
  else if (k < 900) { int kk = k - 600; v = H1[(size_t)r*H_ + kk] * ATT[(size_t)r*H_ + kk]; }
  ushort_t h = f2bf(v);
  AH[i] = h; AL[i] = f2bf(v - bf2f(h));
}

// ---------------- graph analysis v5: stride-133 LDS + parallel depth relaxation ----------------
__global__ __launch_bounds__(256) void k_build(const float* __restrict__ lg, const float* __restrict__ rg,
    int* __restrict__ cnt_g, int* __restrict__ coff_g, int* __restrict__ eidx_g, float* __restrict__ ew_g,
    int* __restrict__ hasp_g, int* __restrict__ depth_g,
    int* __restrict__ lvlcnt_g, int* __restrict__ wl_g,
    int* __restrict__ dcnt_g, int* __restrict__ dlist_g)
{
  int chain = blockIdx.x; int s = chain >> 5, b = chain & 31;
  const float* graph = (s ? rg : lg) + (size_t)b*T_*T_;
  int tid = threadIdx.x;
  __shared__ float gbuf[T_*GLD];           // ~68 KB, bank-conflict-free row reads
  __shared__ int cnt[T_], coff[T_], depth[T_], hasp[T_];
  __shared__ short eidx[ECAP];
  __shared__ float ew[ECAP];
  __shared__ int lcnt[TAILD], lbase[TAILD], lppos[TAILD], lnpos[TAILD];
  __shared__ int etot_s, changed;

  // stage graph: coalesced global float4 reads -> padded LDS rows (scalar writes)
  for (int i = tid; i < 4096; i += 256) {  // 4096 float4s = 128x128
    float4 v = ((const float4*)graph)[i];
    int row = i >> 5, c0 = (i & 31) * 4;
    float* dst = gbuf + row*GLD + c0;
    dst[0] = v.x; dst[1] = v.y; dst[2] = v.z; dst[3] = v.w;
  }
  if (tid < T_) { hasp[tid] = 0; depth[tid] = 0; }
  if (tid < TAILD) { lcnt[tid] = 0; lppos[tid] = 0; lnpos[tid] = 0; }
  __syncthreads();
  // count children (conflict-free row reads)
  if (tid < T_) {
    int j = tid, c = 0;
    const float* gr = gbuf + j*GLD;
    for (int t = 0; t < j; ++t) c += (gr[t] != 0.f) ? 1 : 0;
    cnt[j] = c;
  }
  __syncthreads();
  if (tid == 0) { int a = 0; for (int j = 0; j < T_; ++j) { coff[j] = a; a += cnt[j]; } etot_s = a; }
  __syncthreads();
  // fill edge lists + parent flags
  if (tid < T_) {
    int j = tid, p = coff[j];
    const float* gr = gbuf + j*GLD;
    for (int t = 0; t < j; ++t) {
      float g = gr[t];
      if (g != 0.f && p < ECAP) { eidx[p] = (short)t; ew[p] = g; hasp[t] = 1; ++p; }
    }
  }
  __syncthreads();
  // parallel depth relaxation (monotone; converges in critical-path sweeps)
  for (int iter = 0; iter < T_; ++iter) {
    if (tid == 0) changed = 0;
    __syncthreads();
    if (tid < T_) {
      int j = tid;
      int d = 0, e0 = coff[j], e1 = e0 + cnt[j];
      if (e1 > ECAP) e1 = ECAP;
      for (int k = e0; k < e1; ++k) { int dd = depth[eidx[k]] + 1; d = dd > d ? dd : d; }
      if (d > depth[j]) { depth[j] = d; changed = 1; }
    }
    __syncthreads();
    if (changed == 0) break;
  }
  // compact deep-node list (position order; ~2 nodes/chain)
  if (tid == 0) {
    int dc = 0;
    for (int j = 0; j < T_; ++j)
      if (depth[j] >= TAILD) dlist_g[chain*T_ + dc++] = j;
    dcnt_g[chain] = dc;
  }
  if (tid < T_) { int L = depth[tid]; if (L < TAILD) atomicAdd(&lcnt[L], 1); }
  __syncthreads();
  if (tid < TAILD && lcnt[tid] > 0) lbase[tid] = atomicAdd(&lvlcnt_g[tid], lcnt[tid]);
  __syncthreads();
  // fill worklist chunk: parented nodes from the front, unparented from the back
  if (tid < T_) {
    int L = depth[tid];
    if (L < TAILD) {
      int pos;
      if (hasp[tid]) { int p = atomicAdd(&lppos[L], 1); pos = p; }
      else           { int p = atomicAdd(&lnpos[L], 1); pos = lcnt[L] - 1 - p; }
      wl_g[L*WLCAP + lbase[L] + pos] = (chain << 8) | tid;
    }
  }
  int base = chain * T_;
  if (tid < T_) {
    cnt_g[base+tid] = cnt[tid]; coff_g[base+tid] = coff[tid];
    hasp_g[base+tid] = hasp[tid]; depth_g[base+tid] = depth[tid];
  }
  int etot = etot_s; if (etot > ECAP) etot = ECAP;
  for (int i = tid; i < etot; i += 256) { eidx_g[chain*ECAP + i] = eidx[i]; ew_g[chain*ECAP + i] = ew[i]; }
}

// ---------------- per-level tree-LSTM (round-10 proven: 4 nodes/block, scalar matvec) ----------------
__global__ __launch_bounds__(1024) void k_level(
    const float* __restrict__ xg, const float* __restrict__ bhv, const float* __restrict__ uh1T,
    const int* __restrict__ cnt_g, const int* __restrict__ coff_g,
    const int* __restrict__ eidx_g, const float* __restrict__ ew_g,
    const int* __restrict__ hasp_g, const int* __restrict__ lvlcnt_g, const int* __restrict__ wl_g,
    int L, float* __restrict__ hout, float* __restrict__ chist, float* __restrict__ fh)
{
  int count = lvlcnt_g[L];
  int nblk = (count + 3) >> 2;
  int tid = threadIdx.x;
  __shared__ float h_s[4][H_];
  __shared__ float psum[3][4][H_];
  __shared__ int nodes[4];
  __shared__ int anyp;
  for (int blk = blockIdx.x; blk < nblk; blk += gridDim.x) {
    int base = blk * 4;
    int nn = count - base; if (nn > 4) nn = 4;
    if (tid == 0) anyp = 0;
    __syncthreads();
    if (tid < 4) {
      int pk = (tid < nn) ? wl_g[L*WLCAP + base + tid] : -1;
      nodes[tid] = pk;
      if (pk >= 0 && hasp_g[(pk >> 8)*T_ + (pk & 255)]) atomicAdd(&anyp, 1);
    }
    __syncthreads();
    for (int w = tid; w < nn*H_; w += 1024) {
      int n = w / H_, e = w - n*H_;
      int pk = nodes[n]; int chain = pk >> 8, j = pk & 255;
      size_t cb = (size_t)chain*T_*H_, xb = (size_t)chain*T_*HG;
      const float* xp = xg + xb + (size_t)j*HG;
      float x0 = xp[e], x1 = xp[H_+e], x2 = xp[2*H_+e], x3 = xp[3*H_+e];
      float iu  = sigm(x0 + bhv[e]) * tanhf(x3 + bhv[3*H_+e]);
      float og  = sigm(x2 + bhv[2*H_+e]);
      float x1b = x1 + bhv[H_+e];
      float acc = iu;
      int c0 = coff_g[chain*T_+j], c1 = c0 + cnt_g[chain*T_+j];
      const int* ei = eidx_g + chain*ECAP;
      const float* ewp = ew_g + chain*ECAP;
      for (int k = c0; k < c1; ++k) {
        int t = ei[k];
        acc += ewp[k] * sigm(x1b + fh[cb + (size_t)t*H_ + e]) * chist[cb + (size_t)t*H_ + e];
      }
      chist[cb + (size_t)j*H_ + e] = acc;
      float hv = og * tanhf(acc);
      hout[cb + (size_t)j*H_ + e] = hv;
      h_s[n][e] = hv;
    }
    __syncthreads();
    if (anyp > 0) {
      if (tid < 3*H_) {
        int g = tid / H_, e = tid - g*H_;
        float a0=0.f, a1=0.f, a2=0.f, a3=0.f;
        const float* up = uh1T + e;
        int m0 = g*100, m1 = m0 + 100;
        #pragma unroll 4
        for (int m = m0; m < m1; ++m) {
          float u = up[(size_t)m*H_];
          a0 = fmaf(u, h_s[0][m], a0);
          a1 = fmaf(u, h_s[1][m], a1);
          a2 = fmaf(u, h_s[2][m], a2);
          a3 = fmaf(u, h_s[3][m], a3);
        }
        psum[g][0][e]=a0; psum[g][1][e]=a1; psum[g][2][e]=a2; psum[g][3][e]=a3;
      }
      __syncthreads();
      for (int w = tid; w < nn*H_; w += 1024) {
        int n = w / H_, e = w - n*H_;
        int pk = nodes[n]; int chain = pk >> 8, j = pk & 255;
        if (hasp_g[chain*T_+j]) {
          size_t cb = (size_t)chain*T_*H_;
          fh[cb + (size_t)j*H_ + e] = psum[0][n][e] + psum[1][n][e] + psum[2][n][e];
        }
      }
    }
    __syncthreads();
  }
}

// ---------------- serial tail v3: compact list + 900-thread contiguous-row matvec ----------------
__global__ __launch_bounds__(1024) void k_tail(const float* __restrict__ xg, const float* __restrict__ bhv,
    const float* __restrict__ uh1row,   // raw uh[1] row-major [k][m] (k=output, m=input)
    const int* __restrict__ cnt_g, const int* __restrict__ coff_g,
    const int* __restrict__ eidx_g, const float* __restrict__ ew_g, const int* __restrict__ hasp_g,
    const int* __restrict__ dcnt_g, const int* __restrict__ dlist_g,
    float* __restrict__ hout, float* __restrict__ chist, float* __restrict__ fh)
{
  int chain = blockIdx.x;
  int dc = dcnt_g[chain];
  if (dc == 0) return;
  int tid = threadIdx.x;
  bool act = tid < H_;
  float bh0=0.f,bh1=0.f,bh2=0.f,bh3=0.f;
  if (act) { bh0=bhv[tid]; bh1=bhv[H_+tid]; bh2=bhv[2*H_+tid]; bh3=bhv[3*H_+tid]; }
  __shared__ float h_lds[H_];
  __shared__ float psum[3][H_];
  __shared__ int djs[T_];
  if (tid < dc) djs[tid] = dlist_g[chain*T_ + tid];
  __syncthreads();
  size_t cb = (size_t)chain*T_*H_, xb = (size_t)chain*T_*HG;
  const int* ei = eidx_g + chain*ECAP;
  const float* ewp = ew_g + chain*ECAP;
  for (int di = 0; di < dc; ++di) {
    int j = djs[di];
    if (act) {
      const float* xp = xg + xb + (size_t)j*HG;
      float x0 = xp[tid], x1 = xp[H_+tid], x2 = xp[2*H_+tid], x3 = xp[3*H_+tid];
      float acc = sigm(x0+bh0) * tanhf(x3+bh3);
      float og  = sigm(x2+bh2);
      float x1b = x1 + bh1;
      int c0 = coff_g[chain*T_+j], c1 = c0 + cnt_g[chain*T_+j];
      for (int k = c0; k < c1; ++k) {
        int t = ei[k];
        acc += ewp[k] * sigm(x1b + fh[cb + (size_t)t*H_ + tid]) * chist[cb + (size_t)t*H_ + tid];
      }
      chist[cb + (size_t)j*H_ + tid] = acc;
      float hv = og * tanhf(acc);
      hout[cb + (size_t)j*H_ + tid] = hv;
      h_lds[tid] = hv;
    }
    __syncthreads();
    if (hasp_g[chain*T_+j]) {
      if (tid < 3*H_) {
        int g = tid / H_, e = tid - g*H_;
        float a = 0.f;
        const float* ur = uh1row + (size_t)e*H_ + g*100;   // contiguous 400B chunk
        #pragma unroll 5
        for (int m = 0; m < 100; m += 4) {
          float4 u4 = *(const float4*)(ur + m);
          float4 h4 = *(const float4*)&h_lds[g*100 + m];
          a = fmaf(u4.x, h4.x, a); a = fmaf(u4.y, h4.y, a);
          a = fmaf(u4.z, h4.z, a); a = fmaf(u4.w, h4.w, a);
        }
        psum[g][e] = a;
      }
      __syncthreads();
      if (act) fh[cb + (size_t)j*H_ + tid] = psum[0][tid] + psum[1][tid] + psum[2][tid];
    }
    __syncthreads();
  }
}

// ---------------- split-bf16 MFMA GEMM v4: 2-deep prefetch + XCD-aware block swizzle ----------------
template<int OUTBF, int NT>
__global__ __launch_bounds__(256) void k_gemm_bf(
    const ushort_t* __restrict__ Ah, const ushort_t* __restrict__ Al, int AS,
    const ushort_t* __restrict__ Wh, const ushort_t* __restrict__ Wl, int WS,
    const float* __restrict__ bias, float* __restrict__ C,
    ushort_t* __restrict__ Ch, ushort_t* __restrict__ Cl, int CS,
    int N, int act)
{
  __shared__ ushort_t sAh[128*32], sAl[128*32], sWh[128*32], sWl[128*32];  // 32 KB
  int tid = threadIdx.x;
  // XCD-aware bijective swizzle (T1, m157): nwg % 8 == 0 for all our grids
  int gx = gridDim.x;
  int nwg = gx * gridDim.y;
  int lin = blockIdx.y * gx + blockIdx.x;
  int cpx = nwg >> 3;                       // chunks per XCD
  int wgid = (lin & 7) * cpx + (lin >> 3);  // XCD k owns contiguous tile slab
  int bxs = wgid % gx, bys = wgid / gx;
  int bn = bxs * 128, bm = bys * 128;
  int lane = tid & 63, wave = tid >> 6;
  int wr = (wave >> 1) * 64, wc = (wave & 1) * 64;
  int lrow = lane & 15, q = lane >> 4;

  int srow = tid >> 1, half = tid & 1;
  int ssw = (srow >> 1) & 3;
  int sg0 = ((2*half) ^ ssw) * 8, sg1 = ((2*half+1) ^ ssw) * 8;
  int sbase = srow * 32;
  const ushort_t* pAh = Ah + (size_t)(bm + srow)*AS + half*16;
  const ushort_t* pAl = Al + (size_t)(bm + srow)*AS + half*16;
  int wrow = bn + srow;
  int wsafe = (wrow < N) ? wrow : 0;
  const ushort_t* pWh = Wh + (size_t)wsafe*WS + half*16;
  const ushort_t* pWl = Wl + (size_t)wsafe*WS + half*16;

  bf16x8 aA0,aA1,aA2,aA3,aW0,aW1,aW2,aW3;   // set A
  bf16x8 bA0,bA1,bA2,bA3,bW0,bW1,bW2,bW3;   // set B

#define ISSUE_SET(P,t) { int kb = (t)*32; \
    P##A0 = *(const bf16x8*)(pAh + kb); P##A1 = *(const bf16x8*)(pAh + kb + 8); \
    P##A2 = *(const bf16x8*)(pAl + kb); P##A3 = *(const bf16x8*)(pAl + kb + 8); \
    P##W0 = *(const bf16x8*)(pWh + kb); P##W1 = *(const bf16x8*)(pWh + kb + 8); \
    P##W2 = *(const bf16x8*)(pWl + kb); P##W3 = *(const bf16x8*)(pWl + kb + 8); }
#define COMMIT_SET(P) { \
    *(bf16x8*)&sAh[sbase + sg0] = P##A0; *(bf16x8*)&sAh[sbase + sg1] = P##A1; \
    *(bf16x8*)&sAl[sbase + sg0] = P##A2; *(bf16x8*)&sAl[sbase + sg1] = P##A3; \
    *(bf16x8*)&sWh[sbase + sg0] = P##W0; *(bf16x8*)&sWh[sbase + sg1] = P##W1; \
    *(bf16x8*)&sWl[sbase + sg0] = P##W2; *(bf16x8*)&sWl[sbase + sg1] = P##W3; }

  f32x4 acc[4][4];
  #pragma unroll
  for (int m = 0; m < 4; ++m)
    #pragma unroll
    for (int n = 0; n < 4; ++n) acc[m][n] = (f32x4){0.f,0.f,0.f,0.f};

#define FRAG_MFMA() { \
    bf16x8 ah[4], al[4], bh[4], bl[4]; \
    _Pragma("unroll") \
    for (int m = 0; m < 4; ++m) { \
      int R = wr + m*16 + lrow; \
      int o = R*32 + ((q ^ ((R>>1)&3)) * 8); \
      ah[m] = *(const bf16x8*)&sAh[o]; \
      al[m] = *(const bf16x8*)&sAl[o]; \
    } \
    _Pragma("unroll") \
    for (int n = 0; n < 4; ++n) { \
      int R = wc + n*16 + lrow; \
      int o = R*32 + ((q ^ ((R>>1)&3)) * 8); \
      bh[n] = *(const bf16x8*)&sWh[o]; \
      bl[n] = *(const bf16x8*)&sWl[o]; \
    } \
    _Pragma("unroll") \
    for (int m = 0; m < 4; ++m) \
      _Pragma("unroll") \
      for (int n = 0; n < 4; ++n) { \
        acc[m][n] = __builtin_amdgcn_mfma_f32_16x16x32_bf16(ah[m], bh[n], acc[m][n], 0,0,0); \
        acc[m][n] = __builtin_amdgcn_mfma_f32_16x16x32_bf16(ah[m], bl[n], acc[m][n], 0,0,0); \
        acc[m][n] = __builtin_amdgcn_mfma_f32_16x16x32_bf16(al[m], bh[n], acc[m][n], 0,0,0); \
      } }

  ISSUE_SET(a, 0); COMMIT_SET(a);
  __syncthreads();
  if (NT > 1) ISSUE_SET(b, 1);
  #pragma unroll
  for (int t = 0; t < NT; t += 2) {
    FRAG_MFMA();
    if (t+2 < NT) ISSUE_SET(a, t+2);
    __syncthreads();
    if (t+1 < NT) COMMIT_SET(b);
    __syncthreads();
    if (t+1 < NT) {
      FRAG_MFMA();
      if (t+3 < NT) ISSUE_SET(b, t+3);
      __syncthreads();
      if (t+2 < NT) COMMIT_SET(a);
      __syncthreads();
    }
  }
#undef ISSUE_SET
#undef COMMIT_SET
#undef FRAG_MFMA

  #pragma unroll
  for (int m = 0; m < 4; ++m) {
    int row0 = bm + wr + m*16 + (lane >> 4)*4;
    #pragma unroll
    for (int n = 0; n < 4; ++n) {
      int col = bn + wc + n*16 + lrow;
      if (OUTBF) {
        if (col < CS) {
          float bv = (col < N) ? bias[col] : 0.f;
          #pragma unroll
          for (int r = 0; r < 4; ++r) {
            float v = 0.f;
            if (col < N) { v = acc[m][n][r] + bv; if (act) v = fmaxf(v, 0.f); }
            ushort_t h = f2bf(v);
            Ch[(size_t)(row0 + r)*CS + col] = h;
            Cl[(size_t)(row0 + r)*CS + col] = f2bf(v - bf2f(h));
          }
        }
      } else {
        if (col < N) {
          float bv = bias[col];
          #pragma unroll
          for (int r = 0; r < 4; ++r) {
            float v = acc[m][n][r] + bv;
            if (act) v = fmaxf(v, 0.f);
            C[(size_t)(row0 + r)*N + col] = v;
          }
        }
      }
    }
  }
}

// ---------------- fused MFMA attention v2: bf16 pre-split inputs (round-13) ----------------
__global__ __launch_bounds__(256) void k_attn_mfma(
    const ushort_t* __restrict__ HH, const ushort_t* __restrict__ HL,
    const int* __restrict__ plen, const int* __restrict__ hlen,
    float* __restrict__ ATT)
{
  __shared__ float regA_f[12800];
  __shared__ ushort_t pbuf[2*64*136];
  ushort_t* regA = (ushort_t*)regA_f;

  int tid = threadIdx.x;
  int lane = tid & 63, wave = tid >> 6;
  int lrow = lane & 15, koff = (lane >> 4) * 8;
  int d = blockIdx.x, b = blockIdx.y, q0 = blockIdx.z * 64;
  int qbase = (d*B_ + b)*T_ + q0;
  int kbase = ((1-d)*B_ + b)*T_;
  float* outp = ATT + ((size_t)(d*B_ + b)*T_ + q0) * H_;
  int klen = (d == 0) ? hlen[b] : plen[b];

  ushort_t* sQh = regA;            // [64][40]
  ushort_t* sQl = regA + 2560;
  ushort_t* sKh = regA + 5120;     // [128][40]
  ushort_t* sKl = regA + 10240;
  int qrow = tid >> 2, qo = (tid & 3) * 8;
  int krow = tid >> 1, ko = (tid & 1) * 16;
  const ushort_t* Qh = HH + (size_t)(qbase + qrow)*320 + qo;
  const ushort_t* Ql = HL + (size_t)(qbase + qrow)*320 + qo;
  const ushort_t* Kh = HH + (size_t)(kbase + krow)*320 + ko;
  const ushort_t* Kl = HL + (size_t)(kbase + krow)*320 + ko;

  bf16x8 rqh, rql, rkh0, rkh1, rkl0, rkl1;
  auto issue1 = [&](int t){
    int kb = t*32;
    rqh  = *(const bf16x8*)(Qh + kb);
    rql  = *(const bf16x8*)(Ql + kb);
    rkh0 = *(const bf16x8*)(Kh + kb); rkh1 = *(const bf16x8*)(Kh + kb + 8);
    rkl0 = *(const bf16x8*)(Kl + kb); rkl1 = *(const bf16x8*)(Kl + kb + 8);
  };
  auto commit1 = [&](){
    *(bf16x8*)&sQh[qrow*40 + qo] = rqh;
    *(bf16x8*)&sQl[qrow*40 + qo] = rql;
    *(bf16x8*)&sKh[krow*40 + ko] = rkh0; *(bf16x8*)&sKh[krow*40 + ko + 8] = rkh1;
    *(bf16x8*)&sKl[krow*40 + ko] = rkl0; *(bf16x8*)&sKl[krow*40 + ko + 8] = rkl1;
  };

  f32x4 acc1[4][2];
  #pragma unroll
  for (int m = 0; m < 4; ++m)
    #pragma unroll
    for (int n = 0; n < 2; ++n) acc1[m][n] = (f32x4){0.f,0.f,0.f,0.f};
  int wc = wave * 32;

  issue1(0); commit1();
  __syncthreads();
  for (int t = 0; t < 10; ++t) {
    bool more = (t < 9);
    bf16x8 ah[4], al[4], bh[2], bl[2];
    #pragma unroll
    for (int m = 0; m < 4; ++m) {
      int o = (m*16 + lrow)*40 + koff;
      ah[m] = *(const bf16x8*)&sQh[o];
      al[m] = *(const bf16x8*)&sQl[o];
    }
    #pragma unroll
    for (int n = 0; n < 2; ++n) {
      int o = (wc + n*16 + lrow)*40 + koff;
      bh[n] = *(const bf16x8*)&sKh[o];
      bl[n] = *(const bf16x8*)&sKl[o];
    }
    if (more) issue1(t+1);
    __syncthreads();
    if (more) commit1();
    #pragma unroll
    for (int m = 0; m < 4; ++m)
      #pragma unroll
      for (int n = 0; n < 2; ++n) {
        acc1[m][n] = __builtin_amdgcn_mfma_f32_16x16x32_bf16(ah[m], bh[n], acc1[m][n], 0,0,0);
        acc1[m][n] = __builtin_amdgcn_mfma_f32_16x16x32_bf16(ah[m], bl[n], acc1[m][n], 0,0,0);
        acc1[m][n] = __builtin_amdgcn_mfma_f32_16x16x32_bf16(al[m], bh[n], acc1[m][n], 0,0,0);
      }
    __syncthreads();
  }
  float* sim = regA_f;
  #pragma unroll
  for (int m = 0; m < 4; ++m)
    #pragma unroll
    for (int n = 0; n < 2; ++n)
      #pragma unroll
      for (int r = 0; r < 4; ++r)
        sim[(m*16 + (lane>>4)*4 + r)*132 + wc + n*16 + lrow] = acc1[m][n][r];
  __syncthreads();

  {
    int row = tid >> 2, qtr = (tid & 3) * 32;
    const float* sr = sim + row*132;
    float mx = NEGV;
    for (int c = 0; c < 32; ++c) { int cg = qtr + c; float s = (cg < klen) ? sr[cg] : NEGV; mx = fmaxf(mx, s); }
    mx = fmaxf(mx, __shfl_xor(mx, 1));
    mx = fmaxf(mx, __shfl_xor(mx, 2));
    float sum = 0.f;
    for (int c = 0; c < 32; ++c) { int cg = qtr + c; if (cg < klen) sum += expf(sr[cg] - mx); }
    sum += __shfl_xor(sum, 1);
    sum += __shfl_xor(sum, 2);
    float rinv = 1.f / sum;
    for (int c = 0; c < 32; ++c) {
      int cg = qtr + c;
      float p = (cg < klen) ? expf(sr[cg] - mx) * rinv : 0.f;
      ushort_t h = f2bf(p);
      pbuf[row*136 + cg] = h;
      pbuf[64*136 + row*136 + cg] = f2bf(p - bf2f(h));
    }
  }
  __syncthreads();

  ushort_t* kth = regA;            // [320][40]
  ushort_t* ktl = regA + 12800;
  int wr2 = (wave & 1) * 32;
  int wcf = (wave >> 1) * 160;
  f32x4 acc3[2][10];
  #pragma unroll
  for (int m = 0; m < 2; ++m)
    #pragma unroll
    for (int n = 0; n < 10; ++n) acc3[m][n] = (f32x4){0.f,0.f,0.f,0.f};
  int skey = tid >> 3, sf8 = tid & 7;

  for (int kc = 0; kc < 4; ++kc) {
    __syncthreads();
    int key = kbase + kc*32 + skey;
    const ushort_t* krh = HH + (size_t)key*320;
    const ushort_t* krl = HL + (size_t)key*320;
    for (int f8 = sf8; f8 < 40; f8 += 8) {
      bf16x8 vh = *(const bf16x8*)(krh + f8*8);
      bf16x8 vl = *(const bf16x8*)(krl + f8*8);
      #pragma unroll
      for (int i = 0; i < 8; ++i) {
        int feat = f8*8 + i;
        kth[feat*40 + skey] = (ushort_t)vh[i];
        ktl[feat*40 + skey] = (ushort_t)vl[i];
      }
    }
    __syncthreads();
    bf16x8 ph[2], pl[2], kh[10], kl[10];
    #pragma unroll
    for (int m = 0; m < 2; ++m) {
      int o = (wr2 + m*16 + lrow)*136 + kc*32 + koff;
      ph[m] = *(const bf16x8*)&pbuf[o];
      pl[m] = *(const bf16x8*)&pbuf[64*136 + o];
    }
    #pragma unroll
    for (int n = 0; n < 10; ++n) {
      int o = (wcf + n*16 + lrow)*40 + koff;
      kh[n] = *(const bf16x8*)&kth[o];
      kl[n] = *(const bf16x8*)&ktl[o];
    }
    #pragma unroll
    for (int m = 0; m < 2; ++m)
      #pragma unroll
      for (int n = 0; n < 10; ++n) {
        acc3[m][n] = __builtin_amdgcn_mfma_f32_16x16x32_bf16(ph[m], kh[n], acc3[m][n], 0,0,0);
        acc3[m][n] = __builtin_amdgcn_mfma_f32_16x16x32_bf16(ph[m], kl[n], acc3[m][n], 0,0,0);
        acc3[m][n] = __builtin_amdgcn_mfma_f32_16x16x32_bf16(pl[m], kh[n], acc3[m][n], 0,0,0);
      }
  }
  #pragma unroll
  for (int m = 0; m < 2; ++m) {
    int row0 = wr2 + m*16 + (lane >> 4)*4;
    #pragma unroll
    for (int n = 0; n < 10; ++n) {
      int col = wcf + n*16 + lrow;
      if (col < H_) {
        #pragma unroll
        for (int r = 0; r < 4; ++r)
          outp[(size_t)(row0 + r)*H_ + col] = acc3[m][n][r];
      }
    }
  }
}

// ---------------- pool stage 1 ----------------
__global__ __launch_bounds__(320) void k_pool(const float* __restrict__ H,
    const int* __restrict__ plen, const int* __restrict__ hlen,
    float* __restrict__ psum, float* __restrict__ pmax)
{
  int chain = blockIdx.x; int s = chain >> 5, b = chain & 31;
  int c = blockIdx.y; int t0 = c * 16;
  int len = (s == 0 ? plen[b] : hlen[b]);
  int tid = threadIdx.x;
  __shared__ float buf[16*H_];
  const float* hp = H + (size_t)chain*T_*H_ + (size_t)t0*H_;
  for (int i = tid; i < 16*H_; i += 320) buf[i] = hp[i];
  __syncthreads();
  if (tid < H_) {
    int tmax = len - t0; if (tmax > 16) tmax = 16;
    float sum = 0.f, mx = NEGV;
    for (int t = 0; t < tmax; ++t) { float x = buf[t*H_ + tid]; sum += x; mx = fmaxf(mx, x); }
    int o = (chain*8 + c)*H_ + tid;
    psum[o] = sum; pmax[o] = mx;
  }
}

// ---------------- pool stage 2 + classifier ----------------
__global__ __launch_bounds__(320) void k_classify(
    const float* __restrict__ psum, const float* __restrict__ pmax,
    const int* __restrict__ plen, const int* __restrict__ hlen,
    const float* __restrict__ w1t, const float* __restrict__ b1,
    const float* __restrict__ w2, const float* __restrict__ b2,
    float* __restrict__ out)
{
  int b = blockIdx.x;
  int tid = threadIdx.x;
  __shared__ float v[HG];
  __shared__ float hid[H_];
  for (int s = 0; s < 2; ++s) {
    int chain = s*B_ + b;
    int len = (s == 0 ? plen[b] : hlen[b]);
    if (tid < H_) {
      float sum = 0.f, mx = NEGV;
      #pragma unroll
      for (int c = 0; c < 8; ++c) {
        int o = (chain*8 + c)*H_ + tid;
        sum += psum[o]; mx = fmaxf(mx, pmax[o]);
      }
      v[s*600 + tid]       = sum / (float)len;
      v[s*600 + 300 + tid] = mx;
    }
  }
  __syncthreads();
  if (tid < H_) {
    float a0 = b1[tid], a1 = 0.f, a2 = 0.f, a3 = 0.f;
    for (int m = 0; m < HG; m += 4) {
      a0 = fmaf(v[m+0], w1t[(size_t)(m+0)*H_ + tid], a0);
      a1 = fmaf(v[m+1], w1t[(size_t)(m+1)*H_ + tid], a1);
      a2 = fmaf(v[m+2], w1t[(size_t)(m+2)*H_ + tid], a2);
      a3 = fmaf(v[m+3], w1t[(size_t)(m+3)*H_ + tid], a3);
    }
    hid[tid] = tanhf(a0 + a1 + a2 + a3);
  }
  __syncthreads();
  if (tid < 3) {
    float a = b2[tid];
    const float* wr = w2 + (size_t)tid*H_;
    for (int n = 0; n < H_; ++n) a = fmaf(hid[n], wr[n], a);
    out[b*3 + tid] = a;
  }
}

// ---------------- launch ----------------
extern "C" void kernel_launch(void* const* d_in, const int* in_sizes, int n_in,
                              void* d_out, int out_size, void* d_ws, size_t ws_size,
                              hipStream_t stream) {
  const int*   prem    = (const int*)d_in[0];
  const int*   plen    = (const int*)d_in[1];
  const int*   hyp     = (const int*)d_in[2];
  const int*   hlen    = (const int*)d_in[3];
  const float* lg      = (const float*)d_in[4];
  const float* rg      = (const float*)d_in[5];
  const float* emb     = (const float*)d_in[6];
  const float* enc_wx  = (const float*)d_in[7];
  const float* enc_bx  = (const float*)d_in[8];
  const float* enc_uh  = (const float*)d_in[9];
  const float* enc_bh  = (const float*)d_in[10];
  const float* comp_wx = (const float*)d_in[11];
  const float* comp_bx = (const float*)d_in[12];
  const float* comp_uh = (const float*)d_in[13];
  const float* comp_bh = (const float*)d_in[14];
  const float* proj_w  = (const float*)d_in[15];
  const float* proj_b  = (const float*)d_in[16];
  const float* cls_w1  = (const float*)d_in[17];
  const float* cls_b1  = (const float*)d_in[18];
  const float* cls_w2  = (const float*)d_in[19];
  const float* cls_b2  = (const float*)d_in[20];
  float* outp = (float*)d_out;

  // workspace layout (floats); ENH bf16 aliases XG; PROJ/H-split bf16 alias EH/EL
  float* XG  = (float*)d_ws;                       // 9,830,400 f
  ushort_t* EH = (ushort_t*)(XG + 9830400);        // [8192][320] hi (emb -> h-split -> PROJ)
  ushort_t* EL = EH + 2621440;                     // [8192][320] lo
  float* H1  = XG + 9830400 + 2621440;
  float* CH  = H1 + 2457600;                       // ATT alias
  float* FH  = CH + 2457600;
  float* UTE = FH + 2457600;
  float* UTC = UTE + 90000;
  float* W1T = UTC + 90000;
  ushort_t* WencH  = (ushort_t*)(W1T + 360000);
  ushort_t* WencL  = WencH + 384000;
  ushort_t* WcompH = WencL + 384000;
  ushort_t* WcompL = WcompH + 384000;
  ushort_t* WPH    = WcompL + 384000;
  ushort_t* WPL    = WPH + 278400;
  float* PSUM = W1T + 360000 + 1046400;
  float* PMAX = PSUM + 153600;
  float* EW   = PMAX + 153600;
  int* EIDX   = (int*)(EW + 64*ECAP);
  int* CNT    = EIDX + 64*ECAP;
  int* COFF   = CNT + 64*T_;
  int* DEPTH  = COFF + 64*T_;
  int* HASP   = DEPTH + 64*T_;
  int* LVLCNT = HASP + 64*T_;
  int* WL     = LVLCNT + TAILD;
  int* DCNT   = WL + TAILD*WLCAP;
  int* DLIST  = DCNT + 64;
  float* ATT  = CH;
  ushort_t* ENH_H = (ushort_t*)XG;                 // [8192][928] hi (after enc scan, XG dead)
  ushort_t* ENH_L = ENH_H + 7602176;

  hipMemsetAsync(LVLCNT, 0, TAILD*sizeof(int), stream);
  // 1. weight prep + graph analysis + embedding split
  k_prep_all<<<(1496400 + 255)/256, 256, 0, stream>>>(enc_uh, comp_uh, enc_wx, comp_wx, proj_w, cls_w1,
      UTE, UTC, W1T, WencH, WencL, WcompH, WcompL, WPH, WPL);
  k_build<<<64, 256, 0, stream>>>(lg, rg, CNT, COFF, EIDX, EW, HASP, DEPTH, LVLCNT, WL, DCNT, DLIST);
  k_embed_split<<<10240, 256, 0, stream>>>(prem, hyp, emb, EH, EL);
  // 2. enc xg = emb @ enc_wx^T + enc_bx
  k_gemm_bf<0,10><<<dim3(10, 64), 256, 0, stream>>>(EH, EL, 320, WencH, WencL, 320,
      enc_bx, XG, nullptr, nullptr, 0, HG, 0);
  // 3. enc tree scan (levels 0..3 parallel, deep nodes via compact-list parallel-matvec tail)
  for (int L = 0; L < TAILD; ++L)
    k_level<<<640, 1024, 0, stream>>>(XG, enc_bh, UTE, CNT, COFF, EIDX, EW, HASP, LVLCNT, WL, L, H1, CH, FH);
  k_tail<<<64, 1024, 0, stream>>>(XG, enc_bh, enc_uh + H_*H_, CNT, COFF, EIDX, EW, HASP, DCNT, DLIST, H1, CH, FH);
  // 4. h-split + attention (CH dead -> ATT)
  k_h_split<<<10240, 256, 0, stream>>>(H1, EH, EL);
  k_attn_mfma<<<dim3(2, B_, 2), 256, 0, stream>>>(EH, EL, plen, hlen, ATT);
  // 5. enhance split (enc-xg dead), proj GEMM -> PROJ bf16 hi/lo (overwrites EH/EL)
  k_enh_split<<<29696, 256, 0, stream>>>(H1, ATT, ENH_H, ENH_L);
  k_gemm_bf<1,29><<<dim3(3, 64), 256, 0, stream>>>(ENH_H, ENH_L, 928, WPH, WPL, 928,
      proj_b, nullptr, EH, EL, 320, H_, 1);
  // 6. comp xg = proj @ comp_wx^T + comp_bx (overwrites XG)
  k_gemm_bf<0,10><<<dim3(10, 64), 256, 0, stream>>>(EH, EL, 320, WcompH, WcompL, 320,
      comp_bx, XG, nullptr, nullptr, 0, HG, 0);
  // 7. comp tree scan
  for (int L = 0; L < TAILD; ++L)
    k_level<<<640, 1024, 0, stream>>>(XG, comp_bh, UTC, CNT, COFF, EIDX, EW, HASP, LVLCNT, WL, L, H1, CH, FH);
  k_tail<<<64, 1024, 0, stream>>>(XG, comp_bh, comp_uh + H_*H_, CNT, COFF, EIDX, EW, HASP, DCNT, DLIST, H1, CH, FH);
  // 8. pool + classifier
  k_pool<<<dim3(64, 8), 320, 0, stream>>>(H1, plen, hlen, PSUM, PMAX);
  k_classify<<<B_, 320, 0, stream>>>(PSUM, PMAX, plen, hlen, W1T, cls_b1, cls_w2, cls_b2, outp);
}